// Round 1
// 495.557 us; speedup vs baseline: 1.0417x; 1.0417x over previous
//
#include <hip/hip_runtime.h>
#include <math.h>

#define NN 50000
#define EE 800000
#define BBG 256
#define HHC 128
#define SEG_CAP 448  // LDS x-cache rows per graph (fp16 packed)
#define ESC 512      // per-graph e-cache entries in LDS
#define NBIN 196     // coarse bins of 256 nodes
#define NBLK 196     // blocks in K1/K3 (4096 edges each)

typedef _Float16 half8 __attribute__((ext_vector_type(8)));
typedef _Float16 half4 __attribute__((ext_vector_type(4)));
typedef _Float16 half2v __attribute__((ext_vector_type(2)));

#if defined(__has_builtin)
#if __has_builtin(__builtin_amdgcn_fdot2)
#define USE_FDOT2 1
#endif
#endif

__device__ __forceinline__ float fdot2f(half2v a, half2v b, float c) {
#ifdef USE_FDOT2
  return __builtin_amdgcn_fdot2(a, b, c, false);
#else
  return fmaf((float)a[0], (float)b[0], fmaf((float)a[1], (float)b[1], c));
#endif
}

__device__ __forceinline__ float fsigm(float x) {
  return __builtin_amdgcn_rcpf(1.f + __expf(-x));
}
__device__ __forceinline__ float ftanh(float x) {
  // tanh(x) = 1 - 2/(exp(2x)+1); exact at +-inf limits
  return 1.f - 2.f * __builtin_amdgcn_rcpf(1.f + __expf(2.f * x));
}

__device__ __forceinline__ float4 aff4(float4 v, float4 sc, float4 sh) {
  v.x = fmaxf(fmaf(v.x, sc.x, sh.x), 0.f);
  v.y = fmaxf(fmaf(v.y, sc.y, sh.y), 0.f);
  v.z = fmaxf(fmaf(v.z, sc.z, sh.z), 0.f);
  v.w = fmaxf(fmaf(v.w, sc.w, sh.w), 0.f);
  return v;
}
__device__ __forceinline__ void add4(float4& a, float4 b) {
  a.x += b.x; a.y += b.y; a.z += b.z; a.w += b.w;
}
__device__ __forceinline__ float4 cvt4(half4 h) {
  return make_float4((float)h[0], (float)h[1], (float)h[2], (float)h[3]);
}

// ---------------- merged prep: zero | gptr | coarse hist | weight repack | x->fp16 ----
// LSTM weights -> fp16, gate-interleaved (col op=4j+g), k-PAIR-interleaved for fdot2:
// element (k, op) stored at ((k>>1)<<10) | (op<<1) | (k&1)  -> one uint = half2(k, k+1) of col op
__global__ __launch_bounds__(256) void prep_all_kernel(
    const int* __restrict__ batch,
    const int* __restrict__ ei,
    const float* __restrict__ W0, const float* __restrict__ W1,
    const float* __restrict__ W2, const float* __restrict__ W3,
    const float* __restrict__ Wih0, const float* __restrict__ Whh0,
    const float* __restrict__ WihR, const float* __restrict__ WhhR,
    const float* __restrict__ b0, const float* __restrict__ bR,
    const float* __restrict__ xsrc,
    float* __restrict__ stats, int* __restrict__ gptr, int* __restrict__ partial,
    float* __restrict__ ginWT, _Float16* __restrict__ WT0h,
    _Float16* __restrict__ WTRh, float* __restrict__ bc0, float* __restrict__ bcR,
    _Float16* __restrict__ x16a) {
  __shared__ int hist[NBIN];
  int blk = blockIdx.x, tid = threadIdx.x;
  if (blk == 0) {
    ((float4*)stats)[tid] = make_float4(0.f, 0.f, 0.f, 0.f);  // 1024 floats
    return;
  }
  if (blk <= 196) {  // gptr boundaries
    int i = (blk - 1) * 256 + tid;
    if (i >= NN) return;
    int b = batch[i];
    int prev = (i == 0) ? -1 : batch[i - 1];
    for (int g = prev + 1; g <= b; ++g) gptr[g] = i;
    if (i == NN - 1) {
      for (int g = b + 1; g <= BBG; ++g) gptr[g] = NN;
    }
    return;
  }
  if (blk <= 392) {  // coarse hist
    int b = blk - 197;
    if (tid < NBIN) hist[tid] = 0;
    __syncthreads();
    const int4* dst4 = (const int4*)(ei + EE);
#pragma unroll
    for (int c = 0; c < 4; ++c) {
      int idx = b * 1024 + c * 256 + tid;
      if (idx < EE / 4) {
        int4 d = dst4[idx];
        atomicAdd(&hist[d.x >> 8], 1);
        atomicAdd(&hist[d.y >> 8], 1);
        atomicAdd(&hist[d.z >> 8], 1);
        atomicAdd(&hist[d.w >> 8], 1);
      }
    }
    __syncthreads();
    if (tid < NBIN) partial[tid * NBLK + b] = hist[tid];
    return;
  }
  if (blk >= 2961) {  // x -> fp16 (6250 blocks x 256 = 1,600,000 float4 groups)
    int i = (blk - 2961) * 256 + tid;
    float4 v = ((const float4*)xsrc)[i];
    half4 h;
    h[0] = (_Float16)v.x; h[1] = (_Float16)v.y;
    h[2] = (_Float16)v.z; h[3] = (_Float16)v.w;
    ((half4*)x16a)[i] = h;
    return;
  }
  // weight prep
  int idx = (blk - 393) * 256 + tid;  // [0, 657408)
  if (idx < 65536) {
    int m = idx >> 14;
    int r = idx & 16383;
    int k = r >> 7, o = r & 127;
    const float* W = (m == 0) ? W0 : (m == 1) ? W1 : (m == 2) ? W2 : W3;
    ginWT[idx] = W[o * 128 + k];
  } else if (idx < 262144) {
    int t = idx - 65536;
    int k = t >> 9, op = t & 511;
    int j = op >> 2, g = op & 3;
    int row = g * 128 + j;
    float v = (k < 256) ? Wih0[row * 256 + k] : Whh0[row * 128 + (k - 256)];
    WT0h[((k >> 1) << 10) | (op << 1) | (k & 1)] = (_Float16)v;
  } else if (idx < 655360) {
    int t = idx - 262144;
    int l = t >> 17;
    int rem = t & 131071;
    int k = rem >> 9, op = rem & 511;
    int j = op >> 2, g = op & 3;
    int row = g * 128 + j;
    float v = (k < 128) ? WihR[((size_t)l * 512 + row) * 128 + k]
                        : WhhR[((size_t)l * 512 + row) * 128 + (k - 128)];
    WTRh[((size_t)l << 17) | ((k >> 1) << 10) | (op << 1) | (k & 1)] = (_Float16)v;
  } else {
    int t = idx - 655360;
    if (t < 512) {
      bc0[t] = b0[(t & 3) * 128 + (t >> 2)];
    } else {
      int u = t - 512;
      int l = u >> 9, op = u & 511;
      bcR[u] = bR[l * 512 + (op & 3) * 128 + (op >> 2)];
    }
  }
}

// ---- atomic-free CSR build (two-level counting sort) ----

__global__ void scan_partials_kernel(const int* __restrict__ partial,
                                     int* __restrict__ block_base, int* __restrict__ total) {
  __shared__ int buf[256];
  int bin = blockIdx.x, tid = threadIdx.x;
  int v = (tid < NBLK) ? partial[bin * NBLK + tid] : 0;
  buf[tid] = v;
  __syncthreads();
  for (int off = 1; off < 256; off <<= 1) {
    int t = (tid >= off) ? buf[tid - off] : 0;
    __syncthreads();
    buf[tid] += t;
    __syncthreads();
  }
  if (tid < NBLK) block_base[bin * NBLK + tid] = buf[tid] - v;
  if (tid == 255) total[bin] = buf[255];
}

__global__ void scan_totals_kernel(const int* __restrict__ total, int* __restrict__ coarse_base) {
  __shared__ int buf[256];
  int tid = threadIdx.x;
  int v = (tid < NBIN) ? total[tid] : 0;
  buf[tid] = v;
  __syncthreads();
  for (int off = 1; off < 256; off <<= 1) {
    int t = (tid >= off) ? buf[tid - off] : 0;
    __syncthreads();
    buf[tid] += t;
    __syncthreads();
  }
  if (tid < NBIN) coarse_base[tid] = buf[tid] - v;
  if (tid == 255) coarse_base[NBIN] = buf[255];
}

__global__ __launch_bounds__(256) void bucket_scatter_kernel(const int* __restrict__ ei,
                                                             const int* __restrict__ coarse_base,
                                                             const int* __restrict__ block_base,
                                                             int* __restrict__ packed) {
  __shared__ int cursor[NBIN];
  int tid = threadIdx.x, b = blockIdx.x;
  if (tid < NBIN) cursor[tid] = coarse_base[tid] + block_base[tid * NBLK + b];
  __syncthreads();
  const int4* src4 = (const int4*)ei;
  const int4* dst4 = (const int4*)(ei + EE);
#pragma unroll
  for (int c = 0; c < 4; ++c) {
    int idx = b * 1024 + c * 256 + tid;
    if (idx < EE / 4) {
      int4 s = src4[idx];
      int4 d = dst4[idx];
      int p;
      p = atomicAdd(&cursor[d.x >> 8], 1); packed[p] = (s.x << 8) | (d.x & 255);
      p = atomicAdd(&cursor[d.y >> 8], 1); packed[p] = (s.y << 8) | (d.y & 255);
      p = atomicAdd(&cursor[d.z >> 8], 1); packed[p] = (s.z << 8) | (d.z & 255);
      p = atomicAdd(&cursor[d.w >> 8], 1); packed[p] = (s.w << 8) | (d.w & 255);
    }
  }
}

__global__ __launch_bounds__(256) void csr_finalize_kernel(const int* __restrict__ packed,
                                                           const int* __restrict__ coarse_base,
                                                           int* __restrict__ row_start,
                                                           int* __restrict__ csr) {
  __shared__ int fh[256];
  __shared__ int fb[256];
  int bin = blockIdx.x, tid = threadIdx.x;
  int e0 = coarse_base[bin], e1 = coarse_base[bin + 1];
  fh[tid] = 0;
  __syncthreads();
  for (int e = e0 + tid; e < e1; e += 256) atomicAdd(&fh[packed[e] & 255], 1);
  __syncthreads();
  int v = fh[tid];
  fb[tid] = v;
  __syncthreads();
  for (int off = 1; off < 256; off <<= 1) {
    int t = (tid >= off) ? fb[tid - off] : 0;
    __syncthreads();
    fb[tid] += t;
    __syncthreads();
  }
  int excl = fb[tid] - v;
  int node = bin * 256 + tid;
  if (node < NN) row_start[node] = e0 + excl;
  if (bin == NBIN - 1 && tid == 0) row_start[NN] = EE;
  __syncthreads();
  fb[tid] = excl;  // cursor
  __syncthreads();
  for (int e = e0 + tid; e < e1; e += 256) {
    int p = packed[e];
    int pos = atomicAdd(&fb[p & 255], 1);
    csr[e0 + pos] = p >> 8;
  }
}

// ---------------- GIN ----------------

// one wave per node; each 32-lane half loads a full 256B fp16 row as half4/lane.
template <bool AFF>
__global__ __launch_bounds__(256) void gin_agg_kernel(
    const _Float16* __restrict__ x16, const int* __restrict__ row_start,
    const int* __restrict__ csr,
    const float* __restrict__ stats, const float* __restrict__ gamma,
    const float* __restrict__ beta, float* __restrict__ outp) {
  __shared__ float sc_s[128], sh_s[128];
  if (AFF) {
    int t = threadIdx.x;
    if (t < 128) {
      const float invN = 1.0f / (float)NN;
      float mm = stats[t] * invN;
      float vv = stats[128 + t] * invN - mm * mm;
      float rs = rsqrtf(vv + 1e-5f);
      float sc = gamma[t] * rs;
      sc_s[t] = sc;
      sh_s[t] = beta[t] - mm * sc;
    }
    __syncthreads();
  }
  int node = blockIdx.x * 4 + (threadIdx.x >> 6);  // exact: 12500*4 = 50000
  int lane = threadIdx.x & 63;
  int half = lane >> 5, ln = lane & 31;
  const half4* xh = (const half4*)x16;  // row = node*32 half4s
  float4 sc4 = make_float4(0.f, 0.f, 0.f, 0.f), sh4 = sc4;
  if (AFF) {
    sc4 = *(const float4*)&sc_s[4 * ln];
    sh4 = *(const float4*)&sh_s[4 * ln];
  }
  int s0 = row_start[node], s1 = row_start[node + 1];
  float4 self = cvt4(xh[(size_t)node * 32 + ln]);
  if (AFF) self = aff4(self, sc4, sh4);
  float4 c0 = make_float4(0.f, 0.f, 0.f, 0.f), c1 = c0, c2 = c0, c3 = c0;
  int cnt = s1 - s0;
  int mainEnd = s0 + (cnt & ~15);
  for (int j = s0; j < mainEnd; j += 16) {
    int i0 = csr[j + half + 0];
    int i1 = csr[j + half + 2];
    int i2 = csr[j + half + 4];
    int i3 = csr[j + half + 6];
    int i4 = csr[j + half + 8];
    int i5 = csr[j + half + 10];
    int i6 = csr[j + half + 12];
    int i7 = csr[j + half + 14];
    half4 h0 = xh[(size_t)i0 * 32 + ln];
    half4 h1 = xh[(size_t)i1 * 32 + ln];
    half4 h2 = xh[(size_t)i2 * 32 + ln];
    half4 h3 = xh[(size_t)i3 * 32 + ln];
    half4 h4 = xh[(size_t)i4 * 32 + ln];
    half4 h5 = xh[(size_t)i5 * 32 + ln];
    half4 h6 = xh[(size_t)i6 * 32 + ln];
    half4 h7 = xh[(size_t)i7 * 32 + ln];
    float4 v0 = cvt4(h0);
    float4 v1 = cvt4(h1);
    float4 v2 = cvt4(h2);
    float4 v3 = cvt4(h3);
    float4 v4 = cvt4(h4);
    float4 v5 = cvt4(h5);
    float4 v6 = cvt4(h6);
    float4 v7 = cvt4(h7);
    if (AFF) {
      v0 = aff4(v0, sc4, sh4); v1 = aff4(v1, sc4, sh4);
      v2 = aff4(v2, sc4, sh4); v3 = aff4(v3, sc4, sh4);
      v4 = aff4(v4, sc4, sh4); v5 = aff4(v5, sc4, sh4);
      v6 = aff4(v6, sc4, sh4); v7 = aff4(v7, sc4, sh4);
    }
    add4(c0, v0); add4(c1, v1); add4(c2, v2); add4(c3, v3);
    add4(c0, v4); add4(c1, v5); add4(c2, v6); add4(c3, v7);
  }
  for (int j = mainEnd + half; j < s1; j += 2) {
    int i = csr[j];
    float4 v = cvt4(xh[(size_t)i * 32 + ln]);
    if (AFF) v = aff4(v, sc4, sh4);
    add4(c0, v);
  }
  float4 t;
  t.x = (c0.x + c1.x) + (c2.x + c3.x);
  t.y = (c0.y + c1.y) + (c2.y + c3.y);
  t.z = (c0.z + c1.z) + (c2.z + c3.z);
  t.w = (c0.w + c1.w) + (c2.w + c3.w);
  t.x += __shfl_xor(t.x, 32);
  t.y += __shfl_xor(t.y, 32);
  t.z += __shfl_xor(t.z, 32);
  t.w += __shfl_xor(t.w, 32);
  t.x += self.x; t.y += self.y; t.z += self.z; t.w += self.w;
  if (half == 0) ((float4*)outp)[(size_t)node * 32 + ln] = t;
}

// C = f(A) @ W^T + b, f = optional fused BN(stats)+relu; per-channel stats atomics.
// Optional fp32 output (C may be null) and optional fp16 output copy (h16out).
template <bool BN>
__global__ __launch_bounds__(256) void gemm_gin_kernel(
    const float* __restrict__ A, const float* __restrict__ WT,
    const float* __restrict__ bias,
    const float* __restrict__ stats, const float* __restrict__ gamma,
    const float* __restrict__ beta,
    float* __restrict__ C, _Float16* __restrict__ h16out,
    float* __restrict__ ssum, float* __restrict__ ssq, int M) {
  __shared__ float As[64][132];
  __shared__ float Wt[128][68];
  __shared__ float bsc[128], bsh[128];
  int tid = threadIdx.x;
  if (BN) {
    if (tid < 128) {
      const float invN = 1.0f / (float)NN;
      float mm = stats[tid] * invN;
      float vv = stats[128 + tid] * invN - mm * mm;
      float rs = rsqrtf(vv + 1e-5f);
      float sc = gamma[tid] * rs;
      bsc[tid] = sc;
      bsh[tid] = beta[tid] - mm * sc;
    }
    __syncthreads();
  }
  int tx = tid & 15, ty = tid >> 4;
  int bx = blockIdx.x & 1, by = blockIdx.x >> 1;
  int row0 = by * 64, c0 = bx * 64;
#pragma unroll
  for (int i = 0; i < 8; ++i) {
    int slot = tid + i * 256;
    int r = slot >> 5, k4 = (slot & 31) << 2;
    float4 v = make_float4(0.f, 0.f, 0.f, 0.f);
    if (row0 + r < M) v = *(const float4*)(A + (size_t)(row0 + r) * 128 + k4);
    if (BN) {
      v.x = fmaxf(fmaf(v.x, bsc[k4 + 0], bsh[k4 + 0]), 0.f);
      v.y = fmaxf(fmaf(v.y, bsc[k4 + 1], bsh[k4 + 1]), 0.f);
      v.z = fmaxf(fmaf(v.z, bsc[k4 + 2], bsh[k4 + 2]), 0.f);
      v.w = fmaxf(fmaf(v.w, bsc[k4 + 3], bsh[k4 + 3]), 0.f);
    }
    *(float4*)&As[r][k4] = v;
  }
#pragma unroll
  for (int i = 0; i < 8; ++i) {
    int slot = tid + i * 256;
    int k = slot >> 4, c4 = (slot & 15) << 2;
    *(float4*)&Wt[k][c4] = *(const float4*)(WT + (size_t)k * 128 + c0 + c4);
  }
  __syncthreads();
  float acc[4][4];
#pragma unroll
  for (int i = 0; i < 4; ++i)
#pragma unroll
    for (int j = 0; j < 4; ++j) acc[i][j] = 0.f;
#pragma unroll 4
  for (int kk = 0; kk < 128; kk += 4) {
    float4 w0 = *(const float4*)&Wt[kk + 0][tx << 2];
    float4 w1 = *(const float4*)&Wt[kk + 1][tx << 2];
    float4 w2 = *(const float4*)&Wt[kk + 2][tx << 2];
    float4 w3 = *(const float4*)&Wt[kk + 3][tx << 2];
#pragma unroll
    for (int i = 0; i < 4; ++i) {
      float4 a = *(const float4*)&As[(ty << 2) + i][kk];
      acc[i][0] += a.x * w0.x + a.y * w1.x + a.z * w2.x + a.w * w3.x;
      acc[i][1] += a.x * w0.y + a.y * w1.y + a.z * w2.y + a.w * w3.y;
      acc[i][2] += a.x * w0.z + a.y * w1.z + a.z * w2.z + a.w * w3.z;
      acc[i][3] += a.x * w0.w + a.y * w1.w + a.z * w2.w + a.w * w3.w;
    }
  }
  __syncthreads();
  float b0v = bias[c0 + (tx << 2) + 0];
  float b1v = bias[c0 + (tx << 2) + 1];
  float b2v = bias[c0 + (tx << 2) + 2];
  float b3v = bias[c0 + (tx << 2) + 3];
  float psum[4] = {0.f, 0.f, 0.f, 0.f}, psq[4] = {0.f, 0.f, 0.f, 0.f};
#pragma unroll
  for (int i = 0; i < 4; ++i) {
    int r = row0 + (ty << 2) + i;
    if (r < M) {
      float4 v;
      v.x = acc[i][0] + b0v; v.y = acc[i][1] + b1v;
      v.z = acc[i][2] + b2v; v.w = acc[i][3] + b3v;
      if (C) *(float4*)(C + (size_t)r * 128 + c0 + (tx << 2)) = v;
      if (h16out) {
        half4 hv;
        hv[0] = (_Float16)v.x; hv[1] = (_Float16)v.y;
        hv[2] = (_Float16)v.z; hv[3] = (_Float16)v.w;
        *(half4*)(h16out + (size_t)r * 128 + c0 + (tx << 2)) = hv;
      }
      psum[0] += v.x; psum[1] += v.y; psum[2] += v.z; psum[3] += v.w;
      psq[0] += v.x * v.x; psq[1] += v.y * v.y; psq[2] += v.z * v.z; psq[3] += v.w * v.w;
    }
  }
  float* red = &As[0][0];
#pragma unroll
  for (int j = 0; j < 4; ++j) {
    red[ty * 68 + (tx << 2) + j] = psum[j];
    red[1088 + ty * 68 + (tx << 2) + j] = psq[j];
  }
  __syncthreads();
  if (tid < 64) {
    float s = 0.f, sq = 0.f;
#pragma unroll
    for (int t = 0; t < 16; ++t) { s += red[t * 68 + tid]; sq += red[1088 + t * 68 + tid]; }
    atomicAdd(&ssum[c0 + tid], s);
    atomicAdd(&ssq[c0 + tid], sq);
  }
}

// ---------------- fused Set2Set v5: fdot2 matvec, fp16 LDS x-cache, step-0 skip -------
__global__ void __launch_bounds__(1024) set2set_kernel(
    const float* __restrict__ x, const int* __restrict__ gptr,
    const float* __restrict__ stats, const float* __restrict__ gamma,
    const float* __restrict__ beta,
    const _Float16* __restrict__ WT0h, const _Float16* __restrict__ WTRh,
    const float* __restrict__ bc0, const float* __restrict__ bcR,
    float* __restrict__ ebuf,
    const float* __restrict__ linW, const float* __restrict__ linb,
    float* __restrict__ out) {
  __shared__ half2v xs[SEG_CAP * 64];  // 114688 B (448 rows, fp16-packed)
  __shared__ float wpart[16][512];     // 32 KB (aliased as rpart in attention)
  __shared__ float gates[512];
  __shared__ half2v inp2[192];         // fp16-packed LSTM input (k-pairs)
  __shared__ float hcs[4][128];
  __shared__ float ccs[4][128];
  __shared__ float qst[256];
  __shared__ float es[ESC];            // 2 KB
  __shared__ float bsc[128], bsh[128];
  __shared__ float wred[16];
  __shared__ float smax_s, ssum_s;
  __shared__ float fred[2][4];

  int g = blockIdx.x, tid = threadIdx.x;
  int w16 = tid >> 6, lane = tid & 63;

  // init
  if (tid < 128) {
    const float invN = 1.0f / (float)NN;
    float mm = stats[tid] * invN;
    float vv = stats[128 + tid] * invN - mm * mm;
    float rs = rsqrtf(vv + 1e-5f);
    float sc = gamma[tid] * rs;
    bsc[tid] = sc;
    bsh[tid] = beta[tid] - mm * sc;
#pragma unroll
    for (int l = 0; l < 4; ++l) { hcs[l][tid] = 0.f; ccs[l][tid] = 0.f; }
  }
  if (tid < 256) qst[tid] = 0.f;
  __syncthreads();

  int s0 = gptr[g], s1 = gptr[g + 1];
  int seg = s1 - s0;
  int ncache = seg < SEG_CAP ? seg : SEG_CAP;
  const float2* x2 = (const float2*)x;
  float sc0 = bsc[2 * lane], sc1 = bsc[2 * lane + 1];
  float sh0 = bsh[2 * lane], sh1 = bsh[2 * lane + 1];
  // stage segment into LDS once (BN4-transformed, fp16-packed); one row per wave
  for (int n = w16; n < ncache; n += 16) {
    float2 v = x2[(size_t)(s0 + n) * 64 + lane];
    half2v h;
    h[0] = (_Float16)fmaxf(fmaf(v.x, sc0, sh0), 0.f);
    h[1] = (_Float16)fmaxf(fmaf(v.y, sc1, sh1), 0.f);
    xs[n * 64 + lane] = h;
  }
  __syncthreads();

  int s_ = tid >> 6, cg = tid & 63;  // matvec: K-slice (16), col-group (8 cols)

  for (int step = 0; step < 4; ++step) {
    // ---- 4 stacked LSTM cells ----
    for (int cell = 0; cell < 4; ++cell) {
      const _Float16* WTh; const float* bias; int KP2;
      if (cell == 0) {
        WTh = WT0h; bias = bc0; KP2 = 12;  // K=384 -> 192 k2-pairs, 12 per slice
        if (tid < 192) {
          int k = tid << 1;
          float va, vb;
          if (k < 256) { va = qst[k]; vb = qst[k + 1]; }
          else { va = hcs[0][k - 256]; vb = hcs[0][k - 255]; }
          half2v h; h[0] = (_Float16)va; h[1] = (_Float16)vb;
          inp2[tid] = h;
        }
      } else {
        WTh = WTRh + (size_t)(cell - 1) * 131072;
        bias = bcR + (cell - 1) * 512; KP2 = 8;  // K=256 -> 128 pairs, 8 per slice
        if (tid < 128) {
          int k = tid << 1;
          float va, vb;
          if (k < 128) { va = hcs[cell - 1][k]; vb = hcs[cell - 1][k + 1]; }
          else { va = hcs[cell][k - 128]; vb = hcs[cell][k - 127]; }
          half2v h; h[0] = (_Float16)va; h[1] = (_Float16)vb;
          inp2[tid] = h;
        }
      }
      __syncthreads();
      if (step == 0 && cell == 0) {
        // all inputs are exactly zero at step 0 -> gates = bias (skip matvec entirely)
        if (tid < 512) gates[tid] = bias[tid];
        __syncthreads();
      } else {
        int se = (s_ + g) & 15;  // rotate slice start per block
        int k20 = se * KP2;
        float a0 = 0.f, a1 = 0.f, a2 = 0.f, a3 = 0.f;
        float a4 = 0.f, a5 = 0.f, a6 = 0.f, a7 = 0.f;
        // step 0, cells>=1: old-h half (k>=128) is zero -> only slices se<8 contribute
        if (step != 0 || se < 8) {
          const char* wb = (const char*)WTh + (size_t)k20 * 2048 + (cg << 5);
#pragma unroll 4
          for (int k2 = 0; k2 < KP2; ++k2) {
            uint4 wa = *(const uint4*)(wb + (size_t)k2 * 2048);
            uint4 wc = *(const uint4*)(wb + (size_t)k2 * 2048 + 16);
            half2v i2 = inp2[k20 + k2];
            a0 = fdot2f(i2, __builtin_bit_cast(half2v, wa.x), a0);
            a1 = fdot2f(i2, __builtin_bit_cast(half2v, wa.y), a1);
            a2 = fdot2f(i2, __builtin_bit_cast(half2v, wa.z), a2);
            a3 = fdot2f(i2, __builtin_bit_cast(half2v, wa.w), a3);
            a4 = fdot2f(i2, __builtin_bit_cast(half2v, wc.x), a4);
            a5 = fdot2f(i2, __builtin_bit_cast(half2v, wc.y), a5);
            a6 = fdot2f(i2, __builtin_bit_cast(half2v, wc.z), a6);
            a7 = fdot2f(i2, __builtin_bit_cast(half2v, wc.w), a7);
          }
        }
        *(float4*)&wpart[s_][cg << 3] = make_float4(a0, a1, a2, a3);
        *(float4*)(&wpart[s_][cg << 3] + 4) = make_float4(a4, a5, a6, a7);
        __syncthreads();
        if (tid < 512) {
          float acc = bias[tid];
#pragma unroll
          for (int s = 0; s < 16; ++s) acc += wpart[s][tid];
          gates[tid] = acc;
        }
        __syncthreads();
      }
      if (tid < 128) {
        int j = tid;
        float gi = gates[4 * j + 0];
        float gf = gates[4 * j + 1];
        float gc = gates[4 * j + 2];
        float go = gates[4 * j + 3];
        float cp = ccs[cell][j];
        float si = fsigm(gi);
        float sf = fsigm(gf);
        float so = fsigm(go);
        float cn = sf * cp + si * ftanh(gc);
        ccs[cell][j] = cn;
        hcs[cell][j] = so * ftanh(cn);
      }
      __syncthreads();
    }
    // ---- attention, q = new h[3]; x from fp16 LDS cache ----
    float* rpart = &wpart[0][0];  // alias: time-disjoint with matvec
    float qx = hcs[3][2 * lane], qy = hcs[3][2 * lane + 1];
    half2v q2; q2[0] = (_Float16)qx; q2[1] = (_Float16)qy;
    // pass 1: e + max
    float wmax = -3.0e38f;
    for (int n = w16; n < seg; n += 16) {
      float e;
      if (n < ncache) {
        e = fdot2f(xs[n * 64 + lane], q2, 0.f);
      } else {
        float2 v = x2[(size_t)(s0 + n) * 64 + lane];
        float vx = fmaxf(fmaf(v.x, sc0, sh0), 0.f);
        float vy = fmaxf(fmaf(v.y, sc1, sh1), 0.f);
        e = vx * qx + vy * qy;
      }
#pragma unroll
      for (int sh = 32; sh; sh >>= 1) e += __shfl_xor(e, sh);
      if (lane == 0) { if (n < ESC) es[n] = e; else ebuf[s0 + n] = e; }
      wmax = fmaxf(wmax, e);
    }
    if (lane == 0) wred[w16] = wmax;
    __syncthreads();
    if (tid == 0) {
      float m = wred[0];
#pragma unroll
      for (int t = 1; t < 16; ++t) m = fmaxf(m, wred[t]);
      smax_s = m;
    }
    __syncthreads();
    float m = smax_s;
    // pass 2: sum exp (cache exp back into es/ebuf for pass 3)
    float loc = 0.f;
    for (int n = tid; n < seg; n += 1024) {
      float e = (n < ESC) ? es[n] : ebuf[s0 + n];
      float ex = __expf(e - m);
      if (n < ESC) es[n] = ex; else ebuf[s0 + n] = ex;
      loc += ex;
    }
#pragma unroll
    for (int sh = 32; sh; sh >>= 1) loc += __shfl_xor(loc, sh);
    __syncthreads();
    if (lane == 0) wred[w16] = loc;
    __syncthreads();
    if (tid == 0) {
      float s = 0.f;
#pragma unroll
      for (int t = 0; t < 16; ++t) s += wred[t];
      ssum_s = s;
    }
    __syncthreads();
    float inv = 1.0f / ssum_s;
    // pass 3: r = sum a*x
    float rx = 0.f, ry = 0.f;
    for (int n = w16; n < seg; n += 16) {
      float ex = (n < ESC) ? es[n] : ebuf[s0 + n];
      float coef = ex * inv;
      float vx, vy;
      if (n < ncache) {
        half2v v2 = xs[n * 64 + lane];
        vx = (float)v2[0]; vy = (float)v2[1];
      } else {
        float2 v = x2[(size_t)(s0 + n) * 64 + lane];
        vx = fmaxf(fmaf(v.x, sc0, sh0), 0.f);
        vy = fmaxf(fmaf(v.y, sc1, sh1), 0.f);
      }
      rx += coef * vx; ry += coef * vy;
    }
    rpart[w16 * 128 + 2 * lane] = rx;
    rpart[w16 * 128 + 2 * lane + 1] = ry;
    __syncthreads();
    if (tid < 128) {
      float r = 0.f;
#pragma unroll
      for (int t = 0; t < 16; ++t) r += rpart[t * 128 + tid];
      qst[tid] = hcs[3][tid];
      qst[128 + tid] = r;
    }
    __syncthreads();
  }
  // ---- final linear ----
  if (tid < 256) {
    float val = qst[tid];
    float p0 = val * linW[tid];
    float p1 = val * linW[256 + tid];
#pragma unroll
    for (int sh = 32; sh; sh >>= 1) { p0 += __shfl_xor(p0, sh); p1 += __shfl_xor(p1, sh); }
    if (lane == 0) { fred[0][w16] = p0; fred[1][w16] = p1; }
  }
  __syncthreads();
  if (tid == 0) {
    out[2 * g + 0] = fred[0][0] + fred[0][1] + fred[0][2] + fred[0][3] + linb[0];
    out[2 * g + 1] = fred[1][0] + fred[1][1] + fred[1][2] + fred[1][3] + linb[1];
  }
}

// ---------------- launch ----------------

extern "C" void kernel_launch(void* const* d_in, const int* in_sizes, int n_in,
                              void* d_out, int out_size, void* d_ws, size_t ws_size,
                              hipStream_t stream) {
  const float* x = (const float*)d_in[0];
  const int* ei = (const int*)d_in[1];
  const int* batch = (const int*)d_in[2];
  const float* gW[4]  = {(const float*)d_in[3],  (const float*)d_in[7],
                         (const float*)d_in[11], (const float*)d_in[15]};
  const float* gb[4]  = {(const float*)d_in[4],  (const float*)d_in[8],
                         (const float*)d_in[12], (const float*)d_in[16]};
  const float* gga[4] = {(const float*)d_in[5],  (const float*)d_in[9],
                         (const float*)d_in[13], (const float*)d_in[17]};
  const float* gbe[4] = {(const float*)d_in[6],  (const float*)d_in[10],
                         (const float*)d_in[14], (const float*)d_in[18]};
  const float* Wih0 = (const float*)d_in[19];
  const float* Whh0 = (const float*)d_in[20];
  const float* b0   = (const float*)d_in[21];
  const float* WihR = (const float*)d_in[22];
  const float* WhhR = (const float*)d_in[23];
  const float* bR   = (const float*)d_in[24];
  const float* linW = (const float*)d_in[25];
  const float* linb = (const float*)d_in[26];
  float* out = (float*)d_out;

  char* base = (char*)d_ws;
  size_t off = 0;
  auto allocf = [&](size_t n) { float* p = (float*)(base + off); off += n * sizeof(float); return p; };
  float* xa    = allocf(6400000);
  float* xb    = allocf(6400000);
  float* ginWT = allocf(65536);
  _Float16* WT0h = (_Float16*)(base + off); off += 196608 * 2;
  _Float16* WTRh = (_Float16*)(base + off); off += 393216 * 2;
  _Float16* x16a = (_Float16*)(base + off); off += 6400000 * 2;
  _Float16* x16b = (_Float16*)(base + off); off += 6400000 * 2;
  float* bc0   = allocf(512);
  float* bcR   = allocf(1536);
  float* ebuf  = allocf(50000);
  // ---- zero region: stats only (1024 floats = 256 float4) ----
  float* stats = allocf(1024);     // 4 x (sum128|sq128)
  // ---- ints (all fully written before read; no zeroing needed) ----
  int* row_start = (int*)(base + off); off += 50004 * 4;
  int* gptr = (int*)(base + off); off += 260 * 4;
  int* csr = (int*)(base + off); off += 800000 * 4;
  int* packed = (int*)(base + off); off += 800000 * 4;
  int* partial = (int*)(base + off); off += NBIN * NBLK * 4;
  int* block_base = (int*)(base + off); off += NBIN * NBLK * 4;
  int* total = (int*)(base + off); off += 256 * 4;
  int* coarse_base = (int*)(base + off); off += 260 * 4;
  (void)ws_size; (void)in_sizes; (void)n_in; (void)out_size;

  // merged prep: zero | gptr | hist | weight repack | x->fp16  (grid 2961+6250)
  prep_all_kernel<<<9211, 256, 0, stream>>>(batch, ei, gW[0], gW[1], gW[2], gW[3],
                                            Wih0, Whh0, WihR, WhhR, b0, bR, x,
                                            stats, gptr, partial, ginWT, WT0h, WTRh,
                                            bc0, bcR, x16a);
  scan_partials_kernel<<<NBIN, 256, 0, stream>>>(partial, block_base, total);
  scan_totals_kernel<<<1, 256, 0, stream>>>(total, coarse_base);
  bucket_scatter_kernel<<<NBLK, 256, 0, stream>>>(ei, coarse_base, block_base, packed);
  csr_finalize_kernel<<<NBIN, 256, 0, stream>>>(packed, coarse_base, row_start, csr);

  // GIN layer 1 (gather reads fp16 x)
  gin_agg_kernel<false><<<12500, 256, 0, stream>>>(x16a, row_start, csr,
                                                   nullptr, nullptr, nullptr, xb);
  gemm_gin_kernel<false><<<1564, 256, 0, stream>>>(xb, ginWT + 0 * 16384, gb[0],
                                                   nullptr, nullptr, nullptr,
                                                   xa, nullptr, stats + 0, stats + 128, NN);
  // gemm2: only fp16 output needed (sole consumer is gather2)
  gemm_gin_kernel<true><<<1564, 256, 0, stream>>>(xa, ginWT + 1 * 16384, gb[1],
                                                  stats + 0, gga[0], gbe[0],
                                                  nullptr, x16b, stats + 256, stats + 384, NN);
  // GIN layer 2 (BN2 finalize+affine+relu fused into the fp16 gather)
  gin_agg_kernel<true><<<12500, 256, 0, stream>>>(x16b, row_start, csr,
                                                  stats + 256, gga[1], gbe[1], xa);
  gemm_gin_kernel<false><<<1564, 256, 0, stream>>>(xa, ginWT + 2 * 16384, gb[2],
                                                   nullptr, nullptr, nullptr,
                                                   xb, nullptr, stats + 512, stats + 640, NN);
  gemm_gin_kernel<true><<<1564, 256, 0, stream>>>(xb, ginWT + 3 * 16384, gb[3],
                                                  stats + 512, gga[2], gbe[2],
                                                  xa, nullptr, stats + 768, stats + 896, NN);
  // xa holds pre-BN4 features; BN4 fused into set2set x staging

  // fused Set2Set v5: fdot2 fp16 matvec, fp16 LDS x-cache, step-0 algebraic skip
  set2set_kernel<<<256, 1024, 0, stream>>>(xa, gptr, stats + 768, gga[3], gbe[3],
                                           WT0h, WTRh, bc0, bcR, ebuf, linW, linb, out);
}

// Round 2
// 442.859 us; speedup vs baseline: 1.1656x; 1.1190x over previous
//
#include <hip/hip_runtime.h>
#include <math.h>

#define NN 50000
#define EE 800000
#define BBG 256
#define HHC 128
#define SEG_CAP 448  // LDS x-cache rows per graph (fp16 packed)
#define ESC 512      // per-graph e-cache entries in LDS
#define NBIN 196     // coarse bins of 256 nodes
#define NBLK 196     // blocks in K1/K3 (4096 edges each)

typedef _Float16 half8 __attribute__((ext_vector_type(8)));
typedef _Float16 half4 __attribute__((ext_vector_type(4)));
typedef _Float16 half2v __attribute__((ext_vector_type(2)));
typedef float f32x4 __attribute__((ext_vector_type(4)));

#if defined(__has_builtin)
#if __has_builtin(__builtin_amdgcn_fdot2)
#define USE_FDOT2 1
#endif
#endif

__device__ __forceinline__ float fdot2f(half2v a, half2v b, float c) {
#ifdef USE_FDOT2
  return __builtin_amdgcn_fdot2(a, b, c, false);
#else
  return fmaf((float)a[0], (float)b[0], fmaf((float)a[1], (float)b[1], c));
#endif
}

__device__ __forceinline__ float fsigm(float x) {
  return __builtin_amdgcn_rcpf(1.f + __expf(-x));
}
__device__ __forceinline__ float ftanh(float x) {
  return 1.f - 2.f * __builtin_amdgcn_rcpf(1.f + __expf(2.f * x));
}

__device__ __forceinline__ float4 aff4(float4 v, float4 sc, float4 sh) {
  v.x = fmaxf(fmaf(v.x, sc.x, sh.x), 0.f);
  v.y = fmaxf(fmaf(v.y, sc.y, sh.y), 0.f);
  v.z = fmaxf(fmaf(v.z, sc.z, sh.z), 0.f);
  v.w = fmaxf(fmaf(v.w, sc.w, sh.w), 0.f);
  return v;
}
__device__ __forceinline__ void add4(float4& a, float4 b) {
  a.x += b.x; a.y += b.y; a.z += b.z; a.w += b.w;
}
__device__ __forceinline__ float4 cvt4(half4 h) {
  return make_float4((float)h[0], (float)h[1], (float)h[2], (float)h[3]);
}

// ---------------- merged prep: zero | gptr | coarse hist | weight repack | x->fp16 ----
// GIN weights -> fp16 natural layout W[o][k] (k contiguous) for MFMA B-fragments.
// LSTM weights -> fp16, gate-interleaved, k-pair-interleaved for fdot2.
__global__ __launch_bounds__(256) void prep_all_kernel(
    const int* __restrict__ batch,
    const int* __restrict__ ei,
    const float* __restrict__ W0, const float* __restrict__ W1,
    const float* __restrict__ W2, const float* __restrict__ W3,
    const float* __restrict__ Wih0, const float* __restrict__ Whh0,
    const float* __restrict__ WihR, const float* __restrict__ WhhR,
    const float* __restrict__ b0, const float* __restrict__ bR,
    const float* __restrict__ xsrc,
    float* __restrict__ stats, int* __restrict__ gptr, int* __restrict__ partial,
    _Float16* __restrict__ ginWh, _Float16* __restrict__ WT0h,
    _Float16* __restrict__ WTRh, float* __restrict__ bc0, float* __restrict__ bcR,
    _Float16* __restrict__ x16a) {
  __shared__ int hist[NBIN];
  int blk = blockIdx.x, tid = threadIdx.x;
  if (blk == 0) {
    ((float4*)stats)[tid] = make_float4(0.f, 0.f, 0.f, 0.f);  // 1024 floats
    return;
  }
  if (blk <= 196) {  // gptr boundaries
    int i = (blk - 1) * 256 + tid;
    if (i >= NN) return;
    int b = batch[i];
    int prev = (i == 0) ? -1 : batch[i - 1];
    for (int g = prev + 1; g <= b; ++g) gptr[g] = i;
    if (i == NN - 1) {
      for (int g = b + 1; g <= BBG; ++g) gptr[g] = NN;
    }
    return;
  }
  if (blk <= 392) {  // coarse hist
    int b = blk - 197;
    if (tid < NBIN) hist[tid] = 0;
    __syncthreads();
    const int4* dst4 = (const int4*)(ei + EE);
#pragma unroll
    for (int c = 0; c < 4; ++c) {
      int idx = b * 1024 + c * 256 + tid;
      if (idx < EE / 4) {
        int4 d = dst4[idx];
        atomicAdd(&hist[d.x >> 8], 1);
        atomicAdd(&hist[d.y >> 8], 1);
        atomicAdd(&hist[d.z >> 8], 1);
        atomicAdd(&hist[d.w >> 8], 1);
      }
    }
    __syncthreads();
    if (tid < NBIN) partial[tid * NBLK + b] = hist[tid];
    return;
  }
  if (blk >= 2961) {  // x -> fp16 (6250 blocks x 256 = 1,600,000 float4 groups)
    int i = (blk - 2961) * 256 + tid;
    float4 v = ((const float4*)xsrc)[i];
    half4 h;
    h[0] = (_Float16)v.x; h[1] = (_Float16)v.y;
    h[2] = (_Float16)v.z; h[3] = (_Float16)v.w;
    ((half4*)x16a)[i] = h;
    return;
  }
  // weight prep
  int idx = (blk - 393) * 256 + tid;  // [0, 657408)
  if (idx < 65536) {
    int m = idx >> 14;
    int r = idx & 16383;
    const float* W = (m == 0) ? W0 : (m == 1) ? W1 : (m == 2) ? W2 : W3;
    ginWh[idx] = (_Float16)W[r];  // natural [o][k], k contiguous
  } else if (idx < 262144) {
    int t = idx - 65536;
    int k = t >> 9, op = t & 511;
    int j = op >> 2, g = op & 3;
    int row = g * 128 + j;
    float v = (k < 256) ? Wih0[row * 256 + k] : Whh0[row * 128 + (k - 256)];
    WT0h[((k >> 1) << 10) | (op << 1) | (k & 1)] = (_Float16)v;
  } else if (idx < 655360) {
    int t = idx - 262144;
    int l = t >> 17;
    int rem = t & 131071;
    int k = rem >> 9, op = rem & 511;
    int j = op >> 2, g = op & 3;
    int row = g * 128 + j;
    float v = (k < 128) ? WihR[((size_t)l * 512 + row) * 128 + k]
                        : WhhR[((size_t)l * 512 + row) * 128 + (k - 128)];
    WTRh[((size_t)l << 17) | ((k >> 1) << 10) | (op << 1) | (k & 1)] = (_Float16)v;
  } else {
    int t = idx - 655360;
    if (t < 512) {
      bc0[t] = b0[(t & 3) * 128 + (t >> 2)];
    } else {
      int u = t - 512;
      int l = u >> 9, op = u & 511;
      bcR[u] = bR[l * 512 + (op & 3) * 128 + (op >> 2)];
    }
  }
}

// ---- atomic-free CSR build (two-level counting sort) ----

__global__ void scan_partials_kernel(const int* __restrict__ partial,
                                     int* __restrict__ block_base, int* __restrict__ total) {
  __shared__ int buf[256];
  int bin = blockIdx.x, tid = threadIdx.x;
  int v = (tid < NBLK) ? partial[bin * NBLK + tid] : 0;
  buf[tid] = v;
  __syncthreads();
  for (int off = 1; off < 256; off <<= 1) {
    int t = (tid >= off) ? buf[tid - off] : 0;
    __syncthreads();
    buf[tid] += t;
    __syncthreads();
  }
  if (tid < NBLK) block_base[bin * NBLK + tid] = buf[tid] - v;
  if (tid == 255) total[bin] = buf[255];
}

__global__ void scan_totals_kernel(const int* __restrict__ total, int* __restrict__ coarse_base) {
  __shared__ int buf[256];
  int tid = threadIdx.x;
  int v = (tid < NBIN) ? total[tid] : 0;
  buf[tid] = v;
  __syncthreads();
  for (int off = 1; off < 256; off <<= 1) {
    int t = (tid >= off) ? buf[tid - off] : 0;
    __syncthreads();
    buf[tid] += t;
    __syncthreads();
  }
  if (tid < NBIN) coarse_base[tid] = buf[tid] - v;
  if (tid == 255) coarse_base[NBIN] = buf[255];
}

__global__ __launch_bounds__(256) void bucket_scatter_kernel(const int* __restrict__ ei,
                                                             const int* __restrict__ coarse_base,
                                                             const int* __restrict__ block_base,
                                                             int* __restrict__ packed) {
  __shared__ int cursor[NBIN];
  int tid = threadIdx.x, b = blockIdx.x;
  if (tid < NBIN) cursor[tid] = coarse_base[tid] + block_base[tid * NBLK + b];
  __syncthreads();
  const int4* src4 = (const int4*)ei;
  const int4* dst4 = (const int4*)(ei + EE);
#pragma unroll
  for (int c = 0; c < 4; ++c) {
    int idx = b * 1024 + c * 256 + tid;
    if (idx < EE / 4) {
      int4 s = src4[idx];
      int4 d = dst4[idx];
      int p;
      p = atomicAdd(&cursor[d.x >> 8], 1); packed[p] = (s.x << 8) | (d.x & 255);
      p = atomicAdd(&cursor[d.y >> 8], 1); packed[p] = (s.y << 8) | (d.y & 255);
      p = atomicAdd(&cursor[d.z >> 8], 1); packed[p] = (s.z << 8) | (d.z & 255);
      p = atomicAdd(&cursor[d.w >> 8], 1); packed[p] = (s.w << 8) | (d.w & 255);
    }
  }
}

__global__ __launch_bounds__(256) void csr_finalize_kernel(const int* __restrict__ packed,
                                                           const int* __restrict__ coarse_base,
                                                           int* __restrict__ row_start,
                                                           int* __restrict__ csr) {
  __shared__ int fh[256];
  __shared__ int fb[256];
  int bin = blockIdx.x, tid = threadIdx.x;
  int e0 = coarse_base[bin], e1 = coarse_base[bin + 1];
  fh[tid] = 0;
  __syncthreads();
  for (int e = e0 + tid; e < e1; e += 256) atomicAdd(&fh[packed[e] & 255], 1);
  __syncthreads();
  int v = fh[tid];
  fb[tid] = v;
  __syncthreads();
  for (int off = 1; off < 256; off <<= 1) {
    int t = (tid >= off) ? fb[tid - off] : 0;
    __syncthreads();
    fb[tid] += t;
    __syncthreads();
  }
  int excl = fb[tid] - v;
  int node = bin * 256 + tid;
  if (node < NN) row_start[node] = e0 + excl;
  if (bin == NBIN - 1 && tid == 0) row_start[NN] = EE;
  __syncthreads();
  fb[tid] = excl;  // cursor
  __syncthreads();
  for (int e = e0 + tid; e < e1; e += 256) {
    int p = packed[e];
    int pos = atomicAdd(&fb[p & 255], 1);
    csr[e0 + pos] = p >> 8;
  }
}

// ---------------- GIN ----------------

// one wave per node; each 32-lane half loads a full 256B fp16 row as half4/lane.
template <bool AFF>
__global__ __launch_bounds__(256) void gin_agg_kernel(
    const _Float16* __restrict__ x16, const int* __restrict__ row_start,
    const int* __restrict__ csr,
    const float* __restrict__ stats, const float* __restrict__ gamma,
    const float* __restrict__ beta, float* __restrict__ outp) {
  __shared__ float sc_s[128], sh_s[128];
  if (AFF) {
    int t = threadIdx.x;
    if (t < 128) {
      const float invN = 1.0f / (float)NN;
      float mm = stats[t] * invN;
      float vv = stats[128 + t] * invN - mm * mm;
      float rs = rsqrtf(vv + 1e-5f);
      float sc = gamma[t] * rs;
      sc_s[t] = sc;
      sh_s[t] = beta[t] - mm * sc;
    }
    __syncthreads();
  }
  int node = blockIdx.x * 4 + (threadIdx.x >> 6);  // exact: 12500*4 = 50000
  int lane = threadIdx.x & 63;
  int half = lane >> 5, ln = lane & 31;
  const half4* xh = (const half4*)x16;  // row = node*32 half4s
  float4 sc4 = make_float4(0.f, 0.f, 0.f, 0.f), sh4 = sc4;
  if (AFF) {
    sc4 = *(const float4*)&sc_s[4 * ln];
    sh4 = *(const float4*)&sh_s[4 * ln];
  }
  int s0 = row_start[node], s1 = row_start[node + 1];
  float4 self = cvt4(xh[(size_t)node * 32 + ln]);
  if (AFF) self = aff4(self, sc4, sh4);
  float4 c0 = make_float4(0.f, 0.f, 0.f, 0.f), c1 = c0, c2 = c0, c3 = c0;
  int cnt = s1 - s0;
  int mainEnd = s0 + (cnt & ~15);
  for (int j = s0; j < mainEnd; j += 16) {
    int i0 = csr[j + half + 0];
    int i1 = csr[j + half + 2];
    int i2 = csr[j + half + 4];
    int i3 = csr[j + half + 6];
    int i4 = csr[j + half + 8];
    int i5 = csr[j + half + 10];
    int i6 = csr[j + half + 12];
    int i7 = csr[j + half + 14];
    half4 h0 = xh[(size_t)i0 * 32 + ln];
    half4 h1 = xh[(size_t)i1 * 32 + ln];
    half4 h2 = xh[(size_t)i2 * 32 + ln];
    half4 h3 = xh[(size_t)i3 * 32 + ln];
    half4 h4 = xh[(size_t)i4 * 32 + ln];
    half4 h5 = xh[(size_t)i5 * 32 + ln];
    half4 h6 = xh[(size_t)i6 * 32 + ln];
    half4 h7 = xh[(size_t)i7 * 32 + ln];
    float4 v0 = cvt4(h0);
    float4 v1 = cvt4(h1);
    float4 v2 = cvt4(h2);
    float4 v3 = cvt4(h3);
    float4 v4 = cvt4(h4);
    float4 v5 = cvt4(h5);
    float4 v6 = cvt4(h6);
    float4 v7 = cvt4(h7);
    if (AFF) {
      v0 = aff4(v0, sc4, sh4); v1 = aff4(v1, sc4, sh4);
      v2 = aff4(v2, sc4, sh4); v3 = aff4(v3, sc4, sh4);
      v4 = aff4(v4, sc4, sh4); v5 = aff4(v5, sc4, sh4);
      v6 = aff4(v6, sc4, sh4); v7 = aff4(v7, sc4, sh4);
    }
    add4(c0, v0); add4(c1, v1); add4(c2, v2); add4(c3, v3);
    add4(c0, v4); add4(c1, v5); add4(c2, v6); add4(c3, v7);
  }
  for (int j = mainEnd + half; j < s1; j += 2) {
    int i = csr[j];
    float4 v = cvt4(xh[(size_t)i * 32 + ln]);
    if (AFF) v = aff4(v, sc4, sh4);
    add4(c0, v);
  }
  float4 t;
  t.x = (c0.x + c1.x) + (c2.x + c3.x);
  t.y = (c0.y + c1.y) + (c2.y + c3.y);
  t.z = (c0.z + c1.z) + (c2.z + c3.z);
  t.w = (c0.w + c1.w) + (c2.w + c3.w);
  t.x += __shfl_xor(t.x, 32);
  t.y += __shfl_xor(t.y, 32);
  t.z += __shfl_xor(t.z, 32);
  t.w += __shfl_xor(t.w, 32);
  t.x += self.x; t.y += self.y; t.z += self.z; t.w += self.w;
  if (half == 0) ((float4*)outp)[(size_t)node * 32 + ln] = t;
}

// ---------------- MFMA GIN GEMM ----------------
// C = f(A) @ W^T + b via v_mfma_f32_16x16x32_f16.
// 4 waves/block; wave w owns cols [32w, 32w+32). B-frags (Wh, natural [o][k]
// layout, k contiguous) loaded once per block into regs. Block grid-strides
// 16-row M tiles (NN = 16*3125 exactly). BN+relu fused on A load; bias +
// fp32/fp16 stores + per-column stats fused in epilogue.
// Fragment layouts (16x16x32): A: row=lane&15, k=(lane>>4)*8+j.
//                              B: col=lane&15, k=(lane>>4)*8+j.
//                              C/D: col=lane&15, row=(lane>>4)*4+reg.
template <bool BN, bool AH>
__global__ __launch_bounds__(256) void gemm_gin_mfma_kernel(
    const float* __restrict__ A, const _Float16* __restrict__ A16,
    const _Float16* __restrict__ Wh,
    const float* __restrict__ bias,
    const float* __restrict__ stats, const float* __restrict__ gamma,
    const float* __restrict__ beta,
    float* __restrict__ C, _Float16* __restrict__ h16out,
    float* __restrict__ ssum, float* __restrict__ ssq) {
  __shared__ float bsc_s[128], bsh_s[128];
  int tid = threadIdx.x;
  if (BN) {
    if (tid < 128) {
      const float invN = 1.0f / (float)NN;
      float mm = stats[tid] * invN;
      float vv = stats[128 + tid] * invN - mm * mm;
      float rs = rsqrtf(vv + 1e-5f);
      float sc = gamma[tid] * rs;
      bsc_s[tid] = sc;
      bsh_s[tid] = beta[tid] - mm * sc;
    }
    __syncthreads();
  }
  int w = tid >> 6, l = tid & 63;
  int lr = l & 15, lg = l >> 4;
  int cb = w * 32;
  half8 bf0[4], bf1[4];
#pragma unroll
  for (int ks = 0; ks < 4; ++ks) {
    int k = ks * 32 + lg * 8;
    bf0[ks] = *(const half8*)(Wh + (size_t)(cb + lr) * 128 + k);
    bf1[ks] = *(const half8*)(Wh + (size_t)(cb + 16 + lr) * 128 + k);
  }
  float bv0 = bias[cb + lr], bv1 = bias[cb + 16 + lr];
  float ps0 = 0.f, pq0 = 0.f, ps1 = 0.f, pq1 = 0.f;
  int t0 = blockIdx.x * 4;
  for (int t = 0; t < 4; ++t) {
    int tile = t0 + t;
    if (tile >= 3125) break;
    int r = tile * 16 + lr;
    half8 af[4];
#pragma unroll
    for (int ks = 0; ks < 4; ++ks) {
      int k0 = ks * 32 + lg * 8;
      if constexpr (AH) {
        half8 ah = *(const half8*)(A16 + (size_t)r * 128 + k0);
        if constexpr (BN) {
          float4 s0 = *(const float4*)&bsc_s[k0];
          float4 s1 = *(const float4*)&bsc_s[k0 + 4];
          float4 h0 = *(const float4*)&bsh_s[k0];
          float4 h1 = *(const float4*)&bsh_s[k0 + 4];
          half8 o;
          o[0] = (_Float16)fmaxf(fmaf((float)ah[0], s0.x, h0.x), 0.f);
          o[1] = (_Float16)fmaxf(fmaf((float)ah[1], s0.y, h0.y), 0.f);
          o[2] = (_Float16)fmaxf(fmaf((float)ah[2], s0.z, h0.z), 0.f);
          o[3] = (_Float16)fmaxf(fmaf((float)ah[3], s0.w, h0.w), 0.f);
          o[4] = (_Float16)fmaxf(fmaf((float)ah[4], s1.x, h1.x), 0.f);
          o[5] = (_Float16)fmaxf(fmaf((float)ah[5], s1.y, h1.y), 0.f);
          o[6] = (_Float16)fmaxf(fmaf((float)ah[6], s1.z, h1.z), 0.f);
          o[7] = (_Float16)fmaxf(fmaf((float)ah[7], s1.w, h1.w), 0.f);
          af[ks] = o;
        } else {
          af[ks] = ah;
        }
      } else {
        float4 a0 = *(const float4*)(A + (size_t)r * 128 + k0);
        float4 a1 = *(const float4*)(A + (size_t)r * 128 + k0 + 4);
        if constexpr (BN) {
          float4 s0 = *(const float4*)&bsc_s[k0];
          float4 s1 = *(const float4*)&bsc_s[k0 + 4];
          float4 h0 = *(const float4*)&bsh_s[k0];
          float4 h1 = *(const float4*)&bsh_s[k0 + 4];
          a0 = aff4(a0, s0, h0);
          a1 = aff4(a1, s1, h1);
        }
        half8 o;
        o[0] = (_Float16)a0.x; o[1] = (_Float16)a0.y;
        o[2] = (_Float16)a0.z; o[3] = (_Float16)a0.w;
        o[4] = (_Float16)a1.x; o[5] = (_Float16)a1.y;
        o[6] = (_Float16)a1.z; o[7] = (_Float16)a1.w;
        af[ks] = o;
      }
    }
    f32x4 acc0 = {0.f, 0.f, 0.f, 0.f};
    f32x4 acc1 = {0.f, 0.f, 0.f, 0.f};
#pragma unroll
    for (int ks = 0; ks < 4; ++ks) {
      acc0 = __builtin_amdgcn_mfma_f32_16x16x32_f16(af[ks], bf0[ks], acc0, 0, 0, 0);
      acc1 = __builtin_amdgcn_mfma_f32_16x16x32_f16(af[ks], bf1[ks], acc1, 0, 0, 0);
    }
#pragma unroll
    for (int i = 0; i < 4; ++i) {
      int rr = tile * 16 + lg * 4 + i;
      float v0 = acc0[i] + bv0;
      float v1 = acc1[i] + bv1;
      if (C) {
        C[(size_t)rr * 128 + cb + lr] = v0;
        C[(size_t)rr * 128 + cb + 16 + lr] = v1;
      }
      if (h16out) {
        h16out[(size_t)rr * 128 + cb + lr] = (_Float16)v0;
        h16out[(size_t)rr * 128 + cb + 16 + lr] = (_Float16)v1;
      }
      ps0 += v0; pq0 += v0 * v0;
      ps1 += v1; pq1 += v1 * v1;
    }
  }
  // reduce per-column partials across the 4 k-groups (lanes l, l^16, l^32, l^48)
  ps0 += __shfl_xor(ps0, 16); ps0 += __shfl_xor(ps0, 32);
  pq0 += __shfl_xor(pq0, 16); pq0 += __shfl_xor(pq0, 32);
  ps1 += __shfl_xor(ps1, 16); ps1 += __shfl_xor(ps1, 32);
  pq1 += __shfl_xor(pq1, 16); pq1 += __shfl_xor(pq1, 32);
  if (lg == 0) {
    atomicAdd(&ssum[cb + lr], ps0);
    atomicAdd(&ssq[cb + lr], pq0);
    atomicAdd(&ssum[cb + 16 + lr], ps1);
    atomicAdd(&ssq[cb + 16 + lr], pq1);
  }
}

// ---------------- fused Set2Set v5: fdot2 matvec, fp16 LDS x-cache, step-0 skip -------
__global__ void __launch_bounds__(1024) set2set_kernel(
    const float* __restrict__ x, const int* __restrict__ gptr,
    const float* __restrict__ stats, const float* __restrict__ gamma,
    const float* __restrict__ beta,
    const _Float16* __restrict__ WT0h, const _Float16* __restrict__ WTRh,
    const float* __restrict__ bc0, const float* __restrict__ bcR,
    float* __restrict__ ebuf,
    const float* __restrict__ linW, const float* __restrict__ linb,
    float* __restrict__ out) {
  __shared__ half2v xs[SEG_CAP * 64];  // 114688 B (448 rows, fp16-packed)
  __shared__ float wpart[16][512];     // 32 KB (aliased as rpart in attention)
  __shared__ float gates[512];
  __shared__ half2v inp2[192];         // fp16-packed LSTM input (k-pairs)
  __shared__ float hcs[4][128];
  __shared__ float ccs[4][128];
  __shared__ float qst[256];
  __shared__ float es[ESC];            // 2 KB
  __shared__ float bsc[128], bsh[128];
  __shared__ float wred[16];
  __shared__ float smax_s, ssum_s;
  __shared__ float fred[2][4];

  int g = blockIdx.x, tid = threadIdx.x;
  int w16 = tid >> 6, lane = tid & 63;

  // init
  if (tid < 128) {
    const float invN = 1.0f / (float)NN;
    float mm = stats[tid] * invN;
    float vv = stats[128 + tid] * invN - mm * mm;
    float rs = rsqrtf(vv + 1e-5f);
    float sc = gamma[tid] * rs;
    bsc[tid] = sc;
    bsh[tid] = beta[tid] - mm * sc;
#pragma unroll
    for (int l = 0; l < 4; ++l) { hcs[l][tid] = 0.f; ccs[l][tid] = 0.f; }
  }
  if (tid < 256) qst[tid] = 0.f;
  __syncthreads();

  int s0 = gptr[g], s1 = gptr[g + 1];
  int seg = s1 - s0;
  int ncache = seg < SEG_CAP ? seg : SEG_CAP;
  const float2* x2 = (const float2*)x;
  float sc0 = bsc[2 * lane], sc1 = bsc[2 * lane + 1];
  float sh0 = bsh[2 * lane], sh1 = bsh[2 * lane + 1];
  // stage segment into LDS once (BN4-transformed, fp16-packed); one row per wave
  for (int n = w16; n < ncache; n += 16) {
    float2 v = x2[(size_t)(s0 + n) * 64 + lane];
    half2v h;
    h[0] = (_Float16)fmaxf(fmaf(v.x, sc0, sh0), 0.f);
    h[1] = (_Float16)fmaxf(fmaf(v.y, sc1, sh1), 0.f);
    xs[n * 64 + lane] = h;
  }
  __syncthreads();

  int s_ = tid >> 6, cg = tid & 63;  // matvec: K-slice (16), col-group (8 cols)

  for (int step = 0; step < 4; ++step) {
    // ---- 4 stacked LSTM cells ----
    for (int cell = 0; cell < 4; ++cell) {
      const _Float16* WTh; const float* bias; int KP2;
      if (cell == 0) {
        WTh = WT0h; bias = bc0; KP2 = 12;  // K=384 -> 192 k2-pairs, 12 per slice
        if (tid < 192) {
          int k = tid << 1;
          float va, vb;
          if (k < 256) { va = qst[k]; vb = qst[k + 1]; }
          else { va = hcs[0][k - 256]; vb = hcs[0][k - 255]; }
          half2v h; h[0] = (_Float16)va; h[1] = (_Float16)vb;
          inp2[tid] = h;
        }
      } else {
        WTh = WTRh + (size_t)(cell - 1) * 131072;
        bias = bcR + (cell - 1) * 512; KP2 = 8;  // K=256 -> 128 pairs, 8 per slice
        if (tid < 128) {
          int k = tid << 1;
          float va, vb;
          if (k < 128) { va = hcs[cell - 1][k]; vb = hcs[cell - 1][k + 1]; }
          else { va = hcs[cell][k - 128]; vb = hcs[cell][k - 127]; }
          half2v h; h[0] = (_Float16)va; h[1] = (_Float16)vb;
          inp2[tid] = h;
        }
      }
      __syncthreads();
      if (step == 0 && cell == 0) {
        // all inputs are exactly zero at step 0 -> gates = bias (skip matvec entirely)
        if (tid < 512) gates[tid] = bias[tid];
        __syncthreads();
      } else {
        int se = (s_ + g) & 15;  // rotate slice start per block
        int k20 = se * KP2;
        float a0 = 0.f, a1 = 0.f, a2 = 0.f, a3 = 0.f;
        float a4 = 0.f, a5 = 0.f, a6 = 0.f, a7 = 0.f;
        // step 0, cells>=1: old-h half (k>=128) is zero -> only slices se<8 contribute
        if (step != 0 || se < 8) {
          const char* wb = (const char*)WTh + (size_t)k20 * 2048 + (cg << 5);
#pragma unroll 4
          for (int k2 = 0; k2 < KP2; ++k2) {
            uint4 wa = *(const uint4*)(wb + (size_t)k2 * 2048);
            uint4 wc = *(const uint4*)(wb + (size_t)k2 * 2048 + 16);
            half2v i2 = inp2[k20 + k2];
            a0 = fdot2f(i2, __builtin_bit_cast(half2v, wa.x), a0);
            a1 = fdot2f(i2, __builtin_bit_cast(half2v, wa.y), a1);
            a2 = fdot2f(i2, __builtin_bit_cast(half2v, wa.z), a2);
            a3 = fdot2f(i2, __builtin_bit_cast(half2v, wa.w), a3);
            a4 = fdot2f(i2, __builtin_bit_cast(half2v, wc.x), a4);
            a5 = fdot2f(i2, __builtin_bit_cast(half2v, wc.y), a5);
            a6 = fdot2f(i2, __builtin_bit_cast(half2v, wc.z), a6);
            a7 = fdot2f(i2, __builtin_bit_cast(half2v, wc.w), a7);
          }
        }
        *(float4*)&wpart[s_][cg << 3] = make_float4(a0, a1, a2, a3);
        *(float4*)(&wpart[s_][cg << 3] + 4) = make_float4(a4, a5, a6, a7);
        __syncthreads();
        if (tid < 512) {
          float acc = bias[tid];
#pragma unroll
          for (int s = 0; s < 16; ++s) acc += wpart[s][tid];
          gates[tid] = acc;
        }
        __syncthreads();
      }
      if (tid < 128) {
        int j = tid;
        float gi = gates[4 * j + 0];
        float gf = gates[4 * j + 1];
        float gc = gates[4 * j + 2];
        float go = gates[4 * j + 3];
        float cp = ccs[cell][j];
        float si = fsigm(gi);
        float sf = fsigm(gf);
        float so = fsigm(go);
        float cn = sf * cp + si * ftanh(gc);
        ccs[cell][j] = cn;
        hcs[cell][j] = so * ftanh(cn);
      }
      __syncthreads();
    }
    // ---- attention, q = new h[3]; x from fp16 LDS cache ----
    float* rpart = &wpart[0][0];  // alias: time-disjoint with matvec
    float qx = hcs[3][2 * lane], qy = hcs[3][2 * lane + 1];
    half2v q2; q2[0] = (_Float16)qx; q2[1] = (_Float16)qy;
    // pass 1: e + max
    float wmax = -3.0e38f;
    for (int n = w16; n < seg; n += 16) {
      float e;
      if (n < ncache) {
        e = fdot2f(xs[n * 64 + lane], q2, 0.f);
      } else {
        float2 v = x2[(size_t)(s0 + n) * 64 + lane];
        float vx = fmaxf(fmaf(v.x, sc0, sh0), 0.f);
        float vy = fmaxf(fmaf(v.y, sc1, sh1), 0.f);
        e = vx * qx + vy * qy;
      }
#pragma unroll
      for (int sh = 32; sh; sh >>= 1) e += __shfl_xor(e, sh);
      if (lane == 0) { if (n < ESC) es[n] = e; else ebuf[s0 + n] = e; }
      wmax = fmaxf(wmax, e);
    }
    if (lane == 0) wred[w16] = wmax;
    __syncthreads();
    if (tid == 0) {
      float m = wred[0];
#pragma unroll
      for (int t = 1; t < 16; ++t) m = fmaxf(m, wred[t]);
      smax_s = m;
    }
    __syncthreads();
    float m = smax_s;
    // pass 2: sum exp (cache exp back into es/ebuf for pass 3)
    float loc = 0.f;
    for (int n = tid; n < seg; n += 1024) {
      float e = (n < ESC) ? es[n] : ebuf[s0 + n];
      float ex = __expf(e - m);
      if (n < ESC) es[n] = ex; else ebuf[s0 + n] = ex;
      loc += ex;
    }
#pragma unroll
    for (int sh = 32; sh; sh >>= 1) loc += __shfl_xor(loc, sh);
    __syncthreads();
    if (lane == 0) wred[w16] = loc;
    __syncthreads();
    if (tid == 0) {
      float s = 0.f;
#pragma unroll
      for (int t = 0; t < 16; ++t) s += wred[t];
      ssum_s = s;
    }
    __syncthreads();
    float inv = 1.0f / ssum_s;
    // pass 3: r = sum a*x
    float rx = 0.f, ry = 0.f;
    for (int n = w16; n < seg; n += 16) {
      float ex = (n < ESC) ? es[n] : ebuf[s0 + n];
      float coef = ex * inv;
      float vx, vy;
      if (n < ncache) {
        half2v v2 = xs[n * 64 + lane];
        vx = (float)v2[0]; vy = (float)v2[1];
      } else {
        float2 v = x2[(size_t)(s0 + n) * 64 + lane];
        vx = fmaxf(fmaf(v.x, sc0, sh0), 0.f);
        vy = fmaxf(fmaf(v.y, sc1, sh1), 0.f);
      }
      rx += coef * vx; ry += coef * vy;
    }
    rpart[w16 * 128 + 2 * lane] = rx;
    rpart[w16 * 128 + 2 * lane + 1] = ry;
    __syncthreads();
    if (tid < 128) {
      float r = 0.f;
#pragma unroll
      for (int t = 0; t < 16; ++t) r += rpart[t * 128 + tid];
      qst[tid] = hcs[3][tid];
      qst[128 + tid] = r;
    }
    __syncthreads();
  }
  // ---- final linear ----
  if (tid < 256) {
    float val = qst[tid];
    float p0 = val * linW[tid];
    float p1 = val * linW[256 + tid];
#pragma unroll
    for (int sh = 32; sh; sh >>= 1) { p0 += __shfl_xor(p0, sh); p1 += __shfl_xor(p1, sh); }
    if (lane == 0) { fred[0][w16] = p0; fred[1][w16] = p1; }
  }
  __syncthreads();
  if (tid == 0) {
    out[2 * g + 0] = fred[0][0] + fred[0][1] + fred[0][2] + fred[0][3] + linb[0];
    out[2 * g + 1] = fred[1][0] + fred[1][1] + fred[1][2] + fred[1][3] + linb[1];
  }
}

// ---------------- launch ----------------

extern "C" void kernel_launch(void* const* d_in, const int* in_sizes, int n_in,
                              void* d_out, int out_size, void* d_ws, size_t ws_size,
                              hipStream_t stream) {
  const float* x = (const float*)d_in[0];
  const int* ei = (const int*)d_in[1];
  const int* batch = (const int*)d_in[2];
  const float* gW[4]  = {(const float*)d_in[3],  (const float*)d_in[7],
                         (const float*)d_in[11], (const float*)d_in[15]};
  const float* gb[4]  = {(const float*)d_in[4],  (const float*)d_in[8],
                         (const float*)d_in[12], (const float*)d_in[16]};
  const float* gga[4] = {(const float*)d_in[5],  (const float*)d_in[9],
                         (const float*)d_in[13], (const float*)d_in[17]};
  const float* gbe[4] = {(const float*)d_in[6],  (const float*)d_in[10],
                         (const float*)d_in[14], (const float*)d_in[18]};
  const float* Wih0 = (const float*)d_in[19];
  const float* Whh0 = (const float*)d_in[20];
  const float* b0   = (const float*)d_in[21];
  const float* WihR = (const float*)d_in[22];
  const float* WhhR = (const float*)d_in[23];
  const float* bR   = (const float*)d_in[24];
  const float* linW = (const float*)d_in[25];
  const float* linb = (const float*)d_in[26];
  float* out = (float*)d_out;

  char* base = (char*)d_ws;
  size_t off = 0;
  auto allocf = [&](size_t n) { float* p = (float*)(base + off); off += n * sizeof(float); return p; };
  float* xa    = allocf(6400000);
  float* xb    = allocf(6400000);
  _Float16* ginWh = (_Float16*)(base + off); off += 65536 * 2;
  _Float16* WT0h = (_Float16*)(base + off); off += 196608 * 2;
  _Float16* WTRh = (_Float16*)(base + off); off += 393216 * 2;
  _Float16* x16a = (_Float16*)(base + off); off += 6400000 * 2;
  _Float16* x16b = (_Float16*)(base + off); off += 6400000 * 2;
  float* bc0   = allocf(512);
  float* bcR   = allocf(1536);
  float* ebuf  = allocf(50000);
  // ---- zero region: stats only (1024 floats = 256 float4) ----
  float* stats = allocf(1024);     // 4 x (sum128|sq128)
  // ---- ints (all fully written before read; no zeroing needed) ----
  int* row_start = (int*)(base + off); off += 50004 * 4;
  int* gptr = (int*)(base + off); off += 260 * 4;
  int* csr = (int*)(base + off); off += 800000 * 4;
  int* packed = (int*)(base + off); off += 800000 * 4;
  int* partial = (int*)(base + off); off += NBIN * NBLK * 4;
  int* block_base = (int*)(base + off); off += NBIN * NBLK * 4;
  int* total = (int*)(base + off); off += 256 * 4;
  int* coarse_base = (int*)(base + off); off += 260 * 4;
  (void)ws_size; (void)in_sizes; (void)n_in; (void)out_size;

  // merged prep: zero | gptr | hist | weight repack | x->fp16  (grid 2961+6250)
  prep_all_kernel<<<9211, 256, 0, stream>>>(batch, ei, gW[0], gW[1], gW[2], gW[3],
                                            Wih0, Whh0, WihR, WhhR, b0, bR, x,
                                            stats, gptr, partial, ginWh, WT0h, WTRh,
                                            bc0, bcR, x16a);
  scan_partials_kernel<<<NBIN, 256, 0, stream>>>(partial, block_base, total);
  scan_totals_kernel<<<1, 256, 0, stream>>>(total, coarse_base);
  bucket_scatter_kernel<<<NBLK, 256, 0, stream>>>(ei, coarse_base, block_base, packed);
  csr_finalize_kernel<<<NBIN, 256, 0, stream>>>(packed, coarse_base, row_start, csr);

  // GIN layer 1 (gather reads fp16 x)
  gin_agg_kernel<false><<<12500, 256, 0, stream>>>(x16a, row_start, csr,
                                                   nullptr, nullptr, nullptr, xb);
  // gemm1: raw agg fp32 in, fp16 out only (consumer: gemm2), stats0
  gemm_gin_mfma_kernel<false, false><<<782, 256, 0, stream>>>(
      xb, nullptr, ginWh + 0 * 16384, gb[0],
      nullptr, nullptr, nullptr,
      nullptr, x16a, stats + 0, stats + 128);
  // gemm2: BN1+relu on fp16 A, fp16 out (consumer: gather2), stats1
  gemm_gin_mfma_kernel<true, true><<<782, 256, 0, stream>>>(
      nullptr, x16a, ginWh + 1 * 16384, gb[1],
      stats + 0, gga[0], gbe[0],
      nullptr, x16b, stats + 256, stats + 384);
  // GIN layer 2 (BN2 finalize+affine+relu fused into the fp16 gather)
  gin_agg_kernel<true><<<12500, 256, 0, stream>>>(x16b, row_start, csr,
                                                  stats + 256, gga[1], gbe[1], xa);
  // gemm3: raw agg fp32 in, fp16 out only (consumer: gemm4), stats2
  gemm_gin_mfma_kernel<false, false><<<782, 256, 0, stream>>>(
      xa, nullptr, ginWh + 2 * 16384, gb[2],
      nullptr, nullptr, nullptr,
      nullptr, x16a, stats + 512, stats + 640);
  // gemm4: BN3+relu on fp16 A, fp32 out (consumer: set2set), stats3
  gemm_gin_mfma_kernel<true, true><<<782, 256, 0, stream>>>(
      nullptr, x16a, ginWh + 3 * 16384, gb[3],
      stats + 512, gga[2], gbe[2],
      xa, nullptr, stats + 768, stats + 896);
  // xa holds pre-BN4 features; BN4 fused into set2set x staging

  // fused Set2Set v5: fdot2 fp16 matvec, fp16 LDS x-cache, step-0 algebraic skip
  set2set_kernel<<<256, 1024, 0, stream>>>(xa, gptr, stats + 768, gga[3], gbe[3],
                                           WT0h, WTRh, bc0, bcR, ebuf, linW, linb, out);
}

// Round 3
// 425.440 us; speedup vs baseline: 1.2134x; 1.0409x over previous
//
#include <hip/hip_runtime.h>
#include <math.h>

#define NN 50000
#define EE 800000
#define BBG 256
#define HHC 128
#define SEG_CAP 448  // LDS x-cache rows per graph (fp16 packed)
#define ESC 512      // per-graph e-cache entries in LDS
#define NBIN 196     // coarse bins of 256 nodes
#define NBLK 196     // blocks in K1/K3 (4096 edges each)

typedef _Float16 half8 __attribute__((ext_vector_type(8)));
typedef _Float16 half4 __attribute__((ext_vector_type(4)));
typedef _Float16 half2v __attribute__((ext_vector_type(2)));
typedef float f32x4 __attribute__((ext_vector_type(4)));

#if defined(__has_builtin)
#if __has_builtin(__builtin_amdgcn_fdot2)
#define USE_FDOT2 1
#endif
#endif

__device__ __forceinline__ float fdot2f(half2v a, half2v b, float c) {
#ifdef USE_FDOT2
  return __builtin_amdgcn_fdot2(a, b, c, false);
#else
  return fmaf((float)a[0], (float)b[0], fmaf((float)a[1], (float)b[1], c));
#endif
}

__device__ __forceinline__ float fsigm(float x) {
  return __builtin_amdgcn_rcpf(1.f + __expf(-x));
}
__device__ __forceinline__ float ftanh(float x) {
  return 1.f - 2.f * __builtin_amdgcn_rcpf(1.f + __expf(2.f * x));
}

__device__ __forceinline__ float4 aff4(float4 v, float4 sc, float4 sh) {
  v.x = fmaxf(fmaf(v.x, sc.x, sh.x), 0.f);
  v.y = fmaxf(fmaf(v.y, sc.y, sh.y), 0.f);
  v.z = fmaxf(fmaf(v.z, sc.z, sh.z), 0.f);
  v.w = fmaxf(fmaf(v.w, sc.w, sh.w), 0.f);
  return v;
}

// ---------------- merged prep: zero | gptr | coarse hist | weight repack | x->fp16 ----
// GIN weights -> fp16 natural layout W[o][k] (k contiguous) for MFMA B-fragments.
// LSTM weights -> fp16, gate-interleaved, k-pair-interleaved for fdot2.
__global__ __launch_bounds__(256) void prep_all_kernel(
    const int* __restrict__ batch,
    const int* __restrict__ ei,
    const float* __restrict__ W0, const float* __restrict__ W1,
    const float* __restrict__ W2, const float* __restrict__ W3,
    const float* __restrict__ Wih0, const float* __restrict__ Whh0,
    const float* __restrict__ WihR, const float* __restrict__ WhhR,
    const float* __restrict__ b0, const float* __restrict__ bR,
    const float* __restrict__ xsrc,
    float* __restrict__ stats, int* __restrict__ gptr, int* __restrict__ partial,
    _Float16* __restrict__ ginWh, _Float16* __restrict__ WT0h,
    _Float16* __restrict__ WTRh, float* __restrict__ bc0, float* __restrict__ bcR,
    _Float16* __restrict__ x16a) {
  __shared__ int hist[NBIN];
  int blk = blockIdx.x, tid = threadIdx.x;
  if (blk == 0) {
    ((float4*)stats)[tid] = make_float4(0.f, 0.f, 0.f, 0.f);  // 1024 floats
    return;
  }
  if (blk <= 196) {  // gptr boundaries
    int i = (blk - 1) * 256 + tid;
    if (i >= NN) return;
    int b = batch[i];
    int prev = (i == 0) ? -1 : batch[i - 1];
    for (int g = prev + 1; g <= b; ++g) gptr[g] = i;
    if (i == NN - 1) {
      for (int g = b + 1; g <= BBG; ++g) gptr[g] = NN;
    }
    return;
  }
  if (blk <= 392) {  // coarse hist
    int b = blk - 197;
    if (tid < NBIN) hist[tid] = 0;
    __syncthreads();
    const int4* dst4 = (const int4*)(ei + EE);
#pragma unroll
    for (int c = 0; c < 4; ++c) {
      int idx = b * 1024 + c * 256 + tid;
      if (idx < EE / 4) {
        int4 d = dst4[idx];
        atomicAdd(&hist[d.x >> 8], 1);
        atomicAdd(&hist[d.y >> 8], 1);
        atomicAdd(&hist[d.z >> 8], 1);
        atomicAdd(&hist[d.w >> 8], 1);
      }
    }
    __syncthreads();
    if (tid < NBIN) partial[tid * NBLK + b] = hist[tid];
    return;
  }
  if (blk >= 2961) {  // x -> fp16 (6250 blocks x 256 = 1,600,000 float4 groups)
    int i = (blk - 2961) * 256 + tid;
    float4 v = ((const float4*)xsrc)[i];
    half4 h;
    h[0] = (_Float16)v.x; h[1] = (_Float16)v.y;
    h[2] = (_Float16)v.z; h[3] = (_Float16)v.w;
    ((half4*)x16a)[i] = h;
    return;
  }
  // weight prep
  int idx = (blk - 393) * 256 + tid;  // [0, 657408)
  if (idx < 65536) {
    int m = idx >> 14;
    int r = idx & 16383;
    const float* W = (m == 0) ? W0 : (m == 1) ? W1 : (m == 2) ? W2 : W3;
    ginWh[idx] = (_Float16)W[r];  // natural [o][k], k contiguous
  } else if (idx < 262144) {
    int t = idx - 65536;
    int k = t >> 9, op = t & 511;
    int j = op >> 2, g = op & 3;
    int row = g * 128 + j;
    float v = (k < 256) ? Wih0[row * 256 + k] : Whh0[row * 128 + (k - 256)];
    WT0h[((k >> 1) << 10) | (op << 1) | (k & 1)] = (_Float16)v;
  } else if (idx < 655360) {
    int t = idx - 262144;
    int l = t >> 17;
    int rem = t & 131071;
    int k = rem >> 9, op = rem & 511;
    int j = op >> 2, g = op & 3;
    int row = g * 128 + j;
    float v = (k < 128) ? WihR[((size_t)l * 512 + row) * 128 + k]
                        : WhhR[((size_t)l * 512 + row) * 128 + (k - 128)];
    WTRh[((size_t)l << 17) | ((k >> 1) << 10) | (op << 1) | (k & 1)] = (_Float16)v;
  } else {
    int t = idx - 655360;
    if (t < 512) {
      bc0[t] = b0[(t & 3) * 128 + (t >> 2)];
    } else {
      int u = t - 512;
      int l = u >> 9, op = u & 511;
      bcR[u] = bR[l * 512 + (op & 3) * 128 + (op >> 2)];
    }
  }
}

// ---- atomic-free CSR build (two-level counting sort) ----

__global__ void scan_partials_kernel(const int* __restrict__ partial,
                                     int* __restrict__ block_base, int* __restrict__ total) {
  __shared__ int buf[256];
  int bin = blockIdx.x, tid = threadIdx.x;
  int v = (tid < NBLK) ? partial[bin * NBLK + tid] : 0;
  buf[tid] = v;
  __syncthreads();
  for (int off = 1; off < 256; off <<= 1) {
    int t = (tid >= off) ? buf[tid - off] : 0;
    __syncthreads();
    buf[tid] += t;
    __syncthreads();
  }
  if (tid < NBLK) block_base[bin * NBLK + tid] = buf[tid] - v;
  if (tid == 255) total[bin] = buf[255];
}

__global__ void scan_totals_kernel(const int* __restrict__ total, int* __restrict__ coarse_base) {
  __shared__ int buf[256];
  int tid = threadIdx.x;
  int v = (tid < NBIN) ? total[tid] : 0;
  buf[tid] = v;
  __syncthreads();
  for (int off = 1; off < 256; off <<= 1) {
    int t = (tid >= off) ? buf[tid - off] : 0;
    __syncthreads();
    buf[tid] += t;
    __syncthreads();
  }
  if (tid < NBIN) coarse_base[tid] = buf[tid] - v;
  if (tid == 255) coarse_base[NBIN] = buf[255];
}

__global__ __launch_bounds__(256) void bucket_scatter_kernel(const int* __restrict__ ei,
                                                             const int* __restrict__ coarse_base,
                                                             const int* __restrict__ block_base,
                                                             int* __restrict__ packed) {
  __shared__ int cursor[NBIN];
  int tid = threadIdx.x, b = blockIdx.x;
  if (tid < NBIN) cursor[tid] = coarse_base[tid] + block_base[tid * NBLK + b];
  __syncthreads();
  const int4* src4 = (const int4*)ei;
  const int4* dst4 = (const int4*)(ei + EE);
#pragma unroll
  for (int c = 0; c < 4; ++c) {
    int idx = b * 1024 + c * 256 + tid;
    if (idx < EE / 4) {
      int4 s = src4[idx];
      int4 d = dst4[idx];
      int p;
      p = atomicAdd(&cursor[d.x >> 8], 1); packed[p] = (s.x << 8) | (d.x & 255);
      p = atomicAdd(&cursor[d.y >> 8], 1); packed[p] = (s.y << 8) | (d.y & 255);
      p = atomicAdd(&cursor[d.z >> 8], 1); packed[p] = (s.z << 8) | (d.z & 255);
      p = atomicAdd(&cursor[d.w >> 8], 1); packed[p] = (s.w << 8) | (d.w & 255);
    }
  }
}

__global__ __launch_bounds__(256) void csr_finalize_kernel(const int* __restrict__ packed,
                                                           const int* __restrict__ coarse_base,
                                                           int* __restrict__ row_start,
                                                           int* __restrict__ csr) {
  __shared__ int fh[256];
  __shared__ int fb[256];
  int bin = blockIdx.x, tid = threadIdx.x;
  int e0 = coarse_base[bin], e1 = coarse_base[bin + 1];
  fh[tid] = 0;
  __syncthreads();
  for (int e = e0 + tid; e < e1; e += 256) atomicAdd(&fh[packed[e] & 255], 1);
  __syncthreads();
  int v = fh[tid];
  fb[tid] = v;
  __syncthreads();
  for (int off = 1; off < 256; off <<= 1) {
    int t = (tid >= off) ? fb[tid - off] : 0;
    __syncthreads();
    fb[tid] += t;
    __syncthreads();
  }
  int excl = fb[tid] - v;
  int node = bin * 256 + tid;
  if (node < NN) row_start[node] = e0 + excl;
  if (bin == NBIN - 1 && tid == 0) row_start[NN] = EE;
  __syncthreads();
  fb[tid] = excl;  // cursor
  __syncthreads();
  for (int e = e0 + tid; e < e1; e += 256) {
    int p = packed[e];
    int pos = atomicAdd(&fb[p & 255], 1);
    csr[e0 + pos] = p >> 8;
  }
}

// ---------------- GIN aggregation ----------------
// one wave per node; 16 lanes x half8 (16 B dwordx4) per 256 B row;
// 4 edges concurrently per wave (quarters), 4 row-loads deep per lane.
// Output fp16 (bit-identical to downstream gemm's own A->fp16 conversion).
template <bool AFF>
__global__ __launch_bounds__(256) void gin_agg_kernel(
    const _Float16* __restrict__ x16, const int* __restrict__ row_start,
    const int* __restrict__ csr,
    const float* __restrict__ stats, const float* __restrict__ gamma,
    const float* __restrict__ beta, _Float16* __restrict__ outp) {
  __shared__ float sc_s[128], sh_s[128];
  if (AFF) {
    int tt = threadIdx.x;
    if (tt < 128) {
      const float invN = 1.0f / (float)NN;
      float mm = stats[tt] * invN;
      float vv = stats[128 + tt] * invN - mm * mm;
      float rs = rsqrtf(vv + 1e-5f);
      float sc = gamma[tt] * rs;
      sc_s[tt] = sc;
      sh_s[tt] = beta[tt] - mm * sc;
    }
    __syncthreads();
  }
  int node = blockIdx.x * 4 + (threadIdx.x >> 6);  // exact: 12500*4 = 50000
  int lane = threadIdx.x & 63;
  int q = lane >> 4, t = lane & 15;
  const half8* xh8 = (const half8*)x16;  // row = node*16 half8s
  float scv[8], shv[8];
  if (AFF) {
#pragma unroll
    for (int f = 0; f < 8; ++f) { scv[f] = sc_s[t * 8 + f]; shv[f] = sh_s[t * 8 + f]; }
  }
  int s0 = row_start[node], s1 = row_start[node + 1];
  float acc[8] = {0.f, 0.f, 0.f, 0.f, 0.f, 0.f, 0.f, 0.f};
  int cnt = s1 - s0;
  int mainEnd = s0 + (cnt & ~15);
  for (int j = s0; j < mainEnd; j += 16) {
    int i0 = csr[j + q + 0];
    int i1 = csr[j + q + 4];
    int i2 = csr[j + q + 8];
    int i3 = csr[j + q + 12];
    half8 h0 = xh8[(size_t)i0 * 16 + t];
    half8 h1 = xh8[(size_t)i1 * 16 + t];
    half8 h2 = xh8[(size_t)i2 * 16 + t];
    half8 h3 = xh8[(size_t)i3 * 16 + t];
    if (AFF) {
#pragma unroll
      for (int f = 0; f < 8; ++f) {
        acc[f] += fmaxf(fmaf((float)h0[f], scv[f], shv[f]), 0.f);
        acc[f] += fmaxf(fmaf((float)h1[f], scv[f], shv[f]), 0.f);
        acc[f] += fmaxf(fmaf((float)h2[f], scv[f], shv[f]), 0.f);
        acc[f] += fmaxf(fmaf((float)h3[f], scv[f], shv[f]), 0.f);
      }
    } else {
#pragma unroll
      for (int f = 0; f < 8; ++f) {
        acc[f] += ((float)h0[f] + (float)h1[f]) + ((float)h2[f] + (float)h3[f]);
      }
    }
  }
  for (int j = mainEnd + q; j < s1; j += 4) {
    int i = csr[j];
    half8 h = xh8[(size_t)i * 16 + t];
    if (AFF) {
#pragma unroll
      for (int f = 0; f < 8; ++f) acc[f] += fmaxf(fmaf((float)h[f], scv[f], shv[f]), 0.f);
    } else {
#pragma unroll
      for (int f = 0; f < 8; ++f) acc[f] += (float)h[f];
    }
  }
  // reduce across the 4 quarters (lanes t, t+16, t+32, t+48)
#pragma unroll
  for (int f = 0; f < 8; ++f) {
    acc[f] += __shfl_xor(acc[f], 16);
    acc[f] += __shfl_xor(acc[f], 32);
  }
  if (q == 0) {
    half8 selfh = xh8[(size_t)node * 16 + t];
    half8 hv;
#pragma unroll
    for (int f = 0; f < 8; ++f) {
      float sv = (float)selfh[f];
      if (AFF) sv = fmaxf(fmaf(sv, scv[f], shv[f]), 0.f);
      hv[f] = (_Float16)(acc[f] + sv);
    }
    ((half8*)outp)[(size_t)node * 16 + t] = hv;
  }
}

// ---------------- MFMA GIN GEMM ----------------
// C = f(A) @ W^T + b via v_mfma_f32_16x16x32_f16.
// 4 waves/block; wave w owns cols [32w, 32w+32). B-frags (Wh, natural [o][k]
// layout, k contiguous) loaded once per block into regs. Block grid-strides
// 16-row M tiles (NN = 16*3125 exactly). BN+relu fused on A load; bias +
// fp32/fp16 stores + per-column stats fused in epilogue.
template <bool BN, bool AH>
__global__ __launch_bounds__(256) void gemm_gin_mfma_kernel(
    const float* __restrict__ A, const _Float16* __restrict__ A16,
    const _Float16* __restrict__ Wh,
    const float* __restrict__ bias,
    const float* __restrict__ stats, const float* __restrict__ gamma,
    const float* __restrict__ beta,
    float* __restrict__ C, _Float16* __restrict__ h16out,
    float* __restrict__ ssum, float* __restrict__ ssq) {
  __shared__ float bsc_s[128], bsh_s[128];
  int tid = threadIdx.x;
  if (BN) {
    if (tid < 128) {
      const float invN = 1.0f / (float)NN;
      float mm = stats[tid] * invN;
      float vv = stats[128 + tid] * invN - mm * mm;
      float rs = rsqrtf(vv + 1e-5f);
      float sc = gamma[tid] * rs;
      bsc_s[tid] = sc;
      bsh_s[tid] = beta[tid] - mm * sc;
    }
    __syncthreads();
  }
  int w = tid >> 6, l = tid & 63;
  int lr = l & 15, lg = l >> 4;
  int cb = w * 32;
  half8 bf0[4], bf1[4];
#pragma unroll
  for (int ks = 0; ks < 4; ++ks) {
    int k = ks * 32 + lg * 8;
    bf0[ks] = *(const half8*)(Wh + (size_t)(cb + lr) * 128 + k);
    bf1[ks] = *(const half8*)(Wh + (size_t)(cb + 16 + lr) * 128 + k);
  }
  float bv0 = bias[cb + lr], bv1 = bias[cb + 16 + lr];
  float ps0 = 0.f, pq0 = 0.f, ps1 = 0.f, pq1 = 0.f;
  int t0 = blockIdx.x * 4;
  for (int t = 0; t < 4; ++t) {
    int tile = t0 + t;
    if (tile >= 3125) break;
    int r = tile * 16 + lr;
    half8 af[4];
#pragma unroll
    for (int ks = 0; ks < 4; ++ks) {
      int k0 = ks * 32 + lg * 8;
      if constexpr (AH) {
        half8 ah = *(const half8*)(A16 + (size_t)r * 128 + k0);
        if constexpr (BN) {
          float4 s0 = *(const float4*)&bsc_s[k0];
          float4 s1 = *(const float4*)&bsc_s[k0 + 4];
          float4 h0 = *(const float4*)&bsh_s[k0];
          float4 h1 = *(const float4*)&bsh_s[k0 + 4];
          half8 o;
          o[0] = (_Float16)fmaxf(fmaf((float)ah[0], s0.x, h0.x), 0.f);
          o[1] = (_Float16)fmaxf(fmaf((float)ah[1], s0.y, h0.y), 0.f);
          o[2] = (_Float16)fmaxf(fmaf((float)ah[2], s0.z, h0.z), 0.f);
          o[3] = (_Float16)fmaxf(fmaf((float)ah[3], s0.w, h0.w), 0.f);
          o[4] = (_Float16)fmaxf(fmaf((float)ah[4], s1.x, h1.x), 0.f);
          o[5] = (_Float16)fmaxf(fmaf((float)ah[5], s1.y, h1.y), 0.f);
          o[6] = (_Float16)fmaxf(fmaf((float)ah[6], s1.z, h1.z), 0.f);
          o[7] = (_Float16)fmaxf(fmaf((float)ah[7], s1.w, h1.w), 0.f);
          af[ks] = o;
        } else {
          af[ks] = ah;
        }
      } else {
        float4 a0 = *(const float4*)(A + (size_t)r * 128 + k0);
        float4 a1 = *(const float4*)(A + (size_t)r * 128 + k0 + 4);
        if constexpr (BN) {
          float4 s0 = *(const float4*)&bsc_s[k0];
          float4 s1 = *(const float4*)&bsc_s[k0 + 4];
          float4 h0 = *(const float4*)&bsh_s[k0];
          float4 h1 = *(const float4*)&bsh_s[k0 + 4];
          a0 = aff4(a0, s0, h0);
          a1 = aff4(a1, s1, h1);
        }
        half8 o;
        o[0] = (_Float16)a0.x; o[1] = (_Float16)a0.y;
        o[2] = (_Float16)a0.z; o[3] = (_Float16)a0.w;
        o[4] = (_Float16)a1.x; o[5] = (_Float16)a1.y;
        o[6] = (_Float16)a1.z; o[7] = (_Float16)a1.w;
        af[ks] = o;
      }
    }
    f32x4 acc0 = {0.f, 0.f, 0.f, 0.f};
    f32x4 acc1 = {0.f, 0.f, 0.f, 0.f};
#pragma unroll
    for (int ks = 0; ks < 4; ++ks) {
      acc0 = __builtin_amdgcn_mfma_f32_16x16x32_f16(af[ks], bf0[ks], acc0, 0, 0, 0);
      acc1 = __builtin_amdgcn_mfma_f32_16x16x32_f16(af[ks], bf1[ks], acc1, 0, 0, 0);
    }
#pragma unroll
    for (int i = 0; i < 4; ++i) {
      int rr = tile * 16 + lg * 4 + i;
      float v0 = acc0[i] + bv0;
      float v1 = acc1[i] + bv1;
      if (C) {
        C[(size_t)rr * 128 + cb + lr] = v0;
        C[(size_t)rr * 128 + cb + 16 + lr] = v1;
      }
      if (h16out) {
        h16out[(size_t)rr * 128 + cb + lr] = (_Float16)v0;
        h16out[(size_t)rr * 128 + cb + 16 + lr] = (_Float16)v1;
      }
      ps0 += v0; pq0 += v0 * v0;
      ps1 += v1; pq1 += v1 * v1;
    }
  }
  // reduce per-column partials across the 4 k-groups (lanes l, l^16, l^32, l^48)
  ps0 += __shfl_xor(ps0, 16); ps0 += __shfl_xor(ps0, 32);
  pq0 += __shfl_xor(pq0, 16); pq0 += __shfl_xor(pq0, 32);
  ps1 += __shfl_xor(ps1, 16); ps1 += __shfl_xor(ps1, 32);
  pq1 += __shfl_xor(pq1, 16); pq1 += __shfl_xor(pq1, 32);
  if (lg == 0) {
    atomicAdd(&ssum[cb + lr], ps0);
    atomicAdd(&ssq[cb + lr], pq0);
    atomicAdd(&ssum[cb + 16 + lr], ps1);
    atomicAdd(&ssq[cb + 16 + lr], pq1);
  }
}

// ---------------- fused Set2Set v6: fdot2 matvec, fp16 LDS x-cache, step-0 skip,
// merged gates-reduce+activation (one fewer barrier per cell) -------
__global__ void __launch_bounds__(1024) set2set_kernel(
    const float* __restrict__ x, const int* __restrict__ gptr,
    const float* __restrict__ stats, const float* __restrict__ gamma,
    const float* __restrict__ beta,
    const _Float16* __restrict__ WT0h, const _Float16* __restrict__ WTRh,
    const float* __restrict__ bc0, const float* __restrict__ bcR,
    float* __restrict__ ebuf,
    const float* __restrict__ linW, const float* __restrict__ linb,
    float* __restrict__ out) {
  __shared__ half2v xs[SEG_CAP * 64];  // 114688 B (448 rows, fp16-packed)
  __shared__ float wpart[16][512];     // 32 KB (aliased as rpart in attention)
  __shared__ half2v inp2[192];         // fp16-packed LSTM input (k-pairs)
  __shared__ float hcs[4][128];
  __shared__ float ccs[4][128];
  __shared__ float qst[256];
  __shared__ float es[ESC];            // 2 KB
  __shared__ float bsc[128], bsh[128];
  __shared__ float wred[16];
  __shared__ float smax_s, ssum_s;
  __shared__ float fred[2][4];

  int g = blockIdx.x, tid = threadIdx.x;
  int w16 = tid >> 6, lane = tid & 63;

  // init
  if (tid < 128) {
    const float invN = 1.0f / (float)NN;
    float mm = stats[tid] * invN;
    float vv = stats[128 + tid] * invN - mm * mm;
    float rs = rsqrtf(vv + 1e-5f);
    float sc = gamma[tid] * rs;
    bsc[tid] = sc;
    bsh[tid] = beta[tid] - mm * sc;
#pragma unroll
    for (int l = 0; l < 4; ++l) { hcs[l][tid] = 0.f; ccs[l][tid] = 0.f; }
  }
  if (tid < 256) qst[tid] = 0.f;
  __syncthreads();

  int s0 = gptr[g], s1 = gptr[g + 1];
  int seg = s1 - s0;
  int ncache = seg < SEG_CAP ? seg : SEG_CAP;
  const float2* x2 = (const float2*)x;
  float sc0 = bsc[2 * lane], sc1 = bsc[2 * lane + 1];
  float sh0 = bsh[2 * lane], sh1 = bsh[2 * lane + 1];
  // stage segment into LDS once (BN4-transformed, fp16-packed); one row per wave
  for (int n = w16; n < ncache; n += 16) {
    float2 v = x2[(size_t)(s0 + n) * 64 + lane];
    half2v h;
    h[0] = (_Float16)fmaxf(fmaf(v.x, sc0, sh0), 0.f);
    h[1] = (_Float16)fmaxf(fmaf(v.y, sc1, sh1), 0.f);
    xs[n * 64 + lane] = h;
  }
  __syncthreads();

  int s_ = tid >> 6, cg = tid & 63;  // matvec: K-slice (16), col-group (8 cols)

  for (int step = 0; step < 4; ++step) {
    // ---- 4 stacked LSTM cells ----
    for (int cell = 0; cell < 4; ++cell) {
      const _Float16* WTh; const float* bias; int KP2;
      if (cell == 0) {
        WTh = WT0h; bias = bc0; KP2 = 12;  // K=384 -> 192 k2-pairs, 12 per slice
        if (tid < 192) {
          int k = tid << 1;
          float va, vb;
          if (k < 256) { va = qst[k]; vb = qst[k + 1]; }
          else { va = hcs[0][k - 256]; vb = hcs[0][k - 255]; }
          half2v h; h[0] = (_Float16)va; h[1] = (_Float16)vb;
          inp2[tid] = h;
        }
      } else {
        WTh = WTRh + (size_t)(cell - 1) * 131072;
        bias = bcR + (cell - 1) * 512; KP2 = 8;  // K=256 -> 128 pairs, 8 per slice
        if (tid < 128) {
          int k = tid << 1;
          float va, vb;
          if (k < 128) { va = hcs[cell - 1][k]; vb = hcs[cell - 1][k + 1]; }
          else { va = hcs[cell][k - 128]; vb = hcs[cell][k - 127]; }
          half2v h; h[0] = (_Float16)va; h[1] = (_Float16)vb;
          inp2[tid] = h;
        }
      }
      __syncthreads();
      bool skipmv = (step == 0 && cell == 0);
      if (!skipmv) {
        int se = (s_ + g) & 15;  // rotate slice start per block
        int k20 = se * KP2;
        float a0 = 0.f, a1 = 0.f, a2 = 0.f, a3 = 0.f;
        float a4 = 0.f, a5 = 0.f, a6 = 0.f, a7 = 0.f;
        // step 0, cells>=1: old-h half (k>=128) is zero -> only slices se<8 contribute
        if (step != 0 || se < 8) {
          const char* wb = (const char*)WTh + (size_t)k20 * 2048 + (cg << 5);
#pragma unroll 4
          for (int k2 = 0; k2 < KP2; ++k2) {
            uint4 wa = *(const uint4*)(wb + (size_t)k2 * 2048);
            uint4 wc = *(const uint4*)(wb + (size_t)k2 * 2048 + 16);
            half2v i2 = inp2[k20 + k2];
            a0 = fdot2f(i2, __builtin_bit_cast(half2v, wa.x), a0);
            a1 = fdot2f(i2, __builtin_bit_cast(half2v, wa.y), a1);
            a2 = fdot2f(i2, __builtin_bit_cast(half2v, wa.z), a2);
            a3 = fdot2f(i2, __builtin_bit_cast(half2v, wa.w), a3);
            a4 = fdot2f(i2, __builtin_bit_cast(half2v, wc.x), a4);
            a5 = fdot2f(i2, __builtin_bit_cast(half2v, wc.y), a5);
            a6 = fdot2f(i2, __builtin_bit_cast(half2v, wc.z), a6);
            a7 = fdot2f(i2, __builtin_bit_cast(half2v, wc.w), a7);
          }
        }
        *(float4*)&wpart[s_][cg << 3] = make_float4(a0, a1, a2, a3);
        *(float4*)(&wpart[s_][cg << 3] + 4) = make_float4(a4, a5, a6, a7);
        __syncthreads();
      }
      // merged gates-reduce + activation (128 threads, float4 over 16 slices)
      if (tid < 128) {
        int j = tid;
        float4 ga = *(const float4*)&bias[4 * j];
        if (!skipmv) {
#pragma unroll
          for (int s = 0; s < 16; ++s) {
            float4 wv = *(const float4*)&wpart[s][4 * j];
            ga.x += wv.x; ga.y += wv.y; ga.z += wv.z; ga.w += wv.w;
          }
        }
        float cp = ccs[cell][j];
        float si = fsigm(ga.x);
        float sf = fsigm(ga.y);
        float so = fsigm(ga.w);
        float cn = sf * cp + si * ftanh(ga.z);
        ccs[cell][j] = cn;
        hcs[cell][j] = so * ftanh(cn);
      }
      __syncthreads();
    }
    // ---- attention, q = new h[3]; x from fp16 LDS cache ----
    float* rpart = &wpart[0][0];  // alias: time-disjoint with matvec
    float qx = hcs[3][2 * lane], qy = hcs[3][2 * lane + 1];
    half2v q2; q2[0] = (_Float16)qx; q2[1] = (_Float16)qy;
    // pass 1: e + max
    float wmax = -3.0e38f;
    for (int n = w16; n < seg; n += 16) {
      float e;
      if (n < ncache) {
        e = fdot2f(xs[n * 64 + lane], q2, 0.f);
      } else {
        float2 v = x2[(size_t)(s0 + n) * 64 + lane];
        float vx = fmaxf(fmaf(v.x, sc0, sh0), 0.f);
        float vy = fmaxf(fmaf(v.y, sc1, sh1), 0.f);
        e = vx * qx + vy * qy;
      }
#pragma unroll
      for (int sh = 32; sh; sh >>= 1) e += __shfl_xor(e, sh);
      if (lane == 0) { if (n < ESC) es[n] = e; else ebuf[s0 + n] = e; }
      wmax = fmaxf(wmax, e);
    }
    if (lane == 0) wred[w16] = wmax;
    __syncthreads();
    if (tid == 0) {
      float m = wred[0];
#pragma unroll
      for (int t = 1; t < 16; ++t) m = fmaxf(m, wred[t]);
      smax_s = m;
    }
    __syncthreads();
    float m = smax_s;
    // pass 2: sum exp (cache exp back into es/ebuf for pass 3)
    float loc = 0.f;
    for (int n = tid; n < seg; n += 1024) {
      float e = (n < ESC) ? es[n] : ebuf[s0 + n];
      float ex = __expf(e - m);
      if (n < ESC) es[n] = ex; else ebuf[s0 + n] = ex;
      loc += ex;
    }
#pragma unroll
    for (int sh = 32; sh; sh >>= 1) loc += __shfl_xor(loc, sh);
    __syncthreads();
    if (lane == 0) wred[w16] = loc;
    __syncthreads();
    if (tid == 0) {
      float s = 0.f;
#pragma unroll
      for (int t = 0; t < 16; ++t) s += wred[t];
      ssum_s = s;
    }
    __syncthreads();
    float inv = 1.0f / ssum_s;
    // pass 3: r = sum a*x
    float rx = 0.f, ry = 0.f;
    for (int n = w16; n < seg; n += 16) {
      float ex = (n < ESC) ? es[n] : ebuf[s0 + n];
      float coef = ex * inv;
      float vx, vy;
      if (n < ncache) {
        half2v v2 = xs[n * 64 + lane];
        vx = (float)v2[0]; vy = (float)v2[1];
      } else {
        float2 v = x2[(size_t)(s0 + n) * 64 + lane];
        vx = fmaxf(fmaf(v.x, sc0, sh0), 0.f);
        vy = fmaxf(fmaf(v.y, sc1, sh1), 0.f);
      }
      rx += coef * vx; ry += coef * vy;
    }
    rpart[w16 * 128 + 2 * lane] = rx;
    rpart[w16 * 128 + 2 * lane + 1] = ry;
    __syncthreads();
    if (tid < 128) {
      float r = 0.f;
#pragma unroll
      for (int t = 0; t < 16; ++t) r += rpart[t * 128 + tid];
      qst[tid] = hcs[3][tid];
      qst[128 + tid] = r;
    }
    __syncthreads();
  }
  // ---- final linear ----
  if (tid < 256) {
    float val = qst[tid];
    float p0 = val * linW[tid];
    float p1 = val * linW[256 + tid];
#pragma unroll
    for (int sh = 32; sh; sh >>= 1) { p0 += __shfl_xor(p0, sh); p1 += __shfl_xor(p1, sh); }
    if (lane == 0) { fred[0][w16] = p0; fred[1][w16] = p1; }
  }
  __syncthreads();
  if (tid == 0) {
    out[2 * g + 0] = fred[0][0] + fred[0][1] + fred[0][2] + fred[0][3] + linb[0];
    out[2 * g + 1] = fred[1][0] + fred[1][1] + fred[1][2] + fred[1][3] + linb[1];
  }
}

// ---------------- launch ----------------

extern "C" void kernel_launch(void* const* d_in, const int* in_sizes, int n_in,
                              void* d_out, int out_size, void* d_ws, size_t ws_size,
                              hipStream_t stream) {
  const float* x = (const float*)d_in[0];
  const int* ei = (const int*)d_in[1];
  const int* batch = (const int*)d_in[2];
  const float* gW[4]  = {(const float*)d_in[3],  (const float*)d_in[7],
                         (const float*)d_in[11], (const float*)d_in[15]};
  const float* gb[4]  = {(const float*)d_in[4],  (const float*)d_in[8],
                         (const float*)d_in[12], (const float*)d_in[16]};
  const float* gga[4] = {(const float*)d_in[5],  (const float*)d_in[9],
                         (const float*)d_in[13], (const float*)d_in[17]};
  const float* gbe[4] = {(const float*)d_in[6],  (const float*)d_in[10],
                         (const float*)d_in[14], (const float*)d_in[18]};
  const float* Wih0 = (const float*)d_in[19];
  const float* Whh0 = (const float*)d_in[20];
  const float* b0   = (const float*)d_in[21];
  const float* WihR = (const float*)d_in[22];
  const float* WhhR = (const float*)d_in[23];
  const float* bR   = (const float*)d_in[24];
  const float* linW = (const float*)d_in[25];
  const float* linb = (const float*)d_in[26];
  float* out = (float*)d_out;

  char* base = (char*)d_ws;
  size_t off = 0;
  auto allocf = [&](size_t n) { float* p = (float*)(base + off); off += n * sizeof(float); return p; };
  float* xa    = allocf(6400000);
  _Float16* agg16 = (_Float16*)(base + off); off += 6400000 * 2;
  _Float16* ginWh = (_Float16*)(base + off); off += 65536 * 2;
  _Float16* WT0h = (_Float16*)(base + off); off += 196608 * 2;
  _Float16* WTRh = (_Float16*)(base + off); off += 393216 * 2;
  _Float16* x16a = (_Float16*)(base + off); off += 6400000 * 2;
  _Float16* x16b = (_Float16*)(base + off); off += 6400000 * 2;
  float* bc0   = allocf(512);
  float* bcR   = allocf(1536);
  float* ebuf  = allocf(50000);
  // ---- zero region: stats only (1024 floats = 256 float4) ----
  float* stats = allocf(1024);     // 4 x (sum128|sq128)
  // ---- ints (all fully written before read; no zeroing needed) ----
  int* row_start = (int*)(base + off); off += 50004 * 4;
  int* gptr = (int*)(base + off); off += 260 * 4;
  int* csr = (int*)(base + off); off += 800000 * 4;
  int* packed = (int*)(base + off); off += 800000 * 4;
  int* partial = (int*)(base + off); off += NBIN * NBLK * 4;
  int* block_base = (int*)(base + off); off += NBIN * NBLK * 4;
  int* total = (int*)(base + off); off += 256 * 4;
  int* coarse_base = (int*)(base + off); off += 260 * 4;
  (void)ws_size; (void)in_sizes; (void)n_in; (void)out_size;

  // merged prep: zero | gptr | hist | weight repack | x->fp16  (grid 2961+6250)
  prep_all_kernel<<<9211, 256, 0, stream>>>(batch, ei, gW[0], gW[1], gW[2], gW[3],
                                            Wih0, Whh0, WihR, WhhR, b0, bR, x,
                                            stats, gptr, partial, ginWh, WT0h, WTRh,
                                            bc0, bcR, x16a);
  scan_partials_kernel<<<NBIN, 256, 0, stream>>>(partial, block_base, total);
  scan_totals_kernel<<<1, 256, 0, stream>>>(total, coarse_base);
  bucket_scatter_kernel<<<NBLK, 256, 0, stream>>>(ei, coarse_base, block_base, packed);
  csr_finalize_kernel<<<NBIN, 256, 0, stream>>>(packed, coarse_base, row_start, csr);

  // GIN layer 1: gather (fp16 in/out)
  gin_agg_kernel<false><<<12500, 256, 0, stream>>>(x16a, row_start, csr,
                                                   nullptr, nullptr, nullptr, agg16);
  // gemm1: fp16 agg in, fp16 out only (consumer: gemm2), stats0
  gemm_gin_mfma_kernel<false, true><<<782, 256, 0, stream>>>(
      nullptr, agg16, ginWh + 0 * 16384, gb[0],
      nullptr, nullptr, nullptr,
      nullptr, x16a, stats + 0, stats + 128);
  // gemm2: BN1+relu on fp16 A, fp16 out (consumer: gather2), stats1
  gemm_gin_mfma_kernel<true, true><<<782, 256, 0, stream>>>(
      nullptr, x16a, ginWh + 1 * 16384, gb[1],
      stats + 0, gga[0], gbe[0],
      nullptr, x16b, stats + 256, stats + 384);
  // GIN layer 2: gather with BN2 finalize+affine+relu fused (fp16 in/out)
  gin_agg_kernel<true><<<12500, 256, 0, stream>>>(x16b, row_start, csr,
                                                  stats + 256, gga[1], gbe[1], agg16);
  // gemm3: fp16 agg in, fp16 out only (consumer: gemm4), stats2
  gemm_gin_mfma_kernel<false, true><<<782, 256, 0, stream>>>(
      nullptr, agg16, ginWh + 2 * 16384, gb[2],
      nullptr, nullptr, nullptr,
      nullptr, x16a, stats + 512, stats + 640);
  // gemm4: BN3+relu on fp16 A, fp32 out (consumer: set2set), stats3
  gemm_gin_mfma_kernel<true, true><<<782, 256, 0, stream>>>(
      nullptr, x16a, ginWh + 3 * 16384, gb[3],
      stats + 512, gga[2], gbe[2],
      xa, nullptr, stats + 768, stats + 896);
  // xa holds pre-BN4 features; BN4 fused into set2set x staging

  // fused Set2Set v6
  set2set_kernel<<<256, 1024, 0, stream>>>(xa, gptr, stats + 768, gga[3], gbe[3],
                                           WT0h, WTRh, bc0, bcR, ebuf, linW, linb, out);
}

// Round 4
// 424.178 us; speedup vs baseline: 1.2170x; 1.0030x over previous
//
#include <hip/hip_runtime.h>
#include <math.h>

#define NN 50000
#define EE 800000
#define BBG 256
#define HHC 128
#define SEG_CAP 448  // LDS x-cache rows per graph (fp16 packed)
#define ESC 512      // per-graph e-cache entries in LDS
#define NBIN 196     // coarse bins of 256 nodes
#define NBLK 196     // blocks in K1/K3 (4096 edges each)

typedef _Float16 half8 __attribute__((ext_vector_type(8)));
typedef _Float16 half4 __attribute__((ext_vector_type(4)));
typedef _Float16 half2v __attribute__((ext_vector_type(2)));
typedef float f32x4 __attribute__((ext_vector_type(4)));

#if defined(__has_builtin)
#if __has_builtin(__builtin_amdgcn_fdot2)
#define USE_FDOT2 1
#endif
#endif

__device__ __forceinline__ float fdot2f(half2v a, half2v b, float c) {
#ifdef USE_FDOT2
  return __builtin_amdgcn_fdot2(a, b, c, false);
#else
  return fmaf((float)a[0], (float)b[0], fmaf((float)a[1], (float)b[1], c));
#endif
}

__device__ __forceinline__ float fsigm(float x) {
  return __builtin_amdgcn_rcpf(1.f + __expf(-x));
}
__device__ __forceinline__ float ftanh(float x) {
  return 1.f - 2.f * __builtin_amdgcn_rcpf(1.f + __expf(2.f * x));
}

__device__ __forceinline__ float4 aff4(float4 v, float4 sc, float4 sh) {
  v.x = fmaxf(fmaf(v.x, sc.x, sh.x), 0.f);
  v.y = fmaxf(fmaf(v.y, sc.y, sh.y), 0.f);
  v.z = fmaxf(fmaf(v.z, sc.z, sh.z), 0.f);
  v.w = fmaxf(fmaf(v.w, sc.w, sh.w), 0.f);
  return v;
}

// ---------------- merged prep: zero | gptr | coarse hist | weight repack | x->fp16 ----
// GIN weights -> fp16 natural layout W[o][k] (k contiguous) for MFMA B-fragments.
// LSTM weights -> fp16, gate-interleaved, k-pair-interleaved for fdot2.
__global__ __launch_bounds__(256) void prep_all_kernel(
    const int* __restrict__ batch,
    const int* __restrict__ ei,
    const float* __restrict__ W0, const float* __restrict__ W1,
    const float* __restrict__ W2, const float* __restrict__ W3,
    const float* __restrict__ Wih0, const float* __restrict__ Whh0,
    const float* __restrict__ WihR, const float* __restrict__ WhhR,
    const float* __restrict__ b0, const float* __restrict__ bR,
    const float* __restrict__ xsrc,
    float* __restrict__ stats, int* __restrict__ gptr, int* __restrict__ partial,
    _Float16* __restrict__ ginWh, _Float16* __restrict__ WT0h,
    _Float16* __restrict__ WTRh, float* __restrict__ bc0, float* __restrict__ bcR,
    _Float16* __restrict__ x16a) {
  __shared__ int hist[NBIN];
  int blk = blockIdx.x, tid = threadIdx.x;
  if (blk == 0) {
    ((float4*)stats)[tid] = make_float4(0.f, 0.f, 0.f, 0.f);  // 1024 floats
    return;
  }
  if (blk <= 196) {  // gptr boundaries
    int i = (blk - 1) * 256 + tid;
    if (i >= NN) return;
    int b = batch[i];
    int prev = (i == 0) ? -1 : batch[i - 1];
    for (int g = prev + 1; g <= b; ++g) gptr[g] = i;
    if (i == NN - 1) {
      for (int g = b + 1; g <= BBG; ++g) gptr[g] = NN;
    }
    return;
  }
  if (blk <= 392) {  // coarse hist
    int b = blk - 197;
    if (tid < NBIN) hist[tid] = 0;
    __syncthreads();
    const int4* dst4 = (const int4*)(ei + EE);
#pragma unroll
    for (int c = 0; c < 4; ++c) {
      int idx = b * 1024 + c * 256 + tid;
      if (idx < EE / 4) {
        int4 d = dst4[idx];
        atomicAdd(&hist[d.x >> 8], 1);
        atomicAdd(&hist[d.y >> 8], 1);
        atomicAdd(&hist[d.z >> 8], 1);
        atomicAdd(&hist[d.w >> 8], 1);
      }
    }
    __syncthreads();
    if (tid < NBIN) partial[tid * NBLK + b] = hist[tid];
    return;
  }
  if (blk >= 2961) {  // x -> fp16 (6250 blocks x 256 = 1,600,000 float4 groups)
    int i = (blk - 2961) * 256 + tid;
    float4 v = ((const float4*)xsrc)[i];
    half4 h;
    h[0] = (_Float16)v.x; h[1] = (_Float16)v.y;
    h[2] = (_Float16)v.z; h[3] = (_Float16)v.w;
    ((half4*)x16a)[i] = h;
    return;
  }
  // weight prep
  int idx = (blk - 393) * 256 + tid;  // [0, 657408)
  if (idx < 65536) {
    int m = idx >> 14;
    int r = idx & 16383;
    const float* W = (m == 0) ? W0 : (m == 1) ? W1 : (m == 2) ? W2 : W3;
    ginWh[idx] = (_Float16)W[r];  // natural [o][k], k contiguous
  } else if (idx < 262144) {
    int t = idx - 65536;
    int k = t >> 9, op = t & 511;
    int j = op >> 2, g = op & 3;
    int row = g * 128 + j;
    float v = (k < 256) ? Wih0[row * 256 + k] : Whh0[row * 128 + (k - 256)];
    WT0h[((k >> 1) << 10) | (op << 1) | (k & 1)] = (_Float16)v;
  } else if (idx < 655360) {
    int t = idx - 262144;
    int l = t >> 17;
    int rem = t & 131071;
    int k = rem >> 9, op = rem & 511;
    int j = op >> 2, g = op & 3;
    int row = g * 128 + j;
    float v = (k < 128) ? WihR[((size_t)l * 512 + row) * 128 + k]
                        : WhhR[((size_t)l * 512 + row) * 128 + (k - 128)];
    WTRh[((size_t)l << 17) | ((k >> 1) << 10) | (op << 1) | (k & 1)] = (_Float16)v;
  } else {
    int t = idx - 655360;
    if (t < 512) {
      bc0[t] = b0[(t & 3) * 128 + (t >> 2)];
    } else {
      int u = t - 512;
      int l = u >> 9, op = u & 511;
      bcR[u] = bR[l * 512 + (op & 3) * 128 + (op >> 2)];
    }
  }
}

// ---- atomic-free CSR build (two-level counting sort) ----

__global__ void scan_partials_kernel(const int* __restrict__ partial,
                                     int* __restrict__ block_base, int* __restrict__ total) {
  __shared__ int buf[256];
  int bin = blockIdx.x, tid = threadIdx.x;
  int v = (tid < NBLK) ? partial[bin * NBLK + tid] : 0;
  buf[tid] = v;
  __syncthreads();
  for (int off = 1; off < 256; off <<= 1) {
    int t = (tid >= off) ? buf[tid - off] : 0;
    __syncthreads();
    buf[tid] += t;
    __syncthreads();
  }
  if (tid < NBLK) block_base[bin * NBLK + tid] = buf[tid] - v;
  if (tid == 255) total[bin] = buf[255];
}

__global__ void scan_totals_kernel(const int* __restrict__ total, int* __restrict__ coarse_base) {
  __shared__ int buf[256];
  int tid = threadIdx.x;
  int v = (tid < NBIN) ? total[tid] : 0;
  buf[tid] = v;
  __syncthreads();
  for (int off = 1; off < 256; off <<= 1) {
    int t = (tid >= off) ? buf[tid - off] : 0;
    __syncthreads();
    buf[tid] += t;
    __syncthreads();
  }
  if (tid < NBIN) coarse_base[tid] = buf[tid] - v;
  if (tid == 255) coarse_base[NBIN] = buf[255];
}

__global__ __launch_bounds__(256) void bucket_scatter_kernel(const int* __restrict__ ei,
                                                             const int* __restrict__ coarse_base,
                                                             const int* __restrict__ block_base,
                                                             int* __restrict__ packed) {
  __shared__ int cursor[NBIN];
  int tid = threadIdx.x, b = blockIdx.x;
  if (tid < NBIN) cursor[tid] = coarse_base[tid] + block_base[tid * NBLK + b];
  __syncthreads();
  const int4* src4 = (const int4*)ei;
  const int4* dst4 = (const int4*)(ei + EE);
#pragma unroll
  for (int c = 0; c < 4; ++c) {
    int idx = b * 1024 + c * 256 + tid;
    if (idx < EE / 4) {
      int4 s = src4[idx];
      int4 d = dst4[idx];
      int p;
      p = atomicAdd(&cursor[d.x >> 8], 1); packed[p] = (s.x << 8) | (d.x & 255);
      p = atomicAdd(&cursor[d.y >> 8], 1); packed[p] = (s.y << 8) | (d.y & 255);
      p = atomicAdd(&cursor[d.z >> 8], 1); packed[p] = (s.z << 8) | (d.z & 255);
      p = atomicAdd(&cursor[d.w >> 8], 1); packed[p] = (s.w << 8) | (d.w & 255);
    }
  }
}

__global__ __launch_bounds__(256) void csr_finalize_kernel(const int* __restrict__ packed,
                                                           const int* __restrict__ coarse_base,
                                                           int* __restrict__ row_start,
                                                           int* __restrict__ csr) {
  __shared__ int fh[256];
  __shared__ int fb[256];
  int bin = blockIdx.x, tid = threadIdx.x;
  int e0 = coarse_base[bin], e1 = coarse_base[bin + 1];
  fh[tid] = 0;
  __syncthreads();
  for (int e = e0 + tid; e < e1; e += 256) atomicAdd(&fh[packed[e] & 255], 1);
  __syncthreads();
  int v = fh[tid];
  fb[tid] = v;
  __syncthreads();
  for (int off = 1; off < 256; off <<= 1) {
    int t = (tid >= off) ? fb[tid - off] : 0;
    __syncthreads();
    fb[tid] += t;
    __syncthreads();
  }
  int excl = fb[tid] - v;
  int node = bin * 256 + tid;
  if (node < NN) row_start[node] = e0 + excl;
  if (bin == NBIN - 1 && tid == 0) row_start[NN] = EE;
  __syncthreads();
  fb[tid] = excl;  // cursor
  __syncthreads();
  for (int e = e0 + tid; e < e1; e += 256) {
    int p = packed[e];
    int pos = atomicAdd(&fb[p & 255], 1);
    csr[e0 + pos] = p >> 8;
  }
}

// ---------------- GIN aggregation ----------------
// 16 lanes per node (4 nodes/wave, 16 nodes/block): lane t owns channels
// 8t..8t+7 for the WHOLE reduction -> no cross-lane reduce. 8-deep main loop
// keeps 8 csr-idx + 8 row loads (16 B each) in flight per lane -> ~4x the
// memory-level parallelism of the old 1-wave-per-node form.
template <bool AFF>
__device__ __forceinline__ void acc8(float* acc, half8 h, const float* scv,
                                     const float* shv) {
#pragma unroll
  for (int f = 0; f < 8; ++f) {
    float v = (float)h[f];
    if (AFF) v = fmaxf(fmaf(v, scv[f], shv[f]), 0.f);
    acc[f] += v;
  }
}

template <bool AFF>
__global__ __launch_bounds__(256) void gin_agg_kernel(
    const _Float16* __restrict__ x16, const int* __restrict__ row_start,
    const int* __restrict__ csr,
    const float* __restrict__ stats, const float* __restrict__ gamma,
    const float* __restrict__ beta, _Float16* __restrict__ outp) {
  __shared__ float sc_s[128], sh_s[128];
  if (AFF) {
    int tt = threadIdx.x;
    if (tt < 128) {
      const float invN = 1.0f / (float)NN;
      float mm = stats[tt] * invN;
      float vv = stats[128 + tt] * invN - mm * mm;
      float rs = rsqrtf(vv + 1e-5f);
      float sc = gamma[tt] * rs;
      sc_s[tt] = sc;
      sh_s[tt] = beta[tt] - mm * sc;
    }
    __syncthreads();
  }
  int node = blockIdx.x * 16 + (threadIdx.x >> 4);  // exact: 3125*16 = 50000
  int t = threadIdx.x & 15;
  const half8* xh8 = (const half8*)x16;  // row = node*16 half8s
  float scv[8], shv[8];
  if (AFF) {
#pragma unroll
    for (int f = 0; f < 8; ++f) { scv[f] = sc_s[t * 8 + f]; shv[f] = sh_s[t * 8 + f]; }
  }
  int s0 = row_start[node], s1 = row_start[node + 1];
  float acc[8] = {0.f, 0.f, 0.f, 0.f, 0.f, 0.f, 0.f, 0.f};
  int j = s0;
  for (; j + 8 <= s1; j += 8) {
    int i0 = csr[j + 0];
    int i1 = csr[j + 1];
    int i2 = csr[j + 2];
    int i3 = csr[j + 3];
    int i4 = csr[j + 4];
    int i5 = csr[j + 5];
    int i6 = csr[j + 6];
    int i7 = csr[j + 7];
    half8 h0 = xh8[(size_t)i0 * 16 + t];
    half8 h1 = xh8[(size_t)i1 * 16 + t];
    half8 h2 = xh8[(size_t)i2 * 16 + t];
    half8 h3 = xh8[(size_t)i3 * 16 + t];
    half8 h4 = xh8[(size_t)i4 * 16 + t];
    half8 h5 = xh8[(size_t)i5 * 16 + t];
    half8 h6 = xh8[(size_t)i6 * 16 + t];
    half8 h7 = xh8[(size_t)i7 * 16 + t];
    acc8<AFF>(acc, h0, scv, shv);
    acc8<AFF>(acc, h1, scv, shv);
    acc8<AFF>(acc, h2, scv, shv);
    acc8<AFF>(acc, h3, scv, shv);
    acc8<AFF>(acc, h4, scv, shv);
    acc8<AFF>(acc, h5, scv, shv);
    acc8<AFF>(acc, h6, scv, shv);
    acc8<AFF>(acc, h7, scv, shv);
  }
  if (j + 4 <= s1) {
    int i0 = csr[j + 0];
    int i1 = csr[j + 1];
    int i2 = csr[j + 2];
    int i3 = csr[j + 3];
    half8 h0 = xh8[(size_t)i0 * 16 + t];
    half8 h1 = xh8[(size_t)i1 * 16 + t];
    half8 h2 = xh8[(size_t)i2 * 16 + t];
    half8 h3 = xh8[(size_t)i3 * 16 + t];
    acc8<AFF>(acc, h0, scv, shv);
    acc8<AFF>(acc, h1, scv, shv);
    acc8<AFF>(acc, h2, scv, shv);
    acc8<AFF>(acc, h3, scv, shv);
    j += 4;
  }
  for (; j < s1; ++j) {
    int i = csr[j];
    half8 h = xh8[(size_t)i * 16 + t];
    acc8<AFF>(acc, h, scv, shv);
  }
  half8 selfh = xh8[(size_t)node * 16 + t];
  half8 hv;
#pragma unroll
  for (int f = 0; f < 8; ++f) {
    float sv = (float)selfh[f];
    if (AFF) sv = fmaxf(fmaf(sv, scv[f], shv[f]), 0.f);
    hv[f] = (_Float16)(acc[f] + sv);
  }
  ((half8*)outp)[(size_t)node * 16 + t] = hv;
}

// ---------------- MFMA GIN GEMM ----------------
// C = f(A) @ W^T + b via v_mfma_f32_16x16x32_f16.
// 4 waves/block; wave w owns cols [32w, 32w+32). B-frags (Wh, natural [o][k]
// layout, k contiguous) loaded once per block into regs. Block grid-strides
// 16-row M tiles (NN = 16*3125 exactly). BN+relu fused on A load; bias +
// fp32/fp16 stores + per-column stats fused in epilogue.
template <bool BN, bool AH>
__global__ __launch_bounds__(256) void gemm_gin_mfma_kernel(
    const float* __restrict__ A, const _Float16* __restrict__ A16,
    const _Float16* __restrict__ Wh,
    const float* __restrict__ bias,
    const float* __restrict__ stats, const float* __restrict__ gamma,
    const float* __restrict__ beta,
    float* __restrict__ C, _Float16* __restrict__ h16out,
    float* __restrict__ ssum, float* __restrict__ ssq) {
  __shared__ float bsc_s[128], bsh_s[128];
  int tid = threadIdx.x;
  if (BN) {
    if (tid < 128) {
      const float invN = 1.0f / (float)NN;
      float mm = stats[tid] * invN;
      float vv = stats[128 + tid] * invN - mm * mm;
      float rs = rsqrtf(vv + 1e-5f);
      float sc = gamma[tid] * rs;
      bsc_s[tid] = sc;
      bsh_s[tid] = beta[tid] - mm * sc;
    }
    __syncthreads();
  }
  int w = tid >> 6, l = tid & 63;
  int lr = l & 15, lg = l >> 4;
  int cb = w * 32;
  half8 bf0[4], bf1[4];
#pragma unroll
  for (int ks = 0; ks < 4; ++ks) {
    int k = ks * 32 + lg * 8;
    bf0[ks] = *(const half8*)(Wh + (size_t)(cb + lr) * 128 + k);
    bf1[ks] = *(const half8*)(Wh + (size_t)(cb + 16 + lr) * 128 + k);
  }
  float bv0 = bias[cb + lr], bv1 = bias[cb + 16 + lr];
  float ps0 = 0.f, pq0 = 0.f, ps1 = 0.f, pq1 = 0.f;
  int t0 = blockIdx.x * 4;
  for (int t = 0; t < 4; ++t) {
    int tile = t0 + t;
    if (tile >= 3125) break;
    int r = tile * 16 + lr;
    half8 af[4];
#pragma unroll
    for (int ks = 0; ks < 4; ++ks) {
      int k0 = ks * 32 + lg * 8;
      if constexpr (AH) {
        half8 ah = *(const half8*)(A16 + (size_t)r * 128 + k0);
        if constexpr (BN) {
          float4 s0 = *(const float4*)&bsc_s[k0];
          float4 s1 = *(const float4*)&bsc_s[k0 + 4];
          float4 h0 = *(const float4*)&bsh_s[k0];
          float4 h1 = *(const float4*)&bsh_s[k0 + 4];
          half8 o;
          o[0] = (_Float16)fmaxf(fmaf((float)ah[0], s0.x, h0.x), 0.f);
          o[1] = (_Float16)fmaxf(fmaf((float)ah[1], s0.y, h0.y), 0.f);
          o[2] = (_Float16)fmaxf(fmaf((float)ah[2], s0.z, h0.z), 0.f);
          o[3] = (_Float16)fmaxf(fmaf((float)ah[3], s0.w, h0.w), 0.f);
          o[4] = (_Float16)fmaxf(fmaf((float)ah[4], s1.x, h1.x), 0.f);
          o[5] = (_Float16)fmaxf(fmaf((float)ah[5], s1.y, h1.y), 0.f);
          o[6] = (_Float16)fmaxf(fmaf((float)ah[6], s1.z, h1.z), 0.f);
          o[7] = (_Float16)fmaxf(fmaf((float)ah[7], s1.w, h1.w), 0.f);
          af[ks] = o;
        } else {
          af[ks] = ah;
        }
      } else {
        float4 a0 = *(const float4*)(A + (size_t)r * 128 + k0);
        float4 a1 = *(const float4*)(A + (size_t)r * 128 + k0 + 4);
        if constexpr (BN) {
          float4 s0 = *(const float4*)&bsc_s[k0];
          float4 s1 = *(const float4*)&bsc_s[k0 + 4];
          float4 h0 = *(const float4*)&bsh_s[k0];
          float4 h1 = *(const float4*)&bsh_s[k0 + 4];
          a0 = aff4(a0, s0, h0);
          a1 = aff4(a1, s1, h1);
        }
        half8 o;
        o[0] = (_Float16)a0.x; o[1] = (_Float16)a0.y;
        o[2] = (_Float16)a0.z; o[3] = (_Float16)a0.w;
        o[4] = (_Float16)a1.x; o[5] = (_Float16)a1.y;
        o[6] = (_Float16)a1.z; o[7] = (_Float16)a1.w;
        af[ks] = o;
      }
    }
    f32x4 acc0 = {0.f, 0.f, 0.f, 0.f};
    f32x4 acc1 = {0.f, 0.f, 0.f, 0.f};
#pragma unroll
    for (int ks = 0; ks < 4; ++ks) {
      acc0 = __builtin_amdgcn_mfma_f32_16x16x32_f16(af[ks], bf0[ks], acc0, 0, 0, 0);
      acc1 = __builtin_amdgcn_mfma_f32_16x16x32_f16(af[ks], bf1[ks], acc1, 0, 0, 0);
    }
#pragma unroll
    for (int i = 0; i < 4; ++i) {
      int rr = tile * 16 + lg * 4 + i;
      float v0 = acc0[i] + bv0;
      float v1 = acc1[i] + bv1;
      if (C) {
        C[(size_t)rr * 128 + cb + lr] = v0;
        C[(size_t)rr * 128 + cb + 16 + lr] = v1;
      }
      if (h16out) {
        h16out[(size_t)rr * 128 + cb + lr] = (_Float16)v0;
        h16out[(size_t)rr * 128 + cb + 16 + lr] = (_Float16)v1;
      }
      ps0 += v0; pq0 += v0 * v0;
      ps1 += v1; pq1 += v1 * v1;
    }
  }
  // reduce per-column partials across the 4 k-groups (lanes l, l^16, l^32, l^48)
  ps0 += __shfl_xor(ps0, 16); ps0 += __shfl_xor(ps0, 32);
  pq0 += __shfl_xor(pq0, 16); pq0 += __shfl_xor(pq0, 32);
  ps1 += __shfl_xor(ps1, 16); ps1 += __shfl_xor(ps1, 32);
  pq1 += __shfl_xor(pq1, 16); pq1 += __shfl_xor(pq1, 32);
  if (lg == 0) {
    atomicAdd(&ssum[cb + lr], ps0);
    atomicAdd(&ssq[cb + lr], pq0);
    atomicAdd(&ssum[cb + 16 + lr], ps1);
    atomicAdd(&ssq[cb + 16 + lr], pq1);
  }
}

// ---------------- fused Set2Set v7: fp16 global x, fdot2 matvec, fp16 LDS x-cache,
// step-0 skip, merged gates-reduce+activation -------
__global__ void __launch_bounds__(1024) set2set_kernel(
    const _Float16* __restrict__ x, const int* __restrict__ gptr,
    const float* __restrict__ stats, const float* __restrict__ gamma,
    const float* __restrict__ beta,
    const _Float16* __restrict__ WT0h, const _Float16* __restrict__ WTRh,
    const float* __restrict__ bc0, const float* __restrict__ bcR,
    float* __restrict__ ebuf,
    const float* __restrict__ linW, const float* __restrict__ linb,
    float* __restrict__ out) {
  __shared__ half2v xs[SEG_CAP * 64];  // 114688 B (448 rows, fp16-packed)
  __shared__ float wpart[16][512];     // 32 KB (aliased as rpart in attention)
  __shared__ half2v inp2[192];         // fp16-packed LSTM input (k-pairs)
  __shared__ float hcs[4][128];
  __shared__ float ccs[4][128];
  __shared__ float qst[256];
  __shared__ float es[ESC];            // 2 KB
  __shared__ float bsc[128], bsh[128];
  __shared__ float wred[16];
  __shared__ float smax_s, ssum_s;
  __shared__ float fred[2][4];

  int g = blockIdx.x, tid = threadIdx.x;
  int w16 = tid >> 6, lane = tid & 63;

  // init
  if (tid < 128) {
    const float invN = 1.0f / (float)NN;
    float mm = stats[tid] * invN;
    float vv = stats[128 + tid] * invN - mm * mm;
    float rs = rsqrtf(vv + 1e-5f);
    float sc = gamma[tid] * rs;
    bsc[tid] = sc;
    bsh[tid] = beta[tid] - mm * sc;
#pragma unroll
    for (int l = 0; l < 4; ++l) { hcs[l][tid] = 0.f; ccs[l][tid] = 0.f; }
  }
  if (tid < 256) qst[tid] = 0.f;
  __syncthreads();

  int s0 = gptr[g], s1 = gptr[g + 1];
  int seg = s1 - s0;
  int ncache = seg < SEG_CAP ? seg : SEG_CAP;
  const half2v* xh = (const half2v*)x;
  float sc0 = bsc[2 * lane], sc1 = bsc[2 * lane + 1];
  float sh0 = bsh[2 * lane], sh1 = bsh[2 * lane + 1];
  // stage segment into LDS once (BN4-transformed, fp16-packed); one row per wave
  for (int n = w16; n < ncache; n += 16) {
    half2v v = xh[(size_t)(s0 + n) * 64 + lane];
    half2v h;
    h[0] = (_Float16)fmaxf(fmaf((float)v[0], sc0, sh0), 0.f);
    h[1] = (_Float16)fmaxf(fmaf((float)v[1], sc1, sh1), 0.f);
    xs[n * 64 + lane] = h;
  }
  __syncthreads();

  int s_ = tid >> 6, cg = tid & 63;  // matvec: K-slice (16), col-group (8 cols)

  for (int step = 0; step < 4; ++step) {
    // ---- 4 stacked LSTM cells ----
    for (int cell = 0; cell < 4; ++cell) {
      const _Float16* WTh; const float* bias; int KP2;
      if (cell == 0) {
        WTh = WT0h; bias = bc0; KP2 = 12;  // K=384 -> 192 k2-pairs, 12 per slice
        if (tid < 192) {
          int k = tid << 1;
          float va, vb;
          if (k < 256) { va = qst[k]; vb = qst[k + 1]; }
          else { va = hcs[0][k - 256]; vb = hcs[0][k - 255]; }
          half2v h; h[0] = (_Float16)va; h[1] = (_Float16)vb;
          inp2[tid] = h;
        }
      } else {
        WTh = WTRh + (size_t)(cell - 1) * 131072;
        bias = bcR + (cell - 1) * 512; KP2 = 8;  // K=256 -> 128 pairs, 8 per slice
        if (tid < 128) {
          int k = tid << 1;
          float va, vb;
          if (k < 128) { va = hcs[cell - 1][k]; vb = hcs[cell - 1][k + 1]; }
          else { va = hcs[cell][k - 128]; vb = hcs[cell][k - 127]; }
          half2v h; h[0] = (_Float16)va; h[1] = (_Float16)vb;
          inp2[tid] = h;
        }
      }
      __syncthreads();
      bool skipmv = (step == 0 && cell == 0);
      if (!skipmv) {
        int se = (s_ + g) & 15;  // rotate slice start per block
        int k20 = se * KP2;
        float a0 = 0.f, a1 = 0.f, a2 = 0.f, a3 = 0.f;
        float a4 = 0.f, a5 = 0.f, a6 = 0.f, a7 = 0.f;
        // step 0, cells>=1: old-h half (k>=128) is zero -> only slices se<8 contribute
        if (step != 0 || se < 8) {
          const char* wb = (const char*)WTh + (size_t)k20 * 2048 + (cg << 5);
#pragma unroll 4
          for (int k2 = 0; k2 < KP2; ++k2) {
            uint4 wa = *(const uint4*)(wb + (size_t)k2 * 2048);
            uint4 wc = *(const uint4*)(wb + (size_t)k2 * 2048 + 16);
            half2v i2 = inp2[k20 + k2];
            a0 = fdot2f(i2, __builtin_bit_cast(half2v, wa.x), a0);
            a1 = fdot2f(i2, __builtin_bit_cast(half2v, wa.y), a1);
            a2 = fdot2f(i2, __builtin_bit_cast(half2v, wa.z), a2);
            a3 = fdot2f(i2, __builtin_bit_cast(half2v, wa.w), a3);
            a4 = fdot2f(i2, __builtin_bit_cast(half2v, wc.x), a4);
            a5 = fdot2f(i2, __builtin_bit_cast(half2v, wc.y), a5);
            a6 = fdot2f(i2, __builtin_bit_cast(half2v, wc.z), a6);
            a7 = fdot2f(i2, __builtin_bit_cast(half2v, wc.w), a7);
          }
        }
        *(float4*)&wpart[s_][cg << 3] = make_float4(a0, a1, a2, a3);
        *(float4*)(&wpart[s_][cg << 3] + 4) = make_float4(a4, a5, a6, a7);
        __syncthreads();
      }
      // merged gates-reduce + activation (128 threads, float4 over 16 slices)
      if (tid < 128) {
        int j = tid;
        float4 ga = *(const float4*)&bias[4 * j];
        if (!skipmv) {
#pragma unroll
          for (int s = 0; s < 16; ++s) {
            float4 wv = *(const float4*)&wpart[s][4 * j];
            ga.x += wv.x; ga.y += wv.y; ga.z += wv.z; ga.w += wv.w;
          }
        }
        float cp = ccs[cell][j];
        float si = fsigm(ga.x);
        float sf = fsigm(ga.y);
        float so = fsigm(ga.w);
        float cn = sf * cp + si * ftanh(ga.z);
        ccs[cell][j] = cn;
        hcs[cell][j] = so * ftanh(cn);
      }
      __syncthreads();
    }
    // ---- attention, q = new h[3]; x from fp16 LDS cache ----
    float* rpart = &wpart[0][0];  // alias: time-disjoint with matvec
    float qx = hcs[3][2 * lane], qy = hcs[3][2 * lane + 1];
    half2v q2; q2[0] = (_Float16)qx; q2[1] = (_Float16)qy;
    // pass 1: e + max
    float wmax = -3.0e38f;
    for (int n = w16; n < seg; n += 16) {
      float e;
      if (n < ncache) {
        e = fdot2f(xs[n * 64 + lane], q2, 0.f);
      } else {
        half2v v = xh[(size_t)(s0 + n) * 64 + lane];
        float vx = fmaxf(fmaf((float)v[0], sc0, sh0), 0.f);
        float vy = fmaxf(fmaf((float)v[1], sc1, sh1), 0.f);
        e = vx * qx + vy * qy;
      }
#pragma unroll
      for (int sh = 32; sh; sh >>= 1) e += __shfl_xor(e, sh);
      if (lane == 0) { if (n < ESC) es[n] = e; else ebuf[s0 + n] = e; }
      wmax = fmaxf(wmax, e);
    }
    if (lane == 0) wred[w16] = wmax;
    __syncthreads();
    if (tid == 0) {
      float m = wred[0];
#pragma unroll
      for (int t = 1; t < 16; ++t) m = fmaxf(m, wred[t]);
      smax_s = m;
    }
    __syncthreads();
    float m = smax_s;
    // pass 2: sum exp (cache exp back into es/ebuf for pass 3)
    float loc = 0.f;
    for (int n = tid; n < seg; n += 1024) {
      float e = (n < ESC) ? es[n] : ebuf[s0 + n];
      float ex = __expf(e - m);
      if (n < ESC) es[n] = ex; else ebuf[s0 + n] = ex;
      loc += ex;
    }
#pragma unroll
    for (int sh = 32; sh; sh >>= 1) loc += __shfl_xor(loc, sh);
    __syncthreads();
    if (lane == 0) wred[w16] = loc;
    __syncthreads();
    if (tid == 0) {
      float s = 0.f;
#pragma unroll
      for (int t = 0; t < 16; ++t) s += wred[t];
      ssum_s = s;
    }
    __syncthreads();
    float inv = 1.0f / ssum_s;
    // pass 3: r = sum a*x
    float rx = 0.f, ry = 0.f;
    for (int n = w16; n < seg; n += 16) {
      float ex = (n < ESC) ? es[n] : ebuf[s0 + n];
      float coef = ex * inv;
      float vx, vy;
      if (n < ncache) {
        half2v v2 = xs[n * 64 + lane];
        vx = (float)v2[0]; vy = (float)v2[1];
      } else {
        half2v v = xh[(size_t)(s0 + n) * 64 + lane];
        vx = fmaxf(fmaf((float)v[0], sc0, sh0), 0.f);
        vy = fmaxf(fmaf((float)v[1], sc1, sh1), 0.f);
      }
      rx += coef * vx; ry += coef * vy;
    }
    rpart[w16 * 128 + 2 * lane] = rx;
    rpart[w16 * 128 + 2 * lane + 1] = ry;
    __syncthreads();
    if (tid < 128) {
      float r = 0.f;
#pragma unroll
      for (int t = 0; t < 16; ++t) r += rpart[t * 128 + tid];
      qst[tid] = hcs[3][tid];
      qst[128 + tid] = r;
    }
    __syncthreads();
  }
  // ---- final linear ----
  if (tid < 256) {
    float val = qst[tid];
    float p0 = val * linW[tid];
    float p1 = val * linW[256 + tid];
#pragma unroll
    for (int sh = 32; sh; sh >>= 1) { p0 += __shfl_xor(p0, sh); p1 += __shfl_xor(p1, sh); }
    if (lane == 0) { fred[0][w16] = p0; fred[1][w16] = p1; }
  }
  __syncthreads();
  if (tid == 0) {
    out[2 * g + 0] = fred[0][0] + fred[0][1] + fred[0][2] + fred[0][3] + linb[0];
    out[2 * g + 1] = fred[1][0] + fred[1][1] + fred[1][2] + fred[1][3] + linb[1];
  }
}

// ---------------- launch ----------------

extern "C" void kernel_launch(void* const* d_in, const int* in_sizes, int n_in,
                              void* d_out, int out_size, void* d_ws, size_t ws_size,
                              hipStream_t stream) {
  const float* x = (const float*)d_in[0];
  const int* ei = (const int*)d_in[1];
  const int* batch = (const int*)d_in[2];
  const float* gW[4]  = {(const float*)d_in[3],  (const float*)d_in[7],
                         (const float*)d_in[11], (const float*)d_in[15]};
  const float* gb[4]  = {(const float*)d_in[4],  (const float*)d_in[8],
                         (const float*)d_in[12], (const float*)d_in[16]};
  const float* gga[4] = {(const float*)d_in[5],  (const float*)d_in[9],
                         (const float*)d_in[13], (const float*)d_in[17]};
  const float* gbe[4] = {(const float*)d_in[6],  (const float*)d_in[10],
                         (const float*)d_in[14], (const float*)d_in[18]};
  const float* Wih0 = (const float*)d_in[19];
  const float* Whh0 = (const float*)d_in[20];
  const float* b0   = (const float*)d_in[21];
  const float* WihR = (const float*)d_in[22];
  const float* WhhR = (const float*)d_in[23];
  const float* bR   = (const float*)d_in[24];
  const float* linW = (const float*)d_in[25];
  const float* linb = (const float*)d_in[26];
  float* out = (float*)d_out;

  char* base = (char*)d_ws;
  size_t off = 0;
  auto allocf = [&](size_t n) { float* p = (float*)(base + off); off += n * sizeof(float); return p; };
  _Float16* agg16 = (_Float16*)(base + off); off += 6400000 * 2;
  _Float16* ginWh = (_Float16*)(base + off); off += 65536 * 2;
  _Float16* WT0h = (_Float16*)(base + off); off += 196608 * 2;
  _Float16* WTRh = (_Float16*)(base + off); off += 393216 * 2;
  _Float16* x16a = (_Float16*)(base + off); off += 6400000 * 2;
  _Float16* x16b = (_Float16*)(base + off); off += 6400000 * 2;
  float* bc0   = allocf(512);
  float* bcR   = allocf(1536);
  float* ebuf  = allocf(50000);
  // ---- zero region: stats only (1024 floats = 256 float4) ----
  float* stats = allocf(1024);     // 4 x (sum128|sq128)
  // ---- ints (all fully written before read; no zeroing needed) ----
  int* row_start = (int*)(base + off); off += 50004 * 4;
  int* gptr = (int*)(base + off); off += 260 * 4;
  int* csr = (int*)(base + off); off += 800000 * 4;
  int* packed = (int*)(base + off); off += 800000 * 4;
  int* partial = (int*)(base + off); off += NBIN * NBLK * 4;
  int* block_base = (int*)(base + off); off += NBIN * NBLK * 4;
  int* total = (int*)(base + off); off += 256 * 4;
  int* coarse_base = (int*)(base + off); off += 260 * 4;
  (void)ws_size; (void)in_sizes; (void)n_in; (void)out_size;

  // merged prep: zero | gptr | hist | weight repack | x->fp16  (grid 2961+6250)
  prep_all_kernel<<<9211, 256, 0, stream>>>(batch, ei, gW[0], gW[1], gW[2], gW[3],
                                            Wih0, Whh0, WihR, WhhR, b0, bR, x,
                                            stats, gptr, partial, ginWh, WT0h, WTRh,
                                            bc0, bcR, x16a);
  scan_partials_kernel<<<NBIN, 256, 0, stream>>>(partial, block_base, total);
  scan_totals_kernel<<<1, 256, 0, stream>>>(total, coarse_base);
  bucket_scatter_kernel<<<NBLK, 256, 0, stream>>>(ei, coarse_base, block_base, packed);
  csr_finalize_kernel<<<NBIN, 256, 0, stream>>>(packed, coarse_base, row_start, csr);

  // GIN layer 1: gather (fp16 in/out), 16 lanes/node
  gin_agg_kernel<false><<<3125, 256, 0, stream>>>(x16a, row_start, csr,
                                                  nullptr, nullptr, nullptr, agg16);
  // gemm1: fp16 agg in, fp16 out only (consumer: gemm2), stats0
  gemm_gin_mfma_kernel<false, true><<<782, 256, 0, stream>>>(
      nullptr, agg16, ginWh + 0 * 16384, gb[0],
      nullptr, nullptr, nullptr,
      nullptr, x16a, stats + 0, stats + 128);
  // gemm2: BN1+relu on fp16 A, fp16 out (consumer: gather2), stats1
  gemm_gin_mfma_kernel<true, true><<<782, 256, 0, stream>>>(
      nullptr, x16a, ginWh + 1 * 16384, gb[1],
      stats + 0, gga[0], gbe[0],
      nullptr, x16b, stats + 256, stats + 384);
  // GIN layer 2: gather with BN2 finalize+affine+relu fused (fp16 in/out)
  gin_agg_kernel<true><<<3125, 256, 0, stream>>>(x16b, row_start, csr,
                                                 stats + 256, gga[1], gbe[1], agg16);
  // gemm3: fp16 agg in, fp16 out only (consumer: gemm4), stats2
  gemm_gin_mfma_kernel<false, true><<<782, 256, 0, stream>>>(
      nullptr, agg16, ginWh + 2 * 16384, gb[2],
      nullptr, nullptr, nullptr,
      nullptr, x16a, stats + 512, stats + 640);
  // gemm4: BN3+relu on fp16 A, fp16 out (consumer: set2set), stats3
  gemm_gin_mfma_kernel<true, true><<<782, 256, 0, stream>>>(
      nullptr, x16a, ginWh + 3 * 16384, gb[3],
      stats + 512, gga[2], gbe[2],
      nullptr, x16b, stats + 768, stats + 896);
  // x16b holds pre-BN4 features (fp16); BN4 fused into set2set x staging

  // fused Set2Set v7 (fp16 x input)
  set2set_kernel<<<256, 1024, 0, stream>>>(x16b, gptr, stats + 768, gga[3], gbe[3],
                                           WT0h, WTRh, bc0, bcR, ebuf, linW, linb, out);
}

// Round 6
// 409.198 us; speedup vs baseline: 1.2615x; 1.0366x over previous
//
#include <hip/hip_runtime.h>
#include <math.h>

#define NN 50000
#define EE 800000
#define BBG 256
#define HHC 128
#define SEG_CAP 448  // LDS x-cache rows per graph (fp16 packed)
#define ESC 512      // per-graph e-cache entries in LDS
#define NBIN 196     // coarse bins of 256 nodes
#define NBLK 196     // blocks in K1/K3 (4096 edges each)

typedef _Float16 half8 __attribute__((ext_vector_type(8)));
typedef _Float16 half4 __attribute__((ext_vector_type(4)));
typedef _Float16 half2v __attribute__((ext_vector_type(2)));
typedef float f32x4 __attribute__((ext_vector_type(4)));

#if defined(__has_builtin)
#if __has_builtin(__builtin_amdgcn_fdot2)
#define USE_FDOT2 1
#endif
#endif

__device__ __forceinline__ float fdot2f(half2v a, half2v b, float c) {
#ifdef USE_FDOT2
  return __builtin_amdgcn_fdot2(a, b, c, false);
#else
  return fmaf((float)a[0], (float)b[0], fmaf((float)a[1], (float)b[1], c));
#endif
}

__device__ __forceinline__ float fsigm(float x) {
  return __builtin_amdgcn_rcpf(1.f + __expf(-x));
}
__device__ __forceinline__ float ftanh(float x) {
  return 1.f - 2.f * __builtin_amdgcn_rcpf(1.f + __expf(2.f * x));
}

__device__ __forceinline__ float4 aff4(float4 v, float4 sc, float4 sh) {
  v.x = fmaxf(fmaf(v.x, sc.x, sh.x), 0.f);
  v.y = fmaxf(fmaf(v.y, sc.y, sh.y), 0.f);
  v.z = fmaxf(fmaf(v.z, sc.z, sh.z), 0.f);
  v.w = fmaxf(fmaf(v.w, sc.w, sh.w), 0.f);
  return v;
}

// ---------------- merged prep: zero | gptr | coarse hist | weight repack | x->fp16 ----
__global__ __launch_bounds__(256) void prep_all_kernel(
    const int* __restrict__ batch,
    const int* __restrict__ ei,
    const float* __restrict__ W0, const float* __restrict__ W1,
    const float* __restrict__ W2, const float* __restrict__ W3,
    const float* __restrict__ Wih0, const float* __restrict__ Whh0,
    const float* __restrict__ WihR, const float* __restrict__ WhhR,
    const float* __restrict__ b0, const float* __restrict__ bR,
    const float* __restrict__ xsrc,
    float* __restrict__ stats, int* __restrict__ gptr, int* __restrict__ partial,
    _Float16* __restrict__ ginWh, _Float16* __restrict__ WT0h,
    _Float16* __restrict__ WTRh, float* __restrict__ bc0, float* __restrict__ bcR,
    _Float16* __restrict__ x16a) {
  __shared__ int hist[NBIN];
  int blk = blockIdx.x, tid = threadIdx.x;
  if (blk == 0) {
    ((float4*)stats)[tid] = make_float4(0.f, 0.f, 0.f, 0.f);  // 1024 floats
    return;
  }
  if (blk <= 196) {  // gptr boundaries
    int i = (blk - 1) * 256 + tid;
    if (i >= NN) return;
    int b = batch[i];
    int prev = (i == 0) ? -1 : batch[i - 1];
    for (int g = prev + 1; g <= b; ++g) gptr[g] = i;
    if (i == NN - 1) {
      for (int g = b + 1; g <= BBG; ++g) gptr[g] = NN;
    }
    return;
  }
  if (blk <= 392) {  // coarse hist
    int b = blk - 197;
    if (tid < NBIN) hist[tid] = 0;
    __syncthreads();
    const int4* dst4 = (const int4*)(ei + EE);
#pragma unroll
    for (int c = 0; c < 4; ++c) {
      int idx = b * 1024 + c * 256 + tid;
      if (idx < EE / 4) {
        int4 d = dst4[idx];
        atomicAdd(&hist[d.x >> 8], 1);
        atomicAdd(&hist[d.y >> 8], 1);
        atomicAdd(&hist[d.z >> 8], 1);
        atomicAdd(&hist[d.w >> 8], 1);
      }
    }
    __syncthreads();
    if (tid < NBIN) partial[tid * NBLK + b] = hist[tid];
    return;
  }
  if (blk >= 2961) {  // x -> fp16 (6250 blocks x 256 = 1,600,000 float4 groups)
    int i = (blk - 2961) * 256 + tid;
    float4 v = ((const float4*)xsrc)[i];
    half4 h;
    h[0] = (_Float16)v.x; h[1] = (_Float16)v.y;
    h[2] = (_Float16)v.z; h[3] = (_Float16)v.w;
    ((half4*)x16a)[i] = h;
    return;
  }
  // weight prep
  int idx = (blk - 393) * 256 + tid;  // [0, 657408)
  if (idx < 65536) {
    int m = idx >> 14;
    int r = idx & 16383;
    const float* W = (m == 0) ? W0 : (m == 1) ? W1 : (m == 2) ? W2 : W3;
    ginWh[idx] = (_Float16)W[r];  // natural [o][k], k contiguous
  } else if (idx < 262144) {
    int t = idx - 65536;
    int k = t >> 9, op = t & 511;
    int j = op >> 2, g = op & 3;
    int row = g * 128 + j;
    float v = (k < 256) ? Wih0[row * 256 + k] : Whh0[row * 128 + (k - 256)];
    WT0h[((k >> 1) << 10) | (op << 1) | (k & 1)] = (_Float16)v;
  } else if (idx < 655360) {
    int t = idx - 262144;
    int l = t >> 17;
    int rem = t & 131071;
    int k = rem >> 9, op = rem & 511;
    int j = op >> 2, g = op & 3;
    int row = g * 128 + j;
    float v = (k < 128) ? WihR[((size_t)l * 512 + row) * 128 + k]
                        : WhhR[((size_t)l * 512 + row) * 128 + (k - 128)];
    WTRh[((size_t)l << 17) | ((k >> 1) << 10) | (op << 1) | (k & 1)] = (_Float16)v;
  } else {
    int t = idx - 655360;
    if (t < 512) {
      bc0[t] = b0[(t & 3) * 128 + (t >> 2)];
    } else {
      int u = t - 512;
      int l = u >> 9, op = u & 511;
      bcR[u] = bR[l * 512 + (op & 3) * 128 + (op >> 2)];
    }
  }
}

// ---- atomic-free CSR build (two-level counting sort) ----

__global__ void scan_partials_kernel(const int* __restrict__ partial,
                                     int* __restrict__ block_base, int* __restrict__ total) {
  __shared__ int buf[256];
  int bin = blockIdx.x, tid = threadIdx.x;
  int v = (tid < NBLK) ? partial[bin * NBLK + tid] : 0;
  buf[tid] = v;
  __syncthreads();
  for (int off = 1; off < 256; off <<= 1) {
    int t = (tid >= off) ? buf[tid - off] : 0;
    __syncthreads();
    buf[tid] += t;
    __syncthreads();
  }
  if (tid < NBLK) block_base[bin * NBLK + tid] = buf[tid] - v;
  if (tid == 255) total[bin] = buf[255];
}

// bucket_scatter with LOCAL scan of total[] (scan_totals kernel removed)
__global__ __launch_bounds__(256) void bucket_scatter_kernel(const int* __restrict__ ei,
                                                             const int* __restrict__ total,
                                                             const int* __restrict__ block_base,
                                                             int* __restrict__ packed) {
  __shared__ int sbuf[256];
  __shared__ int cursor[NBIN];
  int tid = threadIdx.x, b = blockIdx.x;
  int v = (tid < NBIN) ? total[tid] : 0;
  sbuf[tid] = v;
  __syncthreads();
  for (int off = 1; off < 256; off <<= 1) {
    int t = (tid >= off) ? sbuf[tid - off] : 0;
    __syncthreads();
    sbuf[tid] += t;
    __syncthreads();
  }
  if (tid < NBIN) cursor[tid] = (sbuf[tid] - v) + block_base[tid * NBLK + b];
  __syncthreads();
  const int4* src4 = (const int4*)ei;
  const int4* dst4 = (const int4*)(ei + EE);
#pragma unroll
  for (int c = 0; c < 4; ++c) {
    int idx = b * 1024 + c * 256 + tid;
    if (idx < EE / 4) {
      int4 s = src4[idx];
      int4 d = dst4[idx];
      int p;
      p = atomicAdd(&cursor[d.x >> 8], 1); packed[p] = (s.x << 8) | (d.x & 255);
      p = atomicAdd(&cursor[d.y >> 8], 1); packed[p] = (s.y << 8) | (d.y & 255);
      p = atomicAdd(&cursor[d.z >> 8], 1); packed[p] = (s.z << 8) | (d.z & 255);
      p = atomicAdd(&cursor[d.w >> 8], 1); packed[p] = (s.w << 8) | (d.w & 255);
    }
  }
}

// csr_finalize with LOCAL scan of total[] (scan_totals kernel removed)
__global__ __launch_bounds__(256) void csr_finalize_kernel(const int* __restrict__ packed,
                                                           const int* __restrict__ total,
                                                           int* __restrict__ row_start,
                                                           int* __restrict__ csr) {
  __shared__ int fh[256];
  __shared__ int fb[256];
  int bin = blockIdx.x, tid = threadIdx.x;
  // local exclusive scan of total -> e0, e1
  int tv = (tid < NBIN) ? total[tid] : 0;
  fb[tid] = tv;
  __syncthreads();
  for (int off = 1; off < 256; off <<= 1) {
    int t = (tid >= off) ? fb[tid - off] : 0;
    __syncthreads();
    fb[tid] += t;
    __syncthreads();
  }
  int e0 = (bin == 0) ? 0 : fb[bin - 1];
  int e1 = fb[bin];
  __syncthreads();
  fh[tid] = 0;
  __syncthreads();
  for (int e = e0 + tid; e < e1; e += 256) atomicAdd(&fh[packed[e] & 255], 1);
  __syncthreads();
  int v = fh[tid];
  fb[tid] = v;
  __syncthreads();
  for (int off = 1; off < 256; off <<= 1) {
    int t = (tid >= off) ? fb[tid - off] : 0;
    __syncthreads();
    fb[tid] += t;
    __syncthreads();
  }
  int excl = fb[tid] - v;
  int node = bin * 256 + tid;
  if (node < NN) row_start[node] = e0 + excl;
  if (bin == NBIN - 1 && tid == 0) row_start[NN] = EE;
  __syncthreads();
  fb[tid] = excl;  // cursor
  __syncthreads();
  for (int e = e0 + tid; e < e1; e += 256) {
    int p = packed[e];
    int pos = atomicAdd(&fb[p & 255], 1);
    csr[e0 + pos] = p >> 8;
  }
}

// ---------------- fused GIN aggregation + MFMA GEMM ----------------
// Phase A: 256 threads = 16 nodes x 16 channel-chunks; each thread gathers its
// node's neighbor rows (8-deep ILP) for channels 8t..8t+7, fp32 accum, +self,
// optional input-side BN+relu (AFF), fp16 -> LDS As[tile][16][136] (pad 136
// keeps 16B alignment, spreads row stride over banks).
// Phase B: 4 waves; wave w owns cols [32w,32w+32); A-frags from LDS (shared by
// all 4 waves), B-frags from global (natural [o][k]); bias + fp16 store +
// per-column stats in epilogue. Numerically identical to the split kernels.
template <bool AFF>
__global__ __launch_bounds__(256) void agg_gemm_kernel(
    const _Float16* __restrict__ x16, const int* __restrict__ row_start,
    const int* __restrict__ csr,
    const float* __restrict__ stats, const float* __restrict__ gamma,
    const float* __restrict__ beta,
    const _Float16* __restrict__ Wh, const float* __restrict__ bias,
    _Float16* __restrict__ h16out,
    float* __restrict__ ssum, float* __restrict__ ssq) {
  __shared__ _Float16 As[4][16][136];
  __shared__ float sc_s[128], sh_s[128];
  int tid = threadIdx.x;
  if (AFF) {
    if (tid < 128) {
      const float invN = 1.0f / (float)NN;
      float mm = stats[tid] * invN;
      float vv = stats[128 + tid] * invN - mm * mm;
      float rs = rsqrtf(vv + 1e-5f);
      float sc = gamma[tid] * rs;
      sc_s[tid] = sc;
      sh_s[tid] = beta[tid] - mm * sc;
    }
    __syncthreads();
  }
  int tile0 = blockIdx.x * 4;
  // ---- phase A: gather ----
  {
    int nloc = tid >> 4;  // 0..15
    int t = tid & 15;     // channel chunk
    const half8* xh8 = (const half8*)x16;
    float scv[8], shv[8];
    if (AFF) {
#pragma unroll
      for (int f = 0; f < 8; ++f) { scv[f] = sc_s[t * 8 + f]; shv[f] = sh_s[t * 8 + f]; }
    }
    for (int tt = 0; tt < 4; ++tt) {
      int tile = tile0 + tt;
      if (tile >= 3125) break;
      int node = tile * 16 + nloc;
      int s0 = row_start[node], s1 = row_start[node + 1];
      float acc[8] = {0.f, 0.f, 0.f, 0.f, 0.f, 0.f, 0.f, 0.f};
      int j = s0;
      for (; j + 8 <= s1; j += 8) {
        int i0 = csr[j + 0];
        int i1 = csr[j + 1];
        int i2 = csr[j + 2];
        int i3 = csr[j + 3];
        int i4 = csr[j + 4];
        int i5 = csr[j + 5];
        int i6 = csr[j + 6];
        int i7 = csr[j + 7];
        half8 h0 = xh8[(size_t)i0 * 16 + t];
        half8 h1 = xh8[(size_t)i1 * 16 + t];
        half8 h2 = xh8[(size_t)i2 * 16 + t];
        half8 h3 = xh8[(size_t)i3 * 16 + t];
        half8 h4 = xh8[(size_t)i4 * 16 + t];
        half8 h5 = xh8[(size_t)i5 * 16 + t];
        half8 h6 = xh8[(size_t)i6 * 16 + t];
        half8 h7 = xh8[(size_t)i7 * 16 + t];
#pragma unroll
        for (int f = 0; f < 8; ++f) {
          if (AFF) {
            acc[f] += fmaxf(fmaf((float)h0[f], scv[f], shv[f]), 0.f);
            acc[f] += fmaxf(fmaf((float)h1[f], scv[f], shv[f]), 0.f);
            acc[f] += fmaxf(fmaf((float)h2[f], scv[f], shv[f]), 0.f);
            acc[f] += fmaxf(fmaf((float)h3[f], scv[f], shv[f]), 0.f);
            acc[f] += fmaxf(fmaf((float)h4[f], scv[f], shv[f]), 0.f);
            acc[f] += fmaxf(fmaf((float)h5[f], scv[f], shv[f]), 0.f);
            acc[f] += fmaxf(fmaf((float)h6[f], scv[f], shv[f]), 0.f);
            acc[f] += fmaxf(fmaf((float)h7[f], scv[f], shv[f]), 0.f);
          } else {
            acc[f] += (((float)h0[f] + (float)h1[f]) + ((float)h2[f] + (float)h3[f])) +
                      (((float)h4[f] + (float)h5[f]) + ((float)h6[f] + (float)h7[f]));
          }
        }
      }
      if (j + 4 <= s1) {
        int i0 = csr[j + 0];
        int i1 = csr[j + 1];
        int i2 = csr[j + 2];
        int i3 = csr[j + 3];
        half8 h0 = xh8[(size_t)i0 * 16 + t];
        half8 h1 = xh8[(size_t)i1 * 16 + t];
        half8 h2 = xh8[(size_t)i2 * 16 + t];
        half8 h3 = xh8[(size_t)i3 * 16 + t];
#pragma unroll
        for (int f = 0; f < 8; ++f) {
          if (AFF) {
            acc[f] += fmaxf(fmaf((float)h0[f], scv[f], shv[f]), 0.f);
            acc[f] += fmaxf(fmaf((float)h1[f], scv[f], shv[f]), 0.f);
            acc[f] += fmaxf(fmaf((float)h2[f], scv[f], shv[f]), 0.f);
            acc[f] += fmaxf(fmaf((float)h3[f], scv[f], shv[f]), 0.f);
          } else {
            acc[f] += ((float)h0[f] + (float)h1[f]) + ((float)h2[f] + (float)h3[f]);
          }
        }
        j += 4;
      }
      for (; j < s1; ++j) {
        int i = csr[j];
        half8 h = xh8[(size_t)i * 16 + t];
#pragma unroll
        for (int f = 0; f < 8; ++f) {
          float v = (float)h[f];
          if (AFF) v = fmaxf(fmaf(v, scv[f], shv[f]), 0.f);
          acc[f] += v;
        }
      }
      half8 selfh = xh8[(size_t)node * 16 + t];
      half8 hv;
#pragma unroll
      for (int f = 0; f < 8; ++f) {
        float sv = (float)selfh[f];
        if (AFF) sv = fmaxf(fmaf(sv, scv[f], shv[f]), 0.f);
        hv[f] = (_Float16)(acc[f] + sv);
      }
      *(half8*)&As[tt][nloc][t * 8] = hv;
    }
  }
  __syncthreads();
  // ---- phase B: MFMA ----
  int w = tid >> 6, l = tid & 63;
  int lr = l & 15, lg = l >> 4;
  int cb = w * 32;
  half8 bf0[4], bf1[4];
#pragma unroll
  for (int ks = 0; ks < 4; ++ks) {
    int k = ks * 32 + lg * 8;
    bf0[ks] = *(const half8*)(Wh + (size_t)(cb + lr) * 128 + k);
    bf1[ks] = *(const half8*)(Wh + (size_t)(cb + 16 + lr) * 128 + k);
  }
  float bv0 = bias[cb + lr], bv1 = bias[cb + 16 + lr];
  float ps0 = 0.f, pq0 = 0.f, ps1 = 0.f, pq1 = 0.f;
  for (int tt = 0; tt < 4; ++tt) {
    int tile = tile0 + tt;
    if (tile >= 3125) break;
    half8 af[4];
#pragma unroll
    for (int ks = 0; ks < 4; ++ks) {
      af[ks] = *(const half8*)&As[tt][lr][ks * 32 + lg * 8];
    }
    f32x4 acc0 = {0.f, 0.f, 0.f, 0.f};
    f32x4 acc1 = {0.f, 0.f, 0.f, 0.f};
#pragma unroll
    for (int ks = 0; ks < 4; ++ks) {
      acc0 = __builtin_amdgcn_mfma_f32_16x16x32_f16(af[ks], bf0[ks], acc0, 0, 0, 0);
      acc1 = __builtin_amdgcn_mfma_f32_16x16x32_f16(af[ks], bf1[ks], acc1, 0, 0, 0);
    }
#pragma unroll
    for (int i = 0; i < 4; ++i) {
      int rr = tile * 16 + lg * 4 + i;
      float v0 = acc0[i] + bv0;
      float v1 = acc1[i] + bv1;
      h16out[(size_t)rr * 128 + cb + lr] = (_Float16)v0;
      h16out[(size_t)rr * 128 + cb + 16 + lr] = (_Float16)v1;
      ps0 += v0; pq0 += v0 * v0;
      ps1 += v1; pq1 += v1 * v1;
    }
  }
  ps0 += __shfl_xor(ps0, 16); ps0 += __shfl_xor(ps0, 32);
  pq0 += __shfl_xor(pq0, 16); pq0 += __shfl_xor(pq0, 32);
  ps1 += __shfl_xor(ps1, 16); ps1 += __shfl_xor(ps1, 32);
  pq1 += __shfl_xor(pq1, 16); pq1 += __shfl_xor(pq1, 32);
  if (lg == 0) {
    atomicAdd(&ssum[cb + lr], ps0);
    atomicAdd(&ssq[cb + lr], pq0);
    atomicAdd(&ssum[cb + 16 + lr], ps1);
    atomicAdd(&ssq[cb + 16 + lr], pq1);
  }
}

// ---------------- MFMA GIN GEMM (BN+relu on fp16 A) ----------------
template <bool BN>
__global__ __launch_bounds__(256) void gemm_gin_mfma_kernel(
    const _Float16* __restrict__ A16,
    const _Float16* __restrict__ Wh,
    const float* __restrict__ bias,
    const float* __restrict__ stats, const float* __restrict__ gamma,
    const float* __restrict__ beta,
    _Float16* __restrict__ h16out,
    float* __restrict__ ssum, float* __restrict__ ssq) {
  __shared__ float bsc_s[128], bsh_s[128];
  int tid = threadIdx.x;
  if (BN) {
    if (tid < 128) {
      const float invN = 1.0f / (float)NN;
      float mm = stats[tid] * invN;
      float vv = stats[128 + tid] * invN - mm * mm;
      float rs = rsqrtf(vv + 1e-5f);
      float sc = gamma[tid] * rs;
      bsc_s[tid] = sc;
      bsh_s[tid] = beta[tid] - mm * sc;
    }
    __syncthreads();
  }
  int w = tid >> 6, l = tid & 63;
  int lr = l & 15, lg = l >> 4;
  int cb = w * 32;
  half8 bf0[4], bf1[4];
#pragma unroll
  for (int ks = 0; ks < 4; ++ks) {
    int k = ks * 32 + lg * 8;
    bf0[ks] = *(const half8*)(Wh + (size_t)(cb + lr) * 128 + k);
    bf1[ks] = *(const half8*)(Wh + (size_t)(cb + 16 + lr) * 128 + k);
  }
  float bv0 = bias[cb + lr], bv1 = bias[cb + 16 + lr];
  float ps0 = 0.f, pq0 = 0.f, ps1 = 0.f, pq1 = 0.f;
  int t0 = blockIdx.x * 4;
  for (int t = 0; t < 4; ++t) {
    int tile = t0 + t;
    if (tile >= 3125) break;
    int r = tile * 16 + lr;
    half8 af[4];
#pragma unroll
    for (int ks = 0; ks < 4; ++ks) {
      int k0 = ks * 32 + lg * 8;
      half8 ah = *(const half8*)(A16 + (size_t)r * 128 + k0);
      if constexpr (BN) {
        float4 s0 = *(const float4*)&bsc_s[k0];
        float4 s1 = *(const float4*)&bsc_s[k0 + 4];
        float4 h0 = *(const float4*)&bsh_s[k0];
        float4 h1 = *(const float4*)&bsh_s[k0 + 4];
        half8 o;
        o[0] = (_Float16)fmaxf(fmaf((float)ah[0], s0.x, h0.x), 0.f);
        o[1] = (_Float16)fmaxf(fmaf((float)ah[1], s0.y, h0.y), 0.f);
        o[2] = (_Float16)fmaxf(fmaf((float)ah[2], s0.z, h0.z), 0.f);
        o[3] = (_Float16)fmaxf(fmaf((float)ah[3], s0.w, h0.w), 0.f);
        o[4] = (_Float16)fmaxf(fmaf((float)ah[4], s1.x, h1.x), 0.f);
        o[5] = (_Float16)fmaxf(fmaf((float)ah[5], s1.y, h1.y), 0.f);
        o[6] = (_Float16)fmaxf(fmaf((float)ah[6], s1.z, h1.z), 0.f);
        o[7] = (_Float16)fmaxf(fmaf((float)ah[7], s1.w, h1.w), 0.f);
        af[ks] = o;
      } else {
        af[ks] = ah;
      }
    }
    f32x4 acc0 = {0.f, 0.f, 0.f, 0.f};
    f32x4 acc1 = {0.f, 0.f, 0.f, 0.f};
#pragma unroll
    for (int ks = 0; ks < 4; ++ks) {
      acc0 = __builtin_amdgcn_mfma_f32_16x16x32_f16(af[ks], bf0[ks], acc0, 0, 0, 0);
      acc1 = __builtin_amdgcn_mfma_f32_16x16x32_f16(af[ks], bf1[ks], acc1, 0, 0, 0);
    }
#pragma unroll
    for (int i = 0; i < 4; ++i) {
      int rr = tile * 16 + lg * 4 + i;
      float v0 = acc0[i] + bv0;
      float v1 = acc1[i] + bv1;
      h16out[(size_t)rr * 128 + cb + lr] = (_Float16)v0;
      h16out[(size_t)rr * 128 + cb + 16 + lr] = (_Float16)v1;
      ps0 += v0; pq0 += v0 * v0;
      ps1 += v1; pq1 += v1 * v1;
    }
  }
  ps0 += __shfl_xor(ps0, 16); ps0 += __shfl_xor(ps0, 32);
  pq0 += __shfl_xor(pq0, 16); pq0 += __shfl_xor(pq0, 32);
  ps1 += __shfl_xor(ps1, 16); ps1 += __shfl_xor(ps1, 32);
  pq1 += __shfl_xor(pq1, 16); pq1 += __shfl_xor(pq1, 32);
  if (lg == 0) {
    atomicAdd(&ssum[cb + lr], ps0);
    atomicAdd(&ssq[cb + lr], pq0);
    atomicAdd(&ssum[cb + 16 + lr], ps1);
    atomicAdd(&ssq[cb + 16 + lr], pq1);
  }
}

// ---------------- fused Set2Set v7: fp16 global x, fdot2 matvec, fp16 LDS x-cache,
// step-0 skip, merged gates-reduce+activation -------
__global__ void __launch_bounds__(1024) set2set_kernel(
    const _Float16* __restrict__ x, const int* __restrict__ gptr,
    const float* __restrict__ stats, const float* __restrict__ gamma,
    const float* __restrict__ beta,
    const _Float16* __restrict__ WT0h, const _Float16* __restrict__ WTRh,
    const float* __restrict__ bc0, const float* __restrict__ bcR,
    float* __restrict__ ebuf,
    const float* __restrict__ linW, const float* __restrict__ linb,
    float* __restrict__ out) {
  __shared__ half2v xs[SEG_CAP * 64];  // 114688 B (448 rows, fp16-packed)
  __shared__ float wpart[16][512];     // 32 KB (aliased as rpart in attention)
  __shared__ half2v inp2[192];         // fp16-packed LSTM input (k-pairs)
  __shared__ float hcs[4][128];
  __shared__ float ccs[4][128];
  __shared__ float qst[256];
  __shared__ float es[ESC];            // 2 KB
  __shared__ float bsc[128], bsh[128];
  __shared__ float wred[16];
  __shared__ float smax_s, ssum_s;
  __shared__ float fred[2][4];

  int g = blockIdx.x, tid = threadIdx.x;
  int w16 = tid >> 6, lane = tid & 63;

  // init
  if (tid < 128) {
    const float invN = 1.0f / (float)NN;
    float mm = stats[tid] * invN;
    float vv = stats[128 + tid] * invN - mm * mm;
    float rs = rsqrtf(vv + 1e-5f);
    float sc = gamma[tid] * rs;
    bsc[tid] = sc;
    bsh[tid] = beta[tid] - mm * sc;
#pragma unroll
    for (int l = 0; l < 4; ++l) { hcs[l][tid] = 0.f; ccs[l][tid] = 0.f; }
  }
  if (tid < 256) qst[tid] = 0.f;
  __syncthreads();

  int s0 = gptr[g], s1 = gptr[g + 1];
  int seg = s1 - s0;
  int ncache = seg < SEG_CAP ? seg : SEG_CAP;
  const half2v* xh = (const half2v*)x;
  float sc0 = bsc[2 * lane], sc1 = bsc[2 * lane + 1];
  float sh0 = bsh[2 * lane], sh1 = bsh[2 * lane + 1];
  // stage segment into LDS once (BN4-transformed, fp16-packed); one row per wave
  for (int n = w16; n < ncache; n += 16) {
    half2v v = xh[(size_t)(s0 + n) * 64 + lane];
    half2v h;
    h[0] = (_Float16)fmaxf(fmaf((float)v[0], sc0, sh0), 0.f);
    h[1] = (_Float16)fmaxf(fmaf((float)v[1], sc1, sh1), 0.f);
    xs[n * 64 + lane] = h;
  }
  __syncthreads();

  int s_ = tid >> 6, cg = tid & 63;  // matvec: K-slice (16), col-group (8 cols)

  for (int step = 0; step < 4; ++step) {
    // ---- 4 stacked LSTM cells ----
    for (int cell = 0; cell < 4; ++cell) {
      const _Float16* WTh; const float* bias; int KP2;
      if (cell == 0) {
        WTh = WT0h; bias = bc0; KP2 = 12;  // K=384 -> 192 k2-pairs, 12 per slice
        if (tid < 192) {
          int k = tid << 1;
          float va, vb;
          if (k < 256) { va = qst[k]; vb = qst[k + 1]; }
          else { va = hcs[0][k - 256]; vb = hcs[0][k - 255]; }
          half2v h; h[0] = (_Float16)va; h[1] = (_Float16)vb;
          inp2[tid] = h;
        }
      } else {
        WTh = WTRh + (size_t)(cell - 1) * 131072;
        bias = bcR + (cell - 1) * 512; KP2 = 8;  // K=256 -> 128 pairs, 8 per slice
        if (tid < 128) {
          int k = tid << 1;
          float va, vb;
          if (k < 128) { va = hcs[cell - 1][k]; vb = hcs[cell - 1][k + 1]; }
          else { va = hcs[cell][k - 128]; vb = hcs[cell][k - 127]; }
          half2v h; h[0] = (_Float16)va; h[1] = (_Float16)vb;
          inp2[tid] = h;
        }
      }
      __syncthreads();
      bool skipmv = (step == 0 && cell == 0);
      if (!skipmv) {
        int se = (s_ + g) & 15;  // rotate slice start per block
        int k20 = se * KP2;
        float a0 = 0.f, a1 = 0.f, a2 = 0.f, a3 = 0.f;
        float a4 = 0.f, a5 = 0.f, a6 = 0.f, a7 = 0.f;
        // step 0, cells>=1: old-h half (k>=128) is zero -> only slices se<8 contribute
        if (step != 0 || se < 8) {
          const char* wb = (const char*)WTh + (size_t)k20 * 2048 + (cg << 5);
#pragma unroll 4
          for (int k2 = 0; k2 < KP2; ++k2) {
            uint4 wa = *(const uint4*)(wb + (size_t)k2 * 2048);
            uint4 wc = *(const uint4*)(wb + (size_t)k2 * 2048 + 16);
            half2v i2 = inp2[k20 + k2];
            a0 = fdot2f(i2, __builtin_bit_cast(half2v, wa.x), a0);
            a1 = fdot2f(i2, __builtin_bit_cast(half2v, wa.y), a1);
            a2 = fdot2f(i2, __builtin_bit_cast(half2v, wa.z), a2);
            a3 = fdot2f(i2, __builtin_bit_cast(half2v, wa.w), a3);
            a4 = fdot2f(i2, __builtin_bit_cast(half2v, wc.x), a4);
            a5 = fdot2f(i2, __builtin_bit_cast(half2v, wc.y), a5);
            a6 = fdot2f(i2, __builtin_bit_cast(half2v, wc.z), a6);
            a7 = fdot2f(i2, __builtin_bit_cast(half2v, wc.w), a7);
          }
        }
        *(float4*)&wpart[s_][cg << 3] = make_float4(a0, a1, a2, a3);
        *(float4*)(&wpart[s_][cg << 3] + 4) = make_float4(a4, a5, a6, a7);
        __syncthreads();
      }
      // merged gates-reduce + activation (128 threads, float4 over 16 slices)
      if (tid < 128) {
        int j = tid;
        float4 ga = *(const float4*)&bias[4 * j];
        if (!skipmv) {
#pragma unroll
          for (int s = 0; s < 16; ++s) {
            float4 wv = *(const float4*)&wpart[s][4 * j];
            ga.x += wv.x; ga.y += wv.y; ga.z += wv.z; ga.w += wv.w;
          }
        }
        float cp = ccs[cell][j];
        float si = fsigm(ga.x);
        float sf = fsigm(ga.y);
        float so = fsigm(ga.w);
        float cn = sf * cp + si * ftanh(ga.z);
        ccs[cell][j] = cn;
        hcs[cell][j] = so * ftanh(cn);
      }
      __syncthreads();
    }
    // ---- attention, q = new h[3]; x from fp16 LDS cache ----
    float* rpart = &wpart[0][0];  // alias: time-disjoint with matvec
    float qx = hcs[3][2 * lane], qy = hcs[3][2 * lane + 1];
    half2v q2; q2[0] = (_Float16)qx; q2[1] = (_Float16)qy;
    // pass 1: e + max
    float wmax = -3.0e38f;
    for (int n = w16; n < seg; n += 16) {
      float e;
      if (n < ncache) {
        e = fdot2f(xs[n * 64 + lane], q2, 0.f);
      } else {
        half2v v = xh[(size_t)(s0 + n) * 64 + lane];
        float vx = fmaxf(fmaf((float)v[0], sc0, sh0), 0.f);
        float vy = fmaxf(fmaf((float)v[1], sc1, sh1), 0.f);
        e = vx * qx + vy * qy;
      }
#pragma unroll
      for (int sh = 32; sh; sh >>= 1) e += __shfl_xor(e, sh);
      if (lane == 0) { if (n < ESC) es[n] = e; else ebuf[s0 + n] = e; }
      wmax = fmaxf(wmax, e);
    }
    if (lane == 0) wred[w16] = wmax;
    __syncthreads();
    if (tid == 0) {
      float m = wred[0];
#pragma unroll
      for (int t = 1; t < 16; ++t) m = fmaxf(m, wred[t]);
      smax_s = m;
    }
    __syncthreads();
    float m = smax_s;
    // pass 2: sum exp (cache exp back into es/ebuf for pass 3)
    float loc = 0.f;
    for (int n = tid; n < seg; n += 1024) {
      float e = (n < ESC) ? es[n] : ebuf[s0 + n];
      float ex = __expf(e - m);
      if (n < ESC) es[n] = ex; else ebuf[s0 + n] = ex;
      loc += ex;
    }
#pragma unroll
    for (int sh = 32; sh; sh >>= 1) loc += __shfl_xor(loc, sh);
    __syncthreads();
    if (lane == 0) wred[w16] = loc;
    __syncthreads();
    if (tid == 0) {
      float s = 0.f;
#pragma unroll
      for (int t = 0; t < 16; ++t) s += wred[t];
      ssum_s = s;
    }
    __syncthreads();
    float inv = 1.0f / ssum_s;
    // pass 3: r = sum a*x
    float rx = 0.f, ry = 0.f;
    for (int n = w16; n < seg; n += 16) {
      float ex = (n < ESC) ? es[n] : ebuf[s0 + n];
      float coef = ex * inv;
      float vx, vy;
      if (n < ncache) {
        half2v v2 = xs[n * 64 + lane];
        vx = (float)v2[0]; vy = (float)v2[1];
      } else {
        half2v v = xh[(size_t)(s0 + n) * 64 + lane];
        vx = fmaxf(fmaf((float)v[0], sc0, sh0), 0.f);
        vy = fmaxf(fmaf((float)v[1], sc1, sh1), 0.f);
      }
      rx += coef * vx; ry += coef * vy;
    }
    rpart[w16 * 128 + 2 * lane] = rx;
    rpart[w16 * 128 + 2 * lane + 1] = ry;
    __syncthreads();
    if (tid < 128) {
      float r = 0.f;
#pragma unroll
      for (int t = 0; t < 16; ++t) r += rpart[t * 128 + tid];
      qst[tid] = hcs[3][tid];
      qst[128 + tid] = r;
    }
    __syncthreads();
  }
  // ---- final linear ----
  if (tid < 256) {
    float val = qst[tid];
    float p0 = val * linW[tid];
    float p1 = val * linW[256 + tid];
#pragma unroll
    for (int sh = 32; sh; sh >>= 1) { p0 += __shfl_xor(p0, sh); p1 += __shfl_xor(p1, sh); }
    if (lane == 0) { fred[0][w16] = p0; fred[1][w16] = p1; }
  }
  __syncthreads();
  if (tid == 0) {
    out[2 * g + 0] = fred[0][0] + fred[0][1] + fred[0][2] + fred[0][3] + linb[0];
    out[2 * g + 1] = fred[1][0] + fred[1][1] + fred[1][2] + fred[1][3] + linb[1];
  }
}

// ---------------- launch ----------------

extern "C" void kernel_launch(void* const* d_in, const int* in_sizes, int n_in,
                              void* d_out, int out_size, void* d_ws, size_t ws_size,
                              hipStream_t stream) {
  const float* x = (const float*)d_in[0];
  const int* ei = (const int*)d_in[1];
  const int* batch = (const int*)d_in[2];
  const float* gW[4]  = {(const float*)d_in[3],  (const float*)d_in[7],
                         (const float*)d_in[11], (const float*)d_in[15]};
  const float* gb[4]  = {(const float*)d_in[4],  (const float*)d_in[8],
                         (const float*)d_in[12], (const float*)d_in[16]};
  const float* gga[4] = {(const float*)d_in[5],  (const float*)d_in[9],
                         (const float*)d_in[13], (const float*)d_in[17]};
  const float* gbe[4] = {(const float*)d_in[6],  (const float*)d_in[10],
                         (const float*)d_in[14], (const float*)d_in[18]};
  const float* Wih0 = (const float*)d_in[19];
  const float* Whh0 = (const float*)d_in[20];
  const float* b0   = (const float*)d_in[21];
  const float* WihR = (const float*)d_in[22];
  const float* WhhR = (const float*)d_in[23];
  const float* bR   = (const float*)d_in[24];
  const float* linW = (const float*)d_in[25];
  const float* linb = (const float*)d_in[26];
  float* out = (float*)d_out;

  char* base = (char*)d_ws;
  size_t off = 0;
  auto allocf = [&](size_t n) { float* p = (float*)(base + off); off += n * sizeof(float); return p; };
  _Float16* bufA = (_Float16*)(base + off); off += 6400000 * 2;  // prep x16 / gemm4 out
  _Float16* bufB = (_Float16*)(base + off); off += 6400000 * 2;  // aggemm1 out / aggemm2 out
  _Float16* bufC = (_Float16*)(base + off); off += 6400000 * 2;  // gemm2 out
  _Float16* ginWh = (_Float16*)(base + off); off += 65536 * 2;
  _Float16* WT0h = (_Float16*)(base + off); off += 196608 * 2;
  _Float16* WTRh = (_Float16*)(base + off); off += 393216 * 2;
  float* bc0   = allocf(512);
  float* bcR   = allocf(1536);
  float* ebuf  = allocf(50000);
  // ---- zero region: stats only (1024 floats = 256 float4) ----
  float* stats = allocf(1024);     // 4 x (sum128|sq128)
  // ---- ints (all fully written before read; no zeroing needed) ----
  int* row_start = (int*)(base + off); off += 50004 * 4;
  int* gptr = (int*)(base + off); off += 260 * 4;
  int* csr = (int*)(base + off); off += 800000 * 4;
  int* packed = (int*)(base + off); off += 800000 * 4;
  int* partial = (int*)(base + off); off += NBIN * NBLK * 4;
  int* block_base = (int*)(base + off); off += NBIN * NBLK * 4;
  int* total = (int*)(base + off); off += 256 * 4;
  (void)ws_size; (void)in_sizes; (void)n_in; (void)out_size;

  // merged prep: zero | gptr | hist | weight repack | x->fp16
  prep_all_kernel<<<9211, 256, 0, stream>>>(batch, ei, gW[0], gW[1], gW[2], gW[3],
                                            Wih0, Whh0, WihR, WhhR, b0, bR, x,
                                            stats, gptr, partial, ginWh, WT0h, WTRh,
                                            bc0, bcR, bufA);
  scan_partials_kernel<<<NBIN, 256, 0, stream>>>(partial, block_base, total);
  bucket_scatter_kernel<<<NBLK, 256, 0, stream>>>(ei, total, block_base, packed);
  csr_finalize_kernel<<<NBIN, 256, 0, stream>>>(packed, total, row_start, csr);

  // GIN layer 1: fused gather+gemm1 (reads bufA, writes bufB), stats0
  agg_gemm_kernel<false><<<782, 256, 0, stream>>>(
      bufA, row_start, csr,
      nullptr, nullptr, nullptr,
      ginWh + 0 * 16384, gb[0],
      bufB, stats + 0, stats + 128);
  // gemm2: BN1+relu on bufB, writes bufC, stats1
  gemm_gin_mfma_kernel<true><<<782, 256, 0, stream>>>(
      bufB, ginWh + 1 * 16384, gb[1],
      stats + 0, gga[0], gbe[0],
      bufC, stats + 256, stats + 384);
  // GIN layer 2: fused gather(BN2+relu on bufC)+gemm3 (writes bufB), stats2
  agg_gemm_kernel<true><<<782, 256, 0, stream>>>(
      bufC, row_start, csr,
      stats + 256, gga[1], gbe[1],
      ginWh + 2 * 16384, gb[2],
      bufB, stats + 512, stats + 640);
  // gemm4: BN3+relu on bufB, writes bufA (set2set input), stats3
  gemm_gin_mfma_kernel<true><<<782, 256, 0, stream>>>(
      bufB, ginWh + 3 * 16384, gb[3],
      stats + 512, gga[2], gbe[2],
      bufA, stats + 768, stats + 896);
  // bufA holds pre-BN4 features (fp16); BN4 fused into set2set x staging

  // fused Set2Set v7 (fp16 x input)
  set2set_kernel<<<256, 1024, 0, stream>>>(bufA, gptr, stats + 768, gga[3], gbe[3],
                                           WT0h, WTRh, bc0, bcR, ebuf, linW, linb, out);
}

// Round 7
// 406.130 us; speedup vs baseline: 1.2711x; 1.0076x over previous
//
#include <hip/hip_runtime.h>
#include <math.h>

#define NN 50000
#define EE 800000
#define BBG 256
#define HHC 128
#define SEG_CAP 448  // LDS x-cache rows per graph (fp16 packed)
#define ESC 512      // per-graph e-cache entries in LDS
#define NBIN 196     // coarse bins of 256 nodes
#define NBLK 196     // blocks in K1/K3 (4096 edges each)

typedef _Float16 half8 __attribute__((ext_vector_type(8)));
typedef _Float16 half4 __attribute__((ext_vector_type(4)));
typedef _Float16 half2v __attribute__((ext_vector_type(2)));
typedef float f32x4 __attribute__((ext_vector_type(4)));

#if defined(__has_builtin)
#if __has_builtin(__builtin_amdgcn_fdot2)
#define USE_FDOT2 1
#endif
#endif

__device__ __forceinline__ float fdot2f(half2v a, half2v b, float c) {
#ifdef USE_FDOT2
  return __builtin_amdgcn_fdot2(a, b, c, false);
#else
  return fmaf((float)a[0], (float)b[0], fmaf((float)a[1], (float)b[1], c));
#endif
}

__device__ __forceinline__ float fsigm(float x) {
  return __builtin_amdgcn_rcpf(1.f + __expf(-x));
}
__device__ __forceinline__ float ftanh(float x) {
  return 1.f - 2.f * __builtin_amdgcn_rcpf(1.f + __expf(2.f * x));
}

// monotonic float<->uint key for atomicMax-based float max
__device__ __forceinline__ unsigned keyf(float f) {
  unsigned u = __float_as_uint(f);
  return (u & 0x80000000u) ? ~u : (u | 0x80000000u);
}
__device__ __forceinline__ float unkeyf(unsigned k) {
  return (k & 0x80000000u) ? __uint_as_float(k ^ 0x80000000u) : __uint_as_float(~k);
}

__device__ __forceinline__ float4 aff4(float4 v, float4 sc, float4 sh) {
  v.x = fmaxf(fmaf(v.x, sc.x, sh.x), 0.f);
  v.y = fmaxf(fmaf(v.y, sc.y, sh.y), 0.f);
  v.z = fmaxf(fmaf(v.z, sc.z, sh.z), 0.f);
  v.w = fmaxf(fmaf(v.w, sc.w, sh.w), 0.f);
  return v;
}

// ---------------- merged prep: zero | gptr | coarse hist | weight repack | x->fp16 ----
__global__ __launch_bounds__(256) void prep_all_kernel(
    const int* __restrict__ batch,
    const int* __restrict__ ei,
    const float* __restrict__ W0, const float* __restrict__ W1,
    const float* __restrict__ W2, const float* __restrict__ W3,
    const float* __restrict__ Wih0, const float* __restrict__ Whh0,
    const float* __restrict__ WihR, const float* __restrict__ WhhR,
    const float* __restrict__ b0, const float* __restrict__ bR,
    const float* __restrict__ xsrc,
    float* __restrict__ stats, int* __restrict__ gptr, int* __restrict__ partial,
    _Float16* __restrict__ ginWh, _Float16* __restrict__ WT0h,
    _Float16* __restrict__ WTRh, float* __restrict__ bc0, float* __restrict__ bcR,
    _Float16* __restrict__ x16a) {
  __shared__ int hist[NBIN];
  int blk = blockIdx.x, tid = threadIdx.x;
  if (blk == 0) {
    ((float4*)stats)[tid] = make_float4(0.f, 0.f, 0.f, 0.f);  // 1024 floats
    return;
  }
  if (blk <= 196) {  // gptr boundaries
    int i = (blk - 1) * 256 + tid;
    if (i >= NN) return;
    int b = batch[i];
    int prev = (i == 0) ? -1 : batch[i - 1];
    for (int g = prev + 1; g <= b; ++g) gptr[g] = i;
    if (i == NN - 1) {
      for (int g = b + 1; g <= BBG; ++g) gptr[g] = NN;
    }
    return;
  }
  if (blk <= 392) {  // coarse hist
    int b = blk - 197;
    if (tid < NBIN) hist[tid] = 0;
    __syncthreads();
    const int4* dst4 = (const int4*)(ei + EE);
#pragma unroll
    for (int c = 0; c < 4; ++c) {
      int idx = b * 1024 + c * 256 + tid;
      if (idx < EE / 4) {
        int4 d = dst4[idx];
        atomicAdd(&hist[d.x >> 8], 1);
        atomicAdd(&hist[d.y >> 8], 1);
        atomicAdd(&hist[d.z >> 8], 1);
        atomicAdd(&hist[d.w >> 8], 1);
      }
    }
    __syncthreads();
    if (tid < NBIN) partial[tid * NBLK + b] = hist[tid];
    return;
  }
  if (blk >= 2961) {  // x -> fp16 (6250 blocks x 256 = 1,600,000 float4 groups)
    int i = (blk - 2961) * 256 + tid;
    float4 v = ((const float4*)xsrc)[i];
    half4 h;
    h[0] = (_Float16)v.x; h[1] = (_Float16)v.y;
    h[2] = (_Float16)v.z; h[3] = (_Float16)v.w;
    ((half4*)x16a)[i] = h;
    return;
  }
  // weight prep
  int idx = (blk - 393) * 256 + tid;  // [0, 657408)
  if (idx < 65536) {
    int m = idx >> 14;
    int r = idx & 16383;
    const float* W = (m == 0) ? W0 : (m == 1) ? W1 : (m == 2) ? W2 : W3;
    ginWh[idx] = (_Float16)W[r];  // natural [o][k], k contiguous
  } else if (idx < 262144) {
    int t = idx - 65536;
    int k = t >> 9, op = t & 511;
    int j = op >> 2, g = op & 3;
    int row = g * 128 + j;
    float v = (k < 256) ? Wih0[row * 256 + k] : Whh0[row * 128 + (k - 256)];
    WT0h[((k >> 1) << 10) | (op << 1) | (k & 1)] = (_Float16)v;
  } else if (idx < 655360) {
    int t = idx - 262144;
    int l = t >> 17;
    int rem = t & 131071;
    int k = rem >> 9, op = rem & 511;
    int j = op >> 2, g = op & 3;
    int row = g * 128 + j;
    float v = (k < 128) ? WihR[((size_t)l * 512 + row) * 128 + k]
                        : WhhR[((size_t)l * 512 + row) * 128 + (k - 128)];
    WTRh[((size_t)l << 17) | ((k >> 1) << 10) | (op << 1) | (k & 1)] = (_Float16)v;
  } else {
    int t = idx - 655360;
    if (t < 512) {
      bc0[t] = b0[(t & 3) * 128 + (t >> 2)];
    } else {
      int u = t - 512;
      int l = u >> 9, op = u & 511;
      bcR[u] = bR[l * 512 + (op & 3) * 128 + (op >> 2)];
    }
  }
}

// ---- atomic-free CSR build (two-level counting sort) ----

__global__ void scan_partials_kernel(const int* __restrict__ partial,
                                     int* __restrict__ block_base, int* __restrict__ total) {
  __shared__ int buf[256];
  int bin = blockIdx.x, tid = threadIdx.x;
  int v = (tid < NBLK) ? partial[bin * NBLK + tid] : 0;
  buf[tid] = v;
  __syncthreads();
  for (int off = 1; off < 256; off <<= 1) {
    int t = (tid >= off) ? buf[tid - off] : 0;
    __syncthreads();
    buf[tid] += t;
    __syncthreads();
  }
  if (tid < NBLK) block_base[bin * NBLK + tid] = buf[tid] - v;
  if (tid == 255) total[bin] = buf[255];
}

// bucket_scatter with LOCAL scan of total[] (scan_totals kernel removed)
__global__ __launch_bounds__(256) void bucket_scatter_kernel(const int* __restrict__ ei,
                                                             const int* __restrict__ total,
                                                             const int* __restrict__ block_base,
                                                             int* __restrict__ packed) {
  __shared__ int sbuf[256];
  __shared__ int cursor[NBIN];
  int tid = threadIdx.x, b = blockIdx.x;
  int v = (tid < NBIN) ? total[tid] : 0;
  sbuf[tid] = v;
  __syncthreads();
  for (int off = 1; off < 256; off <<= 1) {
    int t = (tid >= off) ? sbuf[tid - off] : 0;
    __syncthreads();
    sbuf[tid] += t;
    __syncthreads();
  }
  if (tid < NBIN) cursor[tid] = (sbuf[tid] - v) + block_base[tid * NBLK + b];
  __syncthreads();
  const int4* src4 = (const int4*)ei;
  const int4* dst4 = (const int4*)(ei + EE);
#pragma unroll
  for (int c = 0; c < 4; ++c) {
    int idx = b * 1024 + c * 256 + tid;
    if (idx < EE / 4) {
      int4 s = src4[idx];
      int4 d = dst4[idx];
      int p;
      p = atomicAdd(&cursor[d.x >> 8], 1); packed[p] = (s.x << 8) | (d.x & 255);
      p = atomicAdd(&cursor[d.y >> 8], 1); packed[p] = (s.y << 8) | (d.y & 255);
      p = atomicAdd(&cursor[d.z >> 8], 1); packed[p] = (s.z << 8) | (d.z & 255);
      p = atomicAdd(&cursor[d.w >> 8], 1); packed[p] = (s.w << 8) | (d.w & 255);
    }
  }
}

// csr_finalize with LOCAL scan of total[] (scan_totals kernel removed)
__global__ __launch_bounds__(256) void csr_finalize_kernel(const int* __restrict__ packed,
                                                           const int* __restrict__ total,
                                                           int* __restrict__ row_start,
                                                           int* __restrict__ csr) {
  __shared__ int fh[256];
  __shared__ int fb[256];
  int bin = blockIdx.x, tid = threadIdx.x;
  // local exclusive scan of total -> e0, e1
  int tv = (tid < NBIN) ? total[tid] : 0;
  fb[tid] = tv;
  __syncthreads();
  for (int off = 1; off < 256; off <<= 1) {
    int t = (tid >= off) ? fb[tid - off] : 0;
    __syncthreads();
    fb[tid] += t;
    __syncthreads();
  }
  int e0 = (bin == 0) ? 0 : fb[bin - 1];
  int e1 = fb[bin];
  __syncthreads();
  fh[tid] = 0;
  __syncthreads();
  for (int e = e0 + tid; e < e1; e += 256) atomicAdd(&fh[packed[e] & 255], 1);
  __syncthreads();
  int v = fh[tid];
  fb[tid] = v;
  __syncthreads();
  for (int off = 1; off < 256; off <<= 1) {
    int t = (tid >= off) ? fb[tid - off] : 0;
    __syncthreads();
    fb[tid] += t;
    __syncthreads();
  }
  int excl = fb[tid] - v;
  int node = bin * 256 + tid;
  if (node < NN) row_start[node] = e0 + excl;
  if (bin == NBIN - 1 && tid == 0) row_start[NN] = EE;
  __syncthreads();
  fb[tid] = excl;  // cursor
  __syncthreads();
  for (int e = e0 + tid; e < e1; e += 256) {
    int p = packed[e];
    int pos = atomicAdd(&fb[p & 255], 1);
    csr[e0 + pos] = p >> 8;
  }
}

// ---------------- fused GIN aggregation + MFMA GEMM ----------------
template <bool AFF>
__global__ __launch_bounds__(256) void agg_gemm_kernel(
    const _Float16* __restrict__ x16, const int* __restrict__ row_start,
    const int* __restrict__ csr,
    const float* __restrict__ stats, const float* __restrict__ gamma,
    const float* __restrict__ beta,
    const _Float16* __restrict__ Wh, const float* __restrict__ bias,
    _Float16* __restrict__ h16out,
    float* __restrict__ ssum, float* __restrict__ ssq) {
  __shared__ _Float16 As[4][16][136];
  __shared__ float sc_s[128], sh_s[128];
  int tid = threadIdx.x;
  if (AFF) {
    if (tid < 128) {
      const float invN = 1.0f / (float)NN;
      float mm = stats[tid] * invN;
      float vv = stats[128 + tid] * invN - mm * mm;
      float rs = rsqrtf(vv + 1e-5f);
      float sc = gamma[tid] * rs;
      sc_s[tid] = sc;
      sh_s[tid] = beta[tid] - mm * sc;
    }
    __syncthreads();
  }
  int tile0 = blockIdx.x * 4;
  // ---- phase A: gather ----
  {
    int nloc = tid >> 4;  // 0..15
    int t = tid & 15;     // channel chunk
    const half8* xh8 = (const half8*)x16;
    float scv[8], shv[8];
    if (AFF) {
#pragma unroll
      for (int f = 0; f < 8; ++f) { scv[f] = sc_s[t * 8 + f]; shv[f] = sh_s[t * 8 + f]; }
    }
    for (int tt = 0; tt < 4; ++tt) {
      int tile = tile0 + tt;
      if (tile >= 3125) break;
      int node = tile * 16 + nloc;
      int s0 = row_start[node], s1 = row_start[node + 1];
      float acc[8] = {0.f, 0.f, 0.f, 0.f, 0.f, 0.f, 0.f, 0.f};
      int j = s0;
      for (; j + 8 <= s1; j += 8) {
        int i0 = csr[j + 0];
        int i1 = csr[j + 1];
        int i2 = csr[j + 2];
        int i3 = csr[j + 3];
        int i4 = csr[j + 4];
        int i5 = csr[j + 5];
        int i6 = csr[j + 6];
        int i7 = csr[j + 7];
        half8 h0 = xh8[(size_t)i0 * 16 + t];
        half8 h1 = xh8[(size_t)i1 * 16 + t];
        half8 h2 = xh8[(size_t)i2 * 16 + t];
        half8 h3 = xh8[(size_t)i3 * 16 + t];
        half8 h4 = xh8[(size_t)i4 * 16 + t];
        half8 h5 = xh8[(size_t)i5 * 16 + t];
        half8 h6 = xh8[(size_t)i6 * 16 + t];
        half8 h7 = xh8[(size_t)i7 * 16 + t];
#pragma unroll
        for (int f = 0; f < 8; ++f) {
          if (AFF) {
            acc[f] += fmaxf(fmaf((float)h0[f], scv[f], shv[f]), 0.f);
            acc[f] += fmaxf(fmaf((float)h1[f], scv[f], shv[f]), 0.f);
            acc[f] += fmaxf(fmaf((float)h2[f], scv[f], shv[f]), 0.f);
            acc[f] += fmaxf(fmaf((float)h3[f], scv[f], shv[f]), 0.f);
            acc[f] += fmaxf(fmaf((float)h4[f], scv[f], shv[f]), 0.f);
            acc[f] += fmaxf(fmaf((float)h5[f], scv[f], shv[f]), 0.f);
            acc[f] += fmaxf(fmaf((float)h6[f], scv[f], shv[f]), 0.f);
            acc[f] += fmaxf(fmaf((float)h7[f], scv[f], shv[f]), 0.f);
          } else {
            acc[f] += (((float)h0[f] + (float)h1[f]) + ((float)h2[f] + (float)h3[f])) +
                      (((float)h4[f] + (float)h5[f]) + ((float)h6[f] + (float)h7[f]));
          }
        }
      }
      if (j + 4 <= s1) {
        int i0 = csr[j + 0];
        int i1 = csr[j + 1];
        int i2 = csr[j + 2];
        int i3 = csr[j + 3];
        half8 h0 = xh8[(size_t)i0 * 16 + t];
        half8 h1 = xh8[(size_t)i1 * 16 + t];
        half8 h2 = xh8[(size_t)i2 * 16 + t];
        half8 h3 = xh8[(size_t)i3 * 16 + t];
#pragma unroll
        for (int f = 0; f < 8; ++f) {
          if (AFF) {
            acc[f] += fmaxf(fmaf((float)h0[f], scv[f], shv[f]), 0.f);
            acc[f] += fmaxf(fmaf((float)h1[f], scv[f], shv[f]), 0.f);
            acc[f] += fmaxf(fmaf((float)h2[f], scv[f], shv[f]), 0.f);
            acc[f] += fmaxf(fmaf((float)h3[f], scv[f], shv[f]), 0.f);
          } else {
            acc[f] += ((float)h0[f] + (float)h1[f]) + ((float)h2[f] + (float)h3[f]);
          }
        }
        j += 4;
      }
      for (; j < s1; ++j) {
        int i = csr[j];
        half8 h = xh8[(size_t)i * 16 + t];
#pragma unroll
        for (int f = 0; f < 8; ++f) {
          float v = (float)h[f];
          if (AFF) v = fmaxf(fmaf(v, scv[f], shv[f]), 0.f);
          acc[f] += v;
        }
      }
      half8 selfh = xh8[(size_t)node * 16 + t];
      half8 hv;
#pragma unroll
      for (int f = 0; f < 8; ++f) {
        float sv = (float)selfh[f];
        if (AFF) sv = fmaxf(fmaf(sv, scv[f], shv[f]), 0.f);
        hv[f] = (_Float16)(acc[f] + sv);
      }
      *(half8*)&As[tt][nloc][t * 8] = hv;
    }
  }
  __syncthreads();
  // ---- phase B: MFMA ----
  int w = tid >> 6, l = tid & 63;
  int lr = l & 15, lg = l >> 4;
  int cb = w * 32;
  half8 bf0[4], bf1[4];
#pragma unroll
  for (int ks = 0; ks < 4; ++ks) {
    int k = ks * 32 + lg * 8;
    bf0[ks] = *(const half8*)(Wh + (size_t)(cb + lr) * 128 + k);
    bf1[ks] = *(const half8*)(Wh + (size_t)(cb + 16 + lr) * 128 + k);
  }
  float bv0 = bias[cb + lr], bv1 = bias[cb + 16 + lr];
  float ps0 = 0.f, pq0 = 0.f, ps1 = 0.f, pq1 = 0.f;
  for (int tt = 0; tt < 4; ++tt) {
    int tile = tile0 + tt;
    if (tile >= 3125) break;
    half8 af[4];
#pragma unroll
    for (int ks = 0; ks < 4; ++ks) {
      af[ks] = *(const half8*)&As[tt][lr][ks * 32 + lg * 8];
    }
    f32x4 acc0 = {0.f, 0.f, 0.f, 0.f};
    f32x4 acc1 = {0.f, 0.f, 0.f, 0.f};
#pragma unroll
    for (int ks = 0; ks < 4; ++ks) {
      acc0 = __builtin_amdgcn_mfma_f32_16x16x32_f16(af[ks], bf0[ks], acc0, 0, 0, 0);
      acc1 = __builtin_amdgcn_mfma_f32_16x16x32_f16(af[ks], bf1[ks], acc1, 0, 0, 0);
    }
#pragma unroll
    for (int i = 0; i < 4; ++i) {
      int rr = tile * 16 + lg * 4 + i;
      float v0 = acc0[i] + bv0;
      float v1 = acc1[i] + bv1;
      h16out[(size_t)rr * 128 + cb + lr] = (_Float16)v0;
      h16out[(size_t)rr * 128 + cb + 16 + lr] = (_Float16)v1;
      ps0 += v0; pq0 += v0 * v0;
      ps1 += v1; pq1 += v1 * v1;
    }
  }
  ps0 += __shfl_xor(ps0, 16); ps0 += __shfl_xor(ps0, 32);
  pq0 += __shfl_xor(pq0, 16); pq0 += __shfl_xor(pq0, 32);
  ps1 += __shfl_xor(ps1, 16); ps1 += __shfl_xor(ps1, 32);
  pq1 += __shfl_xor(pq1, 16); pq1 += __shfl_xor(pq1, 32);
  if (lg == 0) {
    atomicAdd(&ssum[cb + lr], ps0);
    atomicAdd(&ssq[cb + lr], pq0);
    atomicAdd(&ssum[cb + 16 + lr], ps1);
    atomicAdd(&ssq[cb + 16 + lr], pq1);
  }
}

// ---------------- MFMA GIN GEMM (BN+relu on fp16 A) ----------------
template <bool BN>
__global__ __launch_bounds__(256) void gemm_gin_mfma_kernel(
    const _Float16* __restrict__ A16,
    const _Float16* __restrict__ Wh,
    const float* __restrict__ bias,
    const float* __restrict__ stats, const float* __restrict__ gamma,
    const float* __restrict__ beta,
    _Float16* __restrict__ h16out,
    float* __restrict__ ssum, float* __restrict__ ssq) {
  __shared__ float bsc_s[128], bsh_s[128];
  int tid = threadIdx.x;
  if (BN) {
    if (tid < 128) {
      const float invN = 1.0f / (float)NN;
      float mm = stats[tid] * invN;
      float vv = stats[128 + tid] * invN - mm * mm;
      float rs = rsqrtf(vv + 1e-5f);
      float sc = gamma[tid] * rs;
      bsc_s[tid] = sc;
      bsh_s[tid] = beta[tid] - mm * sc;
    }
    __syncthreads();
  }
  int w = tid >> 6, l = tid & 63;
  int lr = l & 15, lg = l >> 4;
  int cb = w * 32;
  half8 bf0[4], bf1[4];
#pragma unroll
  for (int ks = 0; ks < 4; ++ks) {
    int k = ks * 32 + lg * 8;
    bf0[ks] = *(const half8*)(Wh + (size_t)(cb + lr) * 128 + k);
    bf1[ks] = *(const half8*)(Wh + (size_t)(cb + 16 + lr) * 128 + k);
  }
  float bv0 = bias[cb + lr], bv1 = bias[cb + 16 + lr];
  float ps0 = 0.f, pq0 = 0.f, ps1 = 0.f, pq1 = 0.f;
  int t0 = blockIdx.x * 4;
  for (int t = 0; t < 4; ++t) {
    int tile = t0 + t;
    if (tile >= 3125) break;
    int r = tile * 16 + lr;
    half8 af[4];
#pragma unroll
    for (int ks = 0; ks < 4; ++ks) {
      int k0 = ks * 32 + lg * 8;
      half8 ah = *(const half8*)(A16 + (size_t)r * 128 + k0);
      if constexpr (BN) {
        float4 s0 = *(const float4*)&bsc_s[k0];
        float4 s1 = *(const float4*)&bsc_s[k0 + 4];
        float4 h0 = *(const float4*)&bsh_s[k0];
        float4 h1 = *(const float4*)&bsh_s[k0 + 4];
        half8 o;
        o[0] = (_Float16)fmaxf(fmaf((float)ah[0], s0.x, h0.x), 0.f);
        o[1] = (_Float16)fmaxf(fmaf((float)ah[1], s0.y, h0.y), 0.f);
        o[2] = (_Float16)fmaxf(fmaf((float)ah[2], s0.z, h0.z), 0.f);
        o[3] = (_Float16)fmaxf(fmaf((float)ah[3], s0.w, h0.w), 0.f);
        o[4] = (_Float16)fmaxf(fmaf((float)ah[4], s1.x, h1.x), 0.f);
        o[5] = (_Float16)fmaxf(fmaf((float)ah[5], s1.y, h1.y), 0.f);
        o[6] = (_Float16)fmaxf(fmaf((float)ah[6], s1.z, h1.z), 0.f);
        o[7] = (_Float16)fmaxf(fmaf((float)ah[7], s1.w, h1.w), 0.f);
        af[ks] = o;
      } else {
        af[ks] = ah;
      }
    }
    f32x4 acc0 = {0.f, 0.f, 0.f, 0.f};
    f32x4 acc1 = {0.f, 0.f, 0.f, 0.f};
#pragma unroll
    for (int ks = 0; ks < 4; ++ks) {
      acc0 = __builtin_amdgcn_mfma_f32_16x16x32_f16(af[ks], bf0[ks], acc0, 0, 0, 0);
      acc1 = __builtin_amdgcn_mfma_f32_16x16x32_f16(af[ks], bf1[ks], acc1, 0, 0, 0);
    }
#pragma unroll
    for (int i = 0; i < 4; ++i) {
      int rr = tile * 16 + lg * 4 + i;
      float v0 = acc0[i] + bv0;
      float v1 = acc1[i] + bv1;
      h16out[(size_t)rr * 128 + cb + lr] = (_Float16)v0;
      h16out[(size_t)rr * 128 + cb + 16 + lr] = (_Float16)v1;
      ps0 += v0; pq0 += v0 * v0;
      ps1 += v1; pq1 += v1 * v1;
    }
  }
  ps0 += __shfl_xor(ps0, 16); ps0 += __shfl_xor(ps0, 32);
  pq0 += __shfl_xor(pq0, 16); pq0 += __shfl_xor(pq0, 32);
  ps1 += __shfl_xor(ps1, 16); ps1 += __shfl_xor(ps1, 32);
  pq1 += __shfl_xor(pq1, 16); pq1 += __shfl_xor(pq1, 32);
  if (lg == 0) {
    atomicAdd(&ssum[cb + lr], ps0);
    atomicAdd(&ssq[cb + lr], pq0);
    atomicAdd(&ssum[cb + 16 + lr], ps1);
    atomicAdd(&ssq[cb + 16 + lr], pq1);
  }
}

// ---------------- fused Set2Set v8: fp16 shadow state (no inp2 staging barrier),
// atomic max/sum (2 fewer barriers/step), fp16 LDS x-cache, step-0 skip -------
__global__ void __launch_bounds__(1024) set2set_kernel(
    const _Float16* __restrict__ x, const int* __restrict__ gptr,
    const float* __restrict__ stats, const float* __restrict__ gamma,
    const float* __restrict__ beta,
    const _Float16* __restrict__ WT0h, const _Float16* __restrict__ WTRh,
    const float* __restrict__ bc0, const float* __restrict__ bcR,
    float* __restrict__ ebuf,
    const float* __restrict__ linW, const float* __restrict__ linb,
    float* __restrict__ out) {
  __shared__ half2v xs[SEG_CAP * 64];   // 114688 B (448 rows, fp16-packed)
  __shared__ float wpart[16][512];      // 32 KB (aliased as rpart in attention)
  __shared__ float hcs[4][128];
  __shared__ float ccs[4][128];
  __shared__ _Float16 h16s[4][128];     // fp16 shadow of hcs (matvec operand)
  __shared__ _Float16 q16s[256];        // fp16 shadow of qst
  __shared__ float qst[256];
  __shared__ float es[ESC];             // 2 KB
  __shared__ float bsc[128], bsh[128];
  __shared__ unsigned smax_u;
  __shared__ float ssum_s;
  __shared__ float fred[2][4];

  int g = blockIdx.x, tid = threadIdx.x;
  int w16 = tid >> 6, lane = tid & 63;

  // init
  if (tid < 128) {
    const float invN = 1.0f / (float)NN;
    float mm = stats[tid] * invN;
    float vv = stats[128 + tid] * invN - mm * mm;
    float rs = rsqrtf(vv + 1e-5f);
    float sc = gamma[tid] * rs;
    bsc[tid] = sc;
    bsh[tid] = beta[tid] - mm * sc;
#pragma unroll
    for (int l = 0; l < 4; ++l) {
      hcs[l][tid] = 0.f; ccs[l][tid] = 0.f; h16s[l][tid] = (_Float16)0.f;
    }
  }
  if (tid < 256) { qst[tid] = 0.f; q16s[tid] = (_Float16)0.f; }
  __syncthreads();

  int s0 = gptr[g], s1 = gptr[g + 1];
  int seg = s1 - s0;
  int ncache = seg < SEG_CAP ? seg : SEG_CAP;
  const half2v* xh = (const half2v*)x;
  float sc0 = bsc[2 * lane], sc1 = bsc[2 * lane + 1];
  float sh0 = bsh[2 * lane], sh1 = bsh[2 * lane + 1];
  // stage segment into LDS once (BN4-transformed, fp16-packed); one row per wave
  for (int n = w16; n < ncache; n += 16) {
    half2v v = xh[(size_t)(s0 + n) * 64 + lane];
    half2v h;
    h[0] = (_Float16)fmaxf(fmaf((float)v[0], sc0, sh0), 0.f);
    h[1] = (_Float16)fmaxf(fmaf((float)v[1], sc1, sh1), 0.f);
    xs[n * 64 + lane] = h;
  }
  __syncthreads();

  int s_ = tid >> 6, cg = tid & 63;  // matvec: K-slice (16), col-group (8 cols)

  for (int step = 0; step < 4; ++step) {
    // ---- 4 stacked LSTM cells ----
    for (int cell = 0; cell < 4; ++cell) {
      const _Float16* WTh; const float* bias; int KP2;
      if (cell == 0) {
        WTh = WT0h; bias = bc0; KP2 = 12;  // K=384 -> 192 k2-pairs, 12 per slice
      } else {
        WTh = WTRh + (size_t)(cell - 1) * 131072;
        bias = bcR + (cell - 1) * 512; KP2 = 8;  // K=256 -> 128 pairs, 8 per slice
      }
      bool skipmv = (step == 0 && cell == 0);
      if (!skipmv) {
        int se = (s_ + g) & 15;  // rotate slice start per block
        int k20 = se * KP2;
        float a0 = 0.f, a1 = 0.f, a2 = 0.f, a3 = 0.f;
        float a4 = 0.f, a5 = 0.f, a6 = 0.f, a7 = 0.f;
        // step 0, cells>=1: old-h half is zero -> only slices se<8 contribute
        if (step != 0 || se < 8) {
          const char* wb = (const char*)WTh + (size_t)k20 * 2048 + (cg << 5);
#pragma unroll 4
          for (int k2 = 0; k2 < KP2; ++k2) {
            uint4 wa = *(const uint4*)(wb + (size_t)k2 * 2048);
            uint4 wc = *(const uint4*)(wb + (size_t)k2 * 2048 + 16);
            int kk = (k20 + k2) << 1;  // wave-uniform
            half2v i2;
            if (cell == 0) {
              i2 = (kk < 256) ? *(const half2v*)&q16s[kk]
                              : *(const half2v*)&h16s[0][kk - 256];
            } else {
              i2 = (kk < 128) ? *(const half2v*)&h16s[cell - 1][kk]
                              : *(const half2v*)&h16s[cell][kk - 128];
            }
            a0 = fdot2f(i2, __builtin_bit_cast(half2v, wa.x), a0);
            a1 = fdot2f(i2, __builtin_bit_cast(half2v, wa.y), a1);
            a2 = fdot2f(i2, __builtin_bit_cast(half2v, wa.z), a2);
            a3 = fdot2f(i2, __builtin_bit_cast(half2v, wa.w), a3);
            a4 = fdot2f(i2, __builtin_bit_cast(half2v, wc.x), a4);
            a5 = fdot2f(i2, __builtin_bit_cast(half2v, wc.y), a5);
            a6 = fdot2f(i2, __builtin_bit_cast(half2v, wc.z), a6);
            a7 = fdot2f(i2, __builtin_bit_cast(half2v, wc.w), a7);
          }
        }
        *(float4*)&wpart[s_][cg << 3] = make_float4(a0, a1, a2, a3);
        *(float4*)(&wpart[s_][cg << 3] + 4) = make_float4(a4, a5, a6, a7);
        __syncthreads();
      }
      // merged gates-reduce + activation (128 threads, float4 over 16 slices)
      if (tid < 128) {
        int j = tid;
        float4 ga = *(const float4*)&bias[4 * j];
        if (!skipmv) {
#pragma unroll
          for (int s = 0; s < 16; ++s) {
            float4 wv = *(const float4*)&wpart[s][4 * j];
            ga.x += wv.x; ga.y += wv.y; ga.z += wv.z; ga.w += wv.w;
          }
        }
        float cp = ccs[cell][j];
        float si = fsigm(ga.x);
        float sf = fsigm(ga.y);
        float so = fsigm(ga.w);
        float cn = sf * cp + si * ftanh(ga.z);
        ccs[cell][j] = cn;
        float hn = so * ftanh(cn);
        hcs[cell][j] = hn;
        h16s[cell][j] = (_Float16)hn;
        if (cell == 3 && j == 0) { smax_u = 0u; ssum_s = 0.f; }
      }
      __syncthreads();
    }
    // ---- attention, q = new h[3]; x from fp16 LDS cache ----
    float* rpart = &wpart[0][0];  // alias: time-disjoint with matvec
    float qx = hcs[3][2 * lane], qy = hcs[3][2 * lane + 1];
    half2v q2; q2[0] = (_Float16)qx; q2[1] = (_Float16)qy;
    // pass 1: e + max (block max via monotonic-key atomicMax, 1 barrier)
    float wmax = -3.0e38f;
    for (int n = w16; n < seg; n += 16) {
      float e;
      if (n < ncache) {
        e = fdot2f(xs[n * 64 + lane], q2, 0.f);
      } else {
        half2v v = xh[(size_t)(s0 + n) * 64 + lane];
        float vx = fmaxf(fmaf((float)v[0], sc0, sh0), 0.f);
        float vy = fmaxf(fmaf((float)v[1], sc1, sh1), 0.f);
        e = vx * qx + vy * qy;
      }
#pragma unroll
      for (int sh = 32; sh; sh >>= 1) e += __shfl_xor(e, sh);
      if (lane == 0) { if (n < ESC) es[n] = e; else ebuf[s0 + n] = e; }
      wmax = fmaxf(wmax, e);
    }
    if (lane == 0) atomicMax(&smax_u, keyf(wmax));
    __syncthreads();
    float m = unkeyf(smax_u);
    // pass 2: sum exp (atomicAdd, 1 barrier); cache exp for pass 3
    float loc = 0.f;
    for (int n = tid; n < seg; n += 1024) {
      float e = (n < ESC) ? es[n] : ebuf[s0 + n];
      float ex = __expf(e - m);
      if (n < ESC) es[n] = ex; else ebuf[s0 + n] = ex;
      loc += ex;
    }
#pragma unroll
    for (int sh = 32; sh; sh >>= 1) loc += __shfl_xor(loc, sh);
    if (lane == 0) atomicAdd(&ssum_s, loc);
    __syncthreads();
    float inv = 1.0f / ssum_s;
    // pass 3: r = sum a*x
    float rx = 0.f, ry = 0.f;
    for (int n = w16; n < seg; n += 16) {
      float ex = (n < ESC) ? es[n] : ebuf[s0 + n];
      float coef = ex * inv;
      float vx, vy;
      if (n < ncache) {
        half2v v2 = xs[n * 64 + lane];
        vx = (float)v2[0]; vy = (float)v2[1];
      } else {
        half2v v = xh[(size_t)(s0 + n) * 64 + lane];
        vx = fmaxf(fmaf((float)v[0], sc0, sh0), 0.f);
        vy = fmaxf(fmaf((float)v[1], sc1, sh1), 0.f);
      }
      rx += coef * vx; ry += coef * vy;
    }
    rpart[w16 * 128 + 2 * lane] = rx;
    rpart[w16 * 128 + 2 * lane + 1] = ry;
    __syncthreads();
    if (tid < 128) {
      float r = 0.f;
#pragma unroll
      for (int t = 0; t < 16; ++t) r += rpart[t * 128 + tid];
      float h3 = hcs[3][tid];
      qst[tid] = h3;
      qst[128 + tid] = r;
      q16s[tid] = (_Float16)h3;
      q16s[128 + tid] = (_Float16)r;
    }
    __syncthreads();
  }
  // ---- final linear ----
  if (tid < 256) {
    float val = qst[tid];
    float p0 = val * linW[tid];
    float p1 = val * linW[256 + tid];
#pragma unroll
    for (int sh = 32; sh; sh >>= 1) { p0 += __shfl_xor(p0, sh); p1 += __shfl_xor(p1, sh); }
    if (lane == 0) { fred[0][w16] = p0; fred[1][w16] = p1; }
  }
  __syncthreads();
  if (tid == 0) {
    out[2 * g + 0] = fred[0][0] + fred[0][1] + fred[0][2] + fred[0][3] + linb[0];
    out[2 * g + 1] = fred[1][0] + fred[1][1] + fred[1][2] + fred[1][3] + linb[1];
  }
}

// ---------------- launch ----------------

extern "C" void kernel_launch(void* const* d_in, const int* in_sizes, int n_in,
                              void* d_out, int out_size, void* d_ws, size_t ws_size,
                              hipStream_t stream) {
  const float* x = (const float*)d_in[0];
  const int* ei = (const int*)d_in[1];
  const int* batch = (const int*)d_in[2];
  const float* gW[4]  = {(const float*)d_in[3],  (const float*)d_in[7],
                         (const float*)d_in[11], (const float*)d_in[15]};
  const float* gb[4]  = {(const float*)d_in[4],  (const float*)d_in[8],
                         (const float*)d_in[12], (const float*)d_in[16]};
  const float* gga[4] = {(const float*)d_in[5],  (const float*)d_in[9],
                         (const float*)d_in[13], (const float*)d_in[17]};
  const float* gbe[4] = {(const float*)d_in[6],  (const float*)d_in[10],
                         (const float*)d_in[14], (const float*)d_in[18]};
  const float* Wih0 = (const float*)d_in[19];
  const float* Whh0 = (const float*)d_in[20];
  const float* b0   = (const float*)d_in[21];
  const float* WihR = (const float*)d_in[22];
  const float* WhhR = (const float*)d_in[23];
  const float* bR   = (const float*)d_in[24];
  const float* linW = (const float*)d_in[25];
  const float* linb = (const float*)d_in[26];
  float* out = (float*)d_out;

  char* base = (char*)d_ws;
  size_t off = 0;
  auto allocf = [&](size_t n) { float* p = (float*)(base + off); off += n * sizeof(float); return p; };
  _Float16* bufA = (_Float16*)(base + off); off += 6400000 * 2;  // prep x16 / gemm4 out
  _Float16* bufB = (_Float16*)(base + off); off += 6400000 * 2;  // aggemm1 out / aggemm2 out
  _Float16* bufC = (_Float16*)(base + off); off += 6400000 * 2;  // gemm2 out
  _Float16* ginWh = (_Float16*)(base + off); off += 65536 * 2;
  _Float16* WT0h = (_Float16*)(base + off); off += 196608 * 2;
  _Float16* WTRh = (_Float16*)(base + off); off += 393216 * 2;
  float* bc0   = allocf(512);
  float* bcR   = allocf(1536);
  float* ebuf  = allocf(50000);
  // ---- zero region: stats only (1024 floats = 256 float4) ----
  float* stats = allocf(1024);     // 4 x (sum128|sq128)
  // ---- ints (all fully written before read; no zeroing needed) ----
  int* row_start = (int*)(base + off); off += 50004 * 4;
  int* gptr = (int*)(base + off); off += 260 * 4;
  int* csr = (int*)(base + off); off += 800000 * 4;
  int* packed = (int*)(base + off); off += 800000 * 4;
  int* partial = (int*)(base + off); off += NBIN * NBLK * 4;
  int* block_base = (int*)(base + off); off += NBIN * NBLK * 4;
  int* total = (int*)(base + off); off += 256 * 4;
  (void)ws_size; (void)in_sizes; (void)n_in; (void)out_size;

  // merged prep: zero | gptr | hist | weight repack | x->fp16
  prep_all_kernel<<<9211, 256, 0, stream>>>(batch, ei, gW[0], gW[1], gW[2], gW[3],
                                            Wih0, Whh0, WihR, WhhR, b0, bR, x,
                                            stats, gptr, partial, ginWh, WT0h, WTRh,
                                            bc0, bcR, bufA);
  scan_partials_kernel<<<NBIN, 256, 0, stream>>>(partial, block_base, total);
  bucket_scatter_kernel<<<NBLK, 256, 0, stream>>>(ei, total, block_base, packed);
  csr_finalize_kernel<<<NBIN, 256, 0, stream>>>(packed, total, row_start, csr);

  // GIN layer 1: fused gather+gemm1 (reads bufA, writes bufB), stats0
  agg_gemm_kernel<false><<<782, 256, 0, stream>>>(
      bufA, row_start, csr,
      nullptr, nullptr, nullptr,
      ginWh + 0 * 16384, gb[0],
      bufB, stats + 0, stats + 128);
  // gemm2: BN1+relu on bufB, writes bufC, stats1
  gemm_gin_mfma_kernel<true><<<782, 256, 0, stream>>>(
      bufB, ginWh + 1 * 16384, gb[1],
      stats + 0, gga[0], gbe[0],
      bufC, stats + 256, stats + 384);
  // GIN layer 2: fused gather(BN2+relu on bufC)+gemm3 (writes bufB), stats2
  agg_gemm_kernel<true><<<782, 256, 0, stream>>>(
      bufC, row_start, csr,
      stats + 256, gga[1], gbe[1],
      ginWh + 2 * 16384, gb[2],
      bufB, stats + 512, stats + 640);
  // gemm4: BN3+relu on bufB, writes bufA (set2set input), stats3
  gemm_gin_mfma_kernel<true><<<782, 256, 0, stream>>>(
      bufB, ginWh + 3 * 16384, gb[3],
      stats + 512, gga[2], gbe[2],
      bufA, stats + 768, stats + 896);
  // bufA holds pre-BN4 features (fp16); BN4 fused into set2set x staging

  // fused Set2Set v8 (fp16 x input)
  set2set_kernel<<<256, 1024, 0, stream>>>(bufA, gptr, stats + 768, gga[3], gbe[3],
                                           WT0h, WTRh, bc0, bcR, ebuf, linW, linb, out);
}